// Round 13
// baseline (1256.662 us; speedup 1.0000x reference)
//
#include <hip/hip_runtime.h>
#include <math.h>

typedef unsigned short ushort_t;

#define B_   8
#define N_   2048
#define K_   16
#define C2_  128
#define C4_  256
#define KH_  8
#define TAP_ 9
#define NK_  32768
#define EPSv 1e-5f
#define BIGF 3.0e38f
#define NMASK 2047

constexpr size_t AL(size_t x) { return (x + 255) & ~(size_t)255; }
constexpr size_t OFF_XT   = 0;                                                  // f32 [B][N][64]
constexpr size_t OFF_IDX  = OFF_XT  + AL(4ull * B_ * N_ * 64);
constexpr size_t OFF_U1   = OFF_IDX + AL(4ull * B_ * N_ * K_);
constexpr size_t OFF_V1   = OFF_U1  + AL(4ull * B_ * 16 * N_);
constexpr size_t OFF_U2   = OFF_V1  + AL(4ull * B_ * N_ * 16);
constexpr size_t OFF_V2   = OFF_U2  + AL(4ull * B_ * 16 * N_);
constexpr size_t OFF_S    = OFF_V2  + AL(4ull * B_ * N_ * 16);                  // f32 [B][N][128]
constexpr size_t OFF_P    = OFF_S   + AL(4ull * B_ * N_ * C2_);                 // f32 [B][N][256]
constexpr size_t OFF_W1   = OFF_P   + AL(4ull * B_ * N_ * C4_);                 // f32 [B][16][NK]
constexpr size_t OFF_QB   = OFF_W1  + AL(4ull * B_ * 16 * NK_);                 // bf16 [B][N][9][256]
constexpr size_t OFF_ITB  = OFF_QB  + AL(2ull * (size_t)B_ * N_ * TAP_ * C4_);  // bf16 [B][N][2048]
constexpr size_t OFF_A4B  = OFF_ITB + AL(2ull * (size_t)B_ * N_ * 2048);        // bf16 [B][N][2048]
constexpr size_t OFF_M    = OFF_A4B + AL(2ull * (size_t)B_ * N_ * 2048);        // bf16 [B][N][2048]
constexpr size_t OFF_PART = OFF_M   + AL(2ull * (size_t)B_ * N_ * 2048);        // f32 [2][B][N][128]
constexpr size_t OFF_OUT2 = OFF_PART+ AL(4ull * 2 * (size_t)B_ * N_ * C2_);     // f32 [B][N][128]
constexpr size_t OFF_WQ2  = OFF_OUT2+ AL(4ull * B_ * N_ * C2_);
constexpr size_t OFF_WC2  = OFF_WQ2 + AL(4ull * TAP_ * C4_ * 64);
constexpr size_t OFF_WP2  = OFF_WC2 + AL(4ull * 3072 * C2_);
constexpr size_t OFF_WS2  = OFF_WP2 + AL(4ull * C4_ * 64);
constexpr size_t OFF_WU12 = OFF_WS2 + AL(4ull * C2_ * 64);
constexpr size_t OFF_WV12 = OFF_WU12+ AL(4ull * 16 * 64);
constexpr size_t OFF_WU22 = OFF_WV12+ AL(4ull * 16 * 64);
constexpr size_t OFF_WV22 = OFF_WU22+ AL(4ull * 64);
constexpr size_t OFF_A12  = OFF_WV22+ AL(4ull * 64);
constexpr size_t OFF_A22  = OFF_A12 + AL(4ull * 64 * 16);
constexpr size_t OFF_ST   = OFF_A22 + AL(4ull * C2_ * 64);
constexpr size_t OFF_PROG = OFF_ST  + AL(4ull * 4096);
constexpr size_t POOL_SZ  = OFF_PROG + AL(4ull * 64);

static char* g_pool_mem = nullptr;
struct PoolInit {
  PoolInit() { if (hipMalloc((void**)&g_pool_mem, POOL_SZ) != hipSuccess) g_pool_mem = nullptr; }
};
static PoolInit g_pool_init;

// g_st float offsets
#define ST_S1S 0
#define ST_S1Q 16
#define ST_S2S 32
#define ST_S2Q 48
#define ST_S5S 64
#define ST_S5Q 320
#define ST_S4S 576
#define ST_S4Q 704
#define ST_S6S 832
#define ST_S6Q 960
#define ST_B1SC 1088
#define ST_B1SH 1104
#define ST_B2SC 1120
#define ST_B2SH 1136
#define ST_B3SC 1152
#define ST_B3SH 1216
#define ST_B4SC 1280
#define ST_B4SH 1408
#define ST_B5SC 1536
#define ST_B5SH 1792
#define ST_B6SC 2048
#define ST_B6SH 2176
#define ST_S3M  2304
#define ST_S3V  2440

#define BASE(b)  char* bb = (b)
#define P_XT   ((float*)(bb + OFF_XT))
#define P_IDX  ((int*)(bb + OFF_IDX))
#define P_U1   ((float*)(bb + OFF_U1))
#define P_V1   ((float*)(bb + OFF_V1))
#define P_U2   ((float*)(bb + OFF_U2))
#define P_V2   ((float*)(bb + OFF_V2))
#define P_Sb   ((float*)(bb + OFF_S))
#define P_P    ((float*)(bb + OFF_P))
#define P_W1   ((float*)(bb + OFF_W1))
#define P_QB   ((ushort_t*)(bb + OFF_QB))
#define P_IT   ((ushort_t*)(bb + OFF_ITB))
#define P_A4   ((ushort_t*)(bb + OFF_A4B))
#define P_M    ((ushort_t*)(bb + OFF_M))
#define P_PART ((float*)(bb + OFF_PART))
#define P_OUT2 ((float*)(bb + OFF_OUT2))
#define P_WQ2  ((float*)(bb + OFF_WQ2))
#define P_WC2  ((float*)(bb + OFF_WC2))
#define P_WP2  ((float*)(bb + OFF_WP2))
#define P_WS2  ((float*)(bb + OFF_WS2))
#define P_WU12 ((float*)(bb + OFF_WU12))
#define P_WV12 ((float*)(bb + OFF_WV12))
#define P_WU22 ((float*)(bb + OFF_WU22))
#define P_WV22 ((float*)(bb + OFF_WV22))
#define P_A12  ((float*)(bb + OFF_A12))
#define P_A22  ((float*)(bb + OFF_A22))
#define P_ST   ((float*)(bb + OFF_ST))
#define P_PROG ((int*)(bb + OFF_PROG))

#define PROG(id) do { if (threadIdx.x == 0) atomicAdd(&P_PROG[(id)], 1); } while (0)

static __device__ __forceinline__ float lrelu(float x) { return x >= 0.0f ? x : 0.01f * x; }
static __device__ __forceinline__ float bf2f(unsigned h) {
  union { float f; unsigned u; } v; v.u = h << 16; return v.f;
}
static __device__ __forceinline__ ushort_t f2bf(float f) {
  union { float f; unsigned u; } v; v.f = f;
  unsigned r = v.u + 0x7fffu + ((v.u >> 16) & 1u);
  return (ushort_t)(r >> 16);
}

// --------------------------------------------------------------------------- id 0
__global__ __launch_bounds__(256) void zero_kernel(char* base)
{
  BASE(base);
  for (int i = threadIdx.x; i < 4096; i += 256) P_ST[i] = 0.0f;
  for (int i = threadIdx.x; i < 64; i += 256) P_PROG[i] = 0;
  __syncthreads();
  if (threadIdx.x == 0) P_PROG[0] = 1;
}

// --------------------------------------------------------------------------- id 8
// xt v2: LDS-tiled transpose (coalesced both sides, conflict-free [c][65]).
__global__ __launch_bounds__(256) void xt_kernel(char* base, const float* __restrict__ x)
{
  BASE(base);
  PROG(8);
  int b = blockIdx.x >> 5; int m0 = (blockIdx.x & 31) * 64;
  int t = threadIdx.x;
  __shared__ float tile[64 * 65];
  for (int i = t; i < 4096; i += 256) {
    int ml = i & 63, c = i >> 6;
    tile[c * 65 + ml] = x[((size_t)(b * 64 + c)) * N_ + m0 + ml];
  }
  __syncthreads();
  for (int i = t; i < 4096; i += 256) {
    int c = i & 63, ml = i >> 6;
    P_XT[((size_t)(b * N_) + m0 + ml) * 64 + c] = tile[c * 65 + ml];
  }
}

// --------------------------------------------------------------------------- id 1
// prep v3: weights only. 576640 elements, grid 2253.
__global__ __launch_bounds__(256) void prep_kernel(char* base,
    const float* __restrict__ fea_w,
    const float* __restrict__ xyz_w, const float* __restrict__ inte_w,
    const float* __restrict__ c2_w, const float* __restrict__ all1_w,
    const float* __restrict__ all2_w)
{
  BASE(base);
  PROG(1);
  int i = blockIdx.x * 256 + threadIdx.x;
  if (i < 1024) { int o = i & 15, c = i >> 4;    // WU12T[c][o]
    P_WU12[i] = fea_w[o * 128 + c] - fea_w[o * 128 + 64 + c]; return; }
  i -= 1024;
  if (i < 1024) { int o = i & 15, c = i >> 4;    // WV12T[c][o]
    P_WV12[i] = fea_w[o * 128 + 64 + c]; return; }
  i -= 1024;
  if (i < 64) { int c = i & 3, o = i >> 2;
    P_WU22[i] = (c < 3) ? (xyz_w[o * 6 + c] - xyz_w[o * 6 + 3 + c]) : 0.0f; return; }
  i -= 64;
  if (i < 64) { int c = i & 3, o = i >> 2;
    P_WV22[i] = (c < 3) ? xyz_w[o * 6 + 3 + c] : 0.0f; return; }
  i -= 64;
  if (i < 16384) { int o = i & 255, c = i >> 8;  // WP2T[c][o]
    float s = 0.0f;
    for (int t = 0; t < TAP_; t++)
      s += inte_w[(o * 128 + c) * TAP_ + t] - inte_w[(o * 128 + 64 + c) * TAP_ + t];
    P_WP2[i] = s; return; }
  i -= 16384;
  if (i < 147456) {                       // WQ2T[t9][c][o]  (o fastest)
    int o = i & 255; int tc = i >> 8; int c = tc & 63; int tt = tc >> 6;
    P_WQ2[i] = inte_w[(o * 128 + 64 + c) * TAP_ + tt]; return; }
  i -= 147456;
  if (i < 8192) { int o = i & 127, c = i >> 7;   // WS2T[c][o]
    float s = 0.0f;
    for (int p = 0; p < 16; p++)
      s += c2_w[(o * 128 + c) * 32 + p] - c2_w[(o * 128 + 64 + c) * 32 + p];
    P_WS2[i] = s; return; }
  i -= 8192;
  if (i < 393216) { int o = i & 127; int k = i >> 7; float v;
    if (k < 1024) { int c = k >> 4, p = k & 15; v = c2_w[(o * 128 + 64 + c) * 32 + p]; }
    else { int kr = k - 1024; int cc = kr >> 4, kk = kr & 15; v = c2_w[(o * 128 + cc) * 32 + 16 + kk]; }
    P_WC2[i] = v; return; }
  i -= 393216;
  if (i < 1024) { int c = i & 15, o = i >> 4; P_A12[i] = all1_w[o * 16 + c]; return; }
  i -= 1024;
  if (i < 8192) {                         // A22T[c][o]  (o fastest)
    int o = i & 127, c = i >> 7; P_A22[i] = all2_w[o * 64 + c]; return; }
}

// --------------------------------------------------------------------------- id 2
// knn v4: 8 queries/block (grid 2048) -> halves x re-read traffic. Distances
// for all 8 queries kept in 64 regs; two-phase selection reuses the same
// 4x2048 LDS rows (write rows 0-3 -> select -> barrier -> write rows 4-7 ->
// select). Selection math identical to v3 (same butterfly, same tiebreak).
__global__ __launch_bounds__(256) void knn_kernel(char* base,
                                                  const float* __restrict__ x)
{
  BASE(base);
  PROG(2);
  int b = blockIdx.x >> 8; int n0 = (blockIdx.x & 255) * 8;
  int t = threadIdx.x;
  __shared__ float sdist[4][N_];
  __shared__ __align__(16) float xn[8][64];
  __shared__ float sxn[8];
  for (int i = t; i < 512; i += 256) {
    int nn = i >> 6, c = i & 63;
    xn[nn][c] = P_XT[((size_t)(b * N_) + n0 + nn) * 64 + c];
  }
  __syncthreads();
  if (t < 8) {
    float s = 0.0f;
    for (int c = 0; c < 64; c++) { float v = xn[t][c]; s += v * v; }
    sxn[t] = s;
  }
  __syncthreads();
  float dd[64]; float xs[8];
#pragma unroll
  for (int i = 0; i < 64; i++) dd[i] = 0.0f;
#pragma unroll
  for (int i = 0; i < 8; i++) xs[i] = 0.0f;
  const float* xbase = x + (size_t)b * 64 * N_ + (t << 3);   // channel-major rows
  for (int cq = 0; cq < 16; cq++) {
    float4 aq[8];
#pragma unroll
    for (int q = 0; q < 8; q++) aq[q] = *(const float4*)&xn[q][cq * 4];
    float p[4][8];
#pragma unroll
    for (int cc = 0; cc < 4; cc++) {
      const float* xr = xbase + (size_t)(cq * 4 + cc) * N_;
      float4 u = *(const float4*)xr;
      float4 v = *(const float4*)(xr + 4);
      p[cc][0] = u.x; p[cc][1] = u.y; p[cc][2] = u.z; p[cc][3] = u.w;
      p[cc][4] = v.x; p[cc][5] = v.y; p[cc][6] = v.z; p[cc][7] = v.w;
    }
#pragma unroll
    for (int j = 0; j < 8; j++) {
      float x0 = p[0][j], x1 = p[1][j], x2 = p[2][j], x3 = p[3][j];
      xs[j] += x0 * x0 + x1 * x1 + x2 * x2 + x3 * x3;
#pragma unroll
      for (int q = 0; q < 8; q++)
        dd[q * 8 + j] += aq[q].x * x0 + aq[q].y * x1 + aq[q].z * x2 + aq[q].w * x3;
    }
  }
  float sxr[8];
#pragma unroll
  for (int q = 0; q < 8; q++) sxr[q] = sxn[q];
  int mb = t << 3;
#pragma unroll
  for (int q = 0; q < 8; q++)
#pragma unroll
    for (int j = 0; j < 8; j++) {
      int m = mb + j;
      float d = -2.0f * dd[q * 8 + j] + sxr[q] + xs[j];
      dd[q * 8 + j] = (m == n0 + q) ? BIGF : d;
    }
  int ln = t & 63; int wv = t >> 6;
#pragma unroll
  for (int half = 0; half < 2; half++) {
    // stage 4 query rows (float4 stores)
#pragma unroll
    for (int q = 0; q < 4; q++) {
      int qq = half * 4 + q;
      *(float4*)&sdist[q][mb] =
          make_float4(dd[qq * 8 + 0], dd[qq * 8 + 1], dd[qq * 8 + 2], dd[qq * 8 + 3]);
      *(float4*)&sdist[q][mb + 4] =
          make_float4(dd[qq * 8 + 4], dd[qq * 8 + 5], dd[qq * 8 + 6], dd[qq * 8 + 7]);
    }
    __syncthreads();
    // selection: wave wv handles query half*4+wv
    float v[32];
#pragma unroll
    for (int j = 0; j < 32; j++) v[j] = sdist[wv][ln + j * 64];
    float bv = v[0]; int bj = 0;
#pragma unroll
    for (int j = 1; j < 32; j++) { if (v[j] < bv) { bv = v[j]; bj = j; } }
    int* op = P_IDX + ((size_t)(b * N_) + n0 + half * 4 + wv) * K_;
    for (int it = 0; it < K_; it++) {
      float rv = bv; int ri = ln + (bj << 6);
#pragma unroll
      for (int off = 32; off > 0; off >>= 1) {
        float ov = __shfl_xor(rv, off);
        int oi = __shfl_xor(ri, off);
        if (ov < rv || (ov == rv && oi < ri)) { rv = ov; ri = oi; }
      }
      if (ln == 0) op[it] = ri;
      if ((ri & 63) == ln) {
        int slot = ri >> 6;
#pragma unroll
        for (int j = 0; j < 32; j++) v[j] = (j == slot) ? BIGF : v[j];
        bv = v[0]; bj = 0;
#pragma unroll
        for (int j = 1; j < 32; j++) { if (v[j] < bv) { bv = v[j]; bj = j; } }
      }
    }
    __syncthreads();   // rows reused next half
  }
}

// --------------------------------------------------------------------------- id 3
// point_gemm v2: register-blocked.
__global__ __launch_bounds__(256) void point_gemm_kernel(char* base,
                                                         const float* __restrict__ pc)
{
  BASE(base);
  PROG(3);
  int b = blockIdx.x >> 6; int m0 = (blockIdx.x & 63) * 32;
  int t = threadIdx.x;
  __shared__ __align__(16) float actS[64][40];   // [c][pt]
  __shared__ float pcs[3][32];
  for (int i = t; i < 2048; i += 256) {
    int c = i & 63, mm = i >> 6;
    actS[c][mm] = P_XT[((size_t)(b * N_) + m0 + mm) * 64 + c];
  }
  if (t < 96) {
    int c = t >> 5, mm = t & 31;
    pcs[c][mm] = pc[(b * 3 + c) * N_ + m0 + mm];
  }
  __syncthreads();
  size_t bN = (size_t)(b * N_);
  // ---- P: 256 outs ----
  {
    int og = t & 31, pg = t >> 5;
    float acc[8][4];
#pragma unroll
    for (int oi = 0; oi < 8; oi++)
#pragma unroll
      for (int pj = 0; pj < 4; pj++) acc[oi][pj] = 0.0f;
    for (int c = 0; c < 64; c++) {
      float4 a = *(const float4*)&actS[c][pg * 4];
      const float* wr = P_WP2 + c * 256 + og * 8;
      float4 w0 = *(const float4*)wr;
      float4 w1 = *(const float4*)(wr + 4);
      float av[4] = {a.x, a.y, a.z, a.w};
      float wv[8] = {w0.x, w0.y, w0.z, w0.w, w1.x, w1.y, w1.z, w1.w};
#pragma unroll
      for (int oi = 0; oi < 8; oi++)
#pragma unroll
        for (int pj = 0; pj < 4; pj++) acc[oi][pj] += wv[oi] * av[pj];
    }
#pragma unroll
    for (int pj = 0; pj < 4; pj++) {
      float* pp = P_P + (bN + m0 + pg * 4 + pj) * C4_ + og * 8;
      *(float4*)pp = make_float4(acc[0][pj], acc[1][pj], acc[2][pj], acc[3][pj]);
      *(float4*)(pp + 4) = make_float4(acc[4][pj], acc[5][pj], acc[6][pj], acc[7][pj]);
    }
  }
  // ---- Sb: 128 outs ----
  {
    int og = t & 15, pg = t >> 4;
    float acc[8][2];
#pragma unroll
    for (int oi = 0; oi < 8; oi++) { acc[oi][0] = 0.0f; acc[oi][1] = 0.0f; }
    for (int c = 0; c < 64; c++) {
      float a0 = actS[c][pg * 2], a1 = actS[c][pg * 2 + 1];
      const float* wr = P_WS2 + c * 128 + og * 8;
      float4 w0 = *(const float4*)wr;
      float4 w1 = *(const float4*)(wr + 4);
      float wv[8] = {w0.x, w0.y, w0.z, w0.w, w1.x, w1.y, w1.z, w1.w};
#pragma unroll
      for (int oi = 0; oi < 8; oi++) { acc[oi][0] += wv[oi] * a0; acc[oi][1] += wv[oi] * a1; }
    }
#pragma unroll
    for (int pj = 0; pj < 2; pj++) {
      float* sp = P_Sb + (bN + m0 + pg * 2 + pj) * C2_ + og * 8;
      *(float4*)sp = make_float4(acc[0][pj], acc[1][pj], acc[2][pj], acc[3][pj]);
      *(float4*)(sp + 4) = make_float4(acc[4][pj], acc[5][pj], acc[6][pj], acc[7][pj]);
    }
  }
  // ---- U1/V1 + U2/V2 ----
  {
    int o = t & 15, pg = t >> 4;
    float aU[2] = {0.0f, 0.0f}, aV[2] = {0.0f, 0.0f};
    for (int c = 0; c < 64; c++) {
      float wu = P_WU12[c * 16 + o];
      float wv = P_WV12[c * 16 + o];
      float a0 = actS[c][pg * 2], a1 = actS[c][pg * 2 + 1];
      aU[0] += wu * a0; aU[1] += wu * a1;
      aV[0] += wv * a0; aV[1] += wv * a1;
    }
    float u0 = P_WU22[o * 4], u1 = P_WU22[o * 4 + 1], u2w = P_WU22[o * 4 + 2];
    float v0 = P_WV22[o * 4], v1 = P_WV22[o * 4 + 1], v2w = P_WV22[o * 4 + 2];
#pragma unroll
    for (int pj = 0; pj < 2; pj++) {
      int m = m0 + pg * 2 + pj;
      P_U1[((b * 16 + o) << 11) + m] = aU[pj];
      P_V1[(bN + m) * 16 + o] = aV[pj];
      float p0 = pcs[0][pg * 2 + pj], p1 = pcs[1][pg * 2 + pj], p2 = pcs[2][pg * 2 + pj];
      P_U2[((b * 16 + o) << 11) + m] = u0 * p0 + u1 * p1 + u2w * p2;
      P_V2[(bN + m) * 16 + o] = v0 * p0 + v1 * p1 + v2w * p2;
    }
  }
}

// --------------------------------------------------------------------------- id 4
// stats12 v2: grid 1024 (16 n/block).
__global__ __launch_bounds__(256) void stats12_kernel(char* base,
    const float* __restrict__ fea_b, const float* __restrict__ xyz_b)
{
  BASE(base);
  PROG(4);
  int b = blockIdx.x >> 7; int n0 = (blockIdx.x & 127) * 16;
  int t = threadIdx.x; int o = t & 15; int kk = t >> 4;
  float fb = fea_b[o], xb = xyz_b[o];
  float s1 = 0, q1 = 0, s2 = 0, q2 = 0;
  for (int nn = 0; nn < 16; nn++) {
    int n = n0 + nn;
    int m = P_IDX[((b << 11) + n) * K_ + kk] & NMASK;
    float a1 = fb + P_U1[((b * 16 + o) << 11) + n] + P_V1[(((size_t)(b << 11) + m) << 4) + o];
    s1 += a1; q1 += a1 * a1;
    float a2 = xb + P_U2[((b * 16 + o) << 11) + n] + P_V2[(((size_t)(b << 11) + m) << 4) + o];
    s2 += a2; q2 += a2 * a2;
  }
  __shared__ float red[256];
  red[t] = s1; __syncthreads();
  if (t < 16) { float s = 0; for (int k2 = 0; k2 < 16; k2++) s += red[k2 * 16 + t]; atomicAdd(&P_ST[ST_S1S + t], s); }
  __syncthreads();
  red[t] = q1; __syncthreads();
  if (t < 16) { float s = 0; for (int k2 = 0; k2 < 16; k2++) s += red[k2 * 16 + t]; atomicAdd(&P_ST[ST_S1Q + t], s); }
  __syncthreads();
  red[t] = s2; __syncthreads();
  if (t < 16) { float s = 0; for (int k2 = 0; k2 < 16; k2++) s += red[k2 * 16 + t]; atomicAdd(&P_ST[ST_S2S + t], s); }
  __syncthreads();
  red[t] = q2; __syncthreads();
  if (t < 16) { float s = 0; for (int k2 = 0; k2 < 16; k2++) s += red[k2 * 16 + t]; atomicAdd(&P_ST[ST_S2Q + t], s); }
}

// --------------------------------------------------------------------------- finalize (ids vary)
__global__ __launch_bounds__(256) void finalize_bn_kernel(char* base,
                                   const float* __restrict__ g,
                                   const float* __restrict__ be,
                                   int sum_off, int sq_off, int sc_off, int sh_off,
                                   int nch, float inv_cnt, int kid)
{
  BASE(base);
  PROG(kid);
  int i = threadIdx.x;
  if (i < nch) {
    float mu = P_ST[sum_off + i] * inv_cnt;
    float var = fmaxf(P_ST[sq_off + i] * inv_cnt - mu * mu, 0.0f);
    float s = g[i] * rsqrtf(var + EPSv);
    P_ST[sc_off + i] = s; P_ST[sh_off + i] = be[i] - mu * s;
  }
}

// --------------------------------------------------------------------------- id 7
// w1 v2: fused stats3 Gram.
__global__ __launch_bounds__(256) void w1_kernel(char* base,
    const float* __restrict__ fea_b, const float* __restrict__ xyz_b)
{
  BASE(base);
  PROG(7);
  int b = blockIdx.x >> 7; int n0 = (blockIdx.x & 127) * 16;
  int t = threadIdx.x;
  __shared__ int sidx[16 * 16];                 // [nl][k]
  __shared__ __align__(16) float ol[16 * 260];  // [c][e], e = nl*16+k
  {
    int nl = t >> 4, k = t & 15;
    sidx[nl * 16 + k] = P_IDX[((size_t)((b << 11) + n0 + nl)) * 16 + k] & NMASK;
  }
  __syncthreads();
  int c = t >> 4; int nl = t & 15; int n = n0 + nl;
  float u1 = P_U1[((b * 16 + c) << 11) + n];
  float u2 = P_U2[((b * 16 + c) << 11) + n];
  float c1 = fea_b[c] + u1, c2v = xyz_b[c] + u2;
  float s1 = P_ST[ST_B1SC + c], h1 = P_ST[ST_B1SH + c];
  float s2 = P_ST[ST_B2SC + c], h2 = P_ST[ST_B2SH + c];
  float o16[16];
#pragma unroll
  for (int kk = 0; kk < 16; kk++) {
    int m = sidx[nl * 16 + kk];
    float a1 = c1 + P_V1[(((size_t)(b << 11) + m) << 4) + c];
    a1 = lrelu(a1 * s1 + h1);
    float a2 = c2v + P_V2[(((size_t)(b << 11) + m) << 4) + c];
    a2 = lrelu(a2 * s2 + h2);
    o16[kk] = a1 * a2;
  }
  float* wp = P_W1 + ((size_t)(b * 16 + c)) * NK_ + ((size_t)n << 4);
#pragma unroll
  for (int j = 0; j < 4; j++)
    *(float4*)(wp + j * 4) = make_float4(o16[4 * j], o16[4 * j + 1], o16[4 * j + 2], o16[4 * j + 3]);
  float* orow = ol + c * 260 + nl * 16;
#pragma unroll
  for (int j = 0; j < 4; j++)
    *(float4*)(orow + j * 4) = make_float4(o16[4 * j], o16[4 * j + 1], o16[4 * j + 2], o16[4 * j + 3]);
  __syncthreads();
  if (t < 136) {
    int cc1 = 0, rem = t;
    while (rem >= 16 - cc1) { rem -= 16 - cc1; cc1++; }
    int cc2 = cc1 + rem;
    const float* r1 = ol + cc1 * 260;
    const float* r2 = ol + cc2 * 260;
    float acc = 0.0f;
    for (int e = 0; e < 256; e += 4) {
      float4 xv = *(const float4*)(r1 + e);
      float4 yv = *(const float4*)(r2 + e);
      acc += xv.x * yv.x + xv.y * yv.y + xv.z * yv.z + xv.w * yv.w;
    }
    atomicAdd(&P_ST[ST_S3M + t], acc);
  } else if (t < 152) {
    const float* r = ol + (t - 136) * 260;
    float acc = 0.0f;
    for (int e = 0; e < 256; e += 4) {
      float4 xv = *(const float4*)(r + e);
      acc += xv.x + xv.y + xv.z + xv.w;
    }
    atomicAdd(&P_ST[ST_S3V + t - 136], acc);
  }
}

// --------------------------------------------------------------------------- id 9
__global__ __launch_bounds__(256) void finalize_bn3_kernel(char* base,
                                    const float* __restrict__ b1,
                                    const float* __restrict__ g,
                                    const float* __restrict__ be)
{
  BASE(base);
  PROG(9);
  int o = threadIdx.x;
  if (o >= 64) return;
  float A[16];
  for (int c = 0; c < 16; c++) A[c] = P_A12[o * 16 + c];
  float dv = 0.0f;
  for (int c = 0; c < 16; c++) dv += A[c] * P_ST[ST_S3V + c];
  float quad = 0.0f; int p = 0;
  for (int c1 = 0; c1 < 16; c1++)
    for (int c2 = c1; c2 < 16; c2++) {
      float m = P_ST[ST_S3M + p]; p++;
      quad += (c1 == c2 ? 1.0f : 2.0f) * A[c1] * A[c2] * m;
    }
  float bo = b1[o];
  const float inv = 1.0f / 262144.0f;
  float mean = dv * inv + bo;
  float e2 = quad * inv + 2.0f * bo * dv * inv + bo * bo;
  float var = fmaxf(e2 - mean * mean, 0.0f);
  float s = g[o] * rsqrtf(var + EPSv);
  P_ST[ST_B3SC + o] = s; P_ST[ST_B3SH + o] = be[o] - mean * s;
}

// --------------------------------------------------------------------------- id 10
// a4 v3: register-blocked 2-phase + FUSED stats4 reduction in the epilogue.
__global__ __launch_bounds__(256) void a4_kernel(char* base,
                                                 const float* __restrict__ all1_b,
                                                 const float* __restrict__ all2_b)
{
  BASE(base);
  PROG(10);
  int b = blockIdx.x >> 9; int col0 = (blockIdx.x & 511) * 64;
  int t = threadIdx.x;
  __shared__ float sw[16 * 68];
  __shared__ __align__(16) float hS[64 * 68];
  for (int i = t; i < 1024; i += 256) {
    int c = i >> 6, l = i & 63;
    sw[c * 68 + l] = P_W1[((size_t)(b * 16 + c)) * NK_ + col0 + l];
  }
  __syncthreads();
  {
    int col = t & 63; int q = t >> 6;
    float in16[16];
#pragma unroll
    for (int c = 0; c < 16; c++) in16[c] = sw[c * 68 + col];
    for (int oo = 0; oo < 16; oo++) {
      int o = q * 16 + oo;
      const float* wr = P_A12 + o * 16;
      float a = all1_b[o];
#pragma unroll
      for (int c = 0; c < 16; c++) a += wr[c] * in16[c];
      hS[o * 68 + col] = lrelu(a * P_ST[ST_B3SC + o] + P_ST[ST_B3SH + o]);
    }
  }
  __syncthreads();
  int cg = t & 15;            // 4 consecutive cols
  int og = t >> 4;            // 8 consecutive outs
  float acc[8][4];
#pragma unroll
  for (int oi = 0; oi < 8; oi++) {
    float bo = all2_b[og * 8 + oi];
#pragma unroll
    for (int cj = 0; cj < 4; cj++) acc[oi][cj] = bo;
  }
  for (int hk = 0; hk < 64; hk++) {
    float4 hv = *(const float4*)&hS[hk * 68 + cg * 4];
    const float* wr = P_A22 + hk * 128 + og * 8;
    float4 w0 = *(const float4*)wr;
    float4 w1 = *(const float4*)(wr + 4);
    float av[4] = {hv.x, hv.y, hv.z, hv.w};
    float wv[8] = {w0.x, w0.y, w0.z, w0.w, w1.x, w1.y, w1.z, w1.w};
#pragma unroll
    for (int oi = 0; oi < 8; oi++)
#pragma unroll
      for (int cj = 0; cj < 4; cj++)
        acc[oi][cj] += wv[oi] * av[cj];
  }
  int colb = col0 + cg * 4;
  int n = colb >> 4; int kk0 = colb & 15;
  ushort_t* dst = P_A4 + ((size_t)(b * N_) + n) * 2048 + kk0;
  float psum[8], qsum[8];
#pragma unroll
  for (int oi = 0; oi < 8; oi++) {
    int o = og * 8 + oi;
    unsigned lo = (unsigned)f2bf(acc[oi][0]) | ((unsigned)f2bf(acc[oi][1]) << 16);
    unsigned hi = (unsigned)f2bf(acc[oi][2]) | ((unsigned)f2bf(acc[oi][3]) << 16);
    *(uint2*)(dst + o * 16) = make_uint2(lo, hi);
    float r0 = bf2f(lo & 0xffffu), r1 = bf2f(lo >> 16);
    float r2 = bf2f(hi & 0xffffu), r3 = bf2f(hi >> 16);
    psum[oi] = r0 + r1 + r2 + r3;
    qsum[oi] = r0 * r0 + r1 * r1 + r2 * r2 + r3 * r3;
  }
  __syncthreads();            // all phase-2 reads of hS done
  float* redS = hS;
#pragma unroll
  for (int oi = 0; oi < 8; oi++) redS[(og * 8 + oi) * 16 + cg] = psum[oi];
  __syncthreads();
  if (t < 128) {
    float s = 0.0f;
    for (int j = 0; j < 16; j++) s += redS[t * 16 + j];
    atomicAdd(&P_ST[ST_S4S + t], s);
  }
  __syncthreads();
#pragma unroll
  for (int oi = 0; oi < 8; oi++) redS[(og * 8 + oi) * 16 + cg] = qsum[oi];
  __syncthreads();
  if (t < 128) {
    float s = 0.0f;
    for (int j = 0; j < 16; j++) s += redS[t * 16 + j];
    atomicAdd(&P_ST[ST_S4Q + t], s);
  }
}

// --------------------------------------------------------------------------- id 13
// softfuse: softmax(bn4(A4)) fused with M = lrelu(bn5(IT)) * P.
__global__ __launch_bounds__(256) void softfuse_kernel(char* base)
{
  BASE(base);
  PROG(13);
  int rid = blockIdx.x * 256 + threadIdx.x;   // 2,097,152
  int cc = rid & 127; int r = rid >> 7;
  float s = P_ST[ST_B4SC + cc], h = P_ST[ST_B4SH + cc];
  size_t base_off = (size_t)r * 2048 + cc * 16;
  const ushort_t* pa = P_A4 + base_off;
  uint4 u0 = *(const uint4*)pa;
  uint4 u1 = *(const uint4*)(pa + 8);
  unsigned ws[8] = {u0.x, u0.y, u0.z, u0.w, u1.x, u1.y, u1.z, u1.w};
  float v[16];
#pragma unroll
  for (int j = 0; j < 8; j++) {
    union { float f; unsigned u; } lo, hi;
    lo.u = ws[j] << 16; hi.u = ws[j] & 0xffff0000u;
    v[2 * j] = lo.f; v[2 * j + 1] = hi.f;
  }
  float mx = -BIGF;
#pragma unroll
  for (int i = 0; i < 16; i++) {
    float y = lrelu(v[i] * s + h);
    v[i] = y; mx = fmaxf(mx, y);
  }
  float sum = 0.0f;
#pragma unroll
  for (int i = 0; i < 16; i++) { float e = expf(v[i] - mx); v[i] = e; sum += e; }
  float inv = (sum > 0.0f) ? 1.0f / sum : 0.0f;
#pragma unroll
  for (int i = 0; i < 16; i++) v[i] = bf2f((unsigned)f2bf(v[i] * inv));
  float s5a = P_ST[ST_B5SC + cc * 2],     h5a = P_ST[ST_B5SH + cc * 2];
  float s5b = P_ST[ST_B5SC + cc * 2 + 1], h5b = P_ST[ST_B5SH + cc * 2 + 1];
  const ushort_t* itp = P_IT + base_off;
  uint4 i0 = *(const uint4*)itp;
  uint4 i1 = *(const uint4*)(itp + 8);
  unsigned iw[8] = {i0.x, i0.y, i0.z, i0.w, i1.x, i1.y, i1.z, i1.w};
  unsigned mw[8];
#pragma unroll
  for (int j = 0; j < 8; j++) {
    union { float f; unsigned u; } il, ih;
    il.u = iw[j] << 16; ih.u = iw[j] & 0xffff0000u;
    float s5 = (j < 4) ? s5a : s5b;
    float h5 = (j < 4) ? h5a : h5b;
    float m0 = lrelu(il.f * s5 + h5) * v[2 * j];
    float m1 = lrelu(ih.f * s5 + h5) * v[2 * j + 1];
    mw[j] = (unsigned)f2bf(m0) | ((unsigned)f2bf(m1) << 16);
  }
  ushort_t* mp = P_M + base_off;
  *(uint4*)mp = make_uint4(mw[0], mw[1], mw[2], mw[3]);
  *(uint4*)(mp + 8) = make_uint4(mw[4], mw[5], mw[6], mw[7]);
}

// --------------------------------------------------------------------------- id 14
// qgemm v2: register-blocked. Block = 32 points x 256 outs x 9 taps.
__global__ __launch_bounds__(256) void qgemm_kernel(char* base)
{
  BASE(base);
  PROG(14);
  int b = blockIdx.x >> 6; int m0 = (blockIdx.x & 63) * 32;
  int t = threadIdx.x;
  int og = t & 31;            // outs og*8 .. +8
  int pg = t >> 5;            // points pg*4 .. +3
  __shared__ __align__(16) float actS[64][40];   // [c][pt]
  for (int i = t; i < 2048; i += 256) {
    int c = i & 63, mm = i >> 6;
    actS[c][mm] = P_XT[((size_t)(b * N_) + m0 + mm) * 64 + c];
  }
  __syncthreads();
  int m = m0 + pg * 4;
  for (int t9 = 0; t9 < TAP_; t9++) {
    const float* wbase = P_WQ2 + ((size_t)t9 * 64) * 256 + og * 8;
    float acc[8][4];
#pragma unroll
    for (int oi = 0; oi < 8; oi++)
#pragma unroll
      for (int pj = 0; pj < 4; pj++) acc[oi][pj] = 0.0f;
    for (int kc = 0; kc < 64; kc++) {
      float4 a = *(const float4*)&actS[kc][pg * 4];
      const float* wr = wbase + (size_t)kc * 256;
      float4 w0 = *(const float4*)wr;
      float4 w1 = *(const float4*)(wr + 4);
      float av[4] = {a.x, a.y, a.z, a.w};
      float wv[8] = {w0.x, w0.y, w0.z, w0.w, w1.x, w1.y, w1.z, w1.w};
#pragma unroll
      for (int oi = 0; oi < 8; oi++)
#pragma unroll
        for (int pj = 0; pj < 4; pj++)
          acc[oi][pj] += wv[oi] * av[pj];
    }
#pragma unroll
    for (int pj = 0; pj < 4; pj++) {
      ushort_t* qp = P_QB + ((size_t)(b * N_ + m + pj) * TAP_ + t9) * C4_ + og * 8;
      unsigned u0 = (unsigned)f2bf(acc[0][pj]) | ((unsigned)f2bf(acc[1][pj]) << 16);
      unsigned u1 = (unsigned)f2bf(acc[2][pj]) | ((unsigned)f2bf(acc[3][pj]) << 16);
      unsigned u2 = (unsigned)f2bf(acc[4][pj]) | ((unsigned)f2bf(acc[5][pj]) << 16);
      unsigned u3 = (unsigned)f2bf(acc[6][pj]) | ((unsigned)f2bf(acc[7][pj]) << 16);
      *(uint4*)qp = make_uint4(u0, u1, u2, u3);
    }
  }
}

// --------------------------------------------------------------------------- id 15
__global__ __launch_bounds__(256) void inte_fused_kernel(char* base,
                                                         const float* __restrict__ inte_b)
{
  BASE(base);
  PROG(15);
  int b = blockIdx.x >> 9; int n0 = (blockIdx.x & 511) * 4;
  int t = threadIdx.x; int o = t;
  __shared__ int sidx[4][16];
  if (t < 64) sidx[t >> 4][t & 15] = P_IDX[((size_t)(b * N_) + n0 + (t >> 4)) * K_ + (t & 15)] & NMASK;
  __syncthreads();
  float bias = inte_b[o];
  float ssum = 0.0f, ssq = 0.0f;
  for (int nn = 0; nn < 4; nn++) {
    int n = n0 + nn;
    float bse = bias + P_P[((size_t)(b * N_) + n) * C4_ + o];
    float acc[8];
#pragma unroll
    for (int j = 0; j < 8; j++) acc[j] = bse;
    for (int p = 0; p < 16; p++) {
      const ushort_t* qr = P_QB + (size_t)(b * N_ + sidx[nn][p]) * TAP_ * C4_ + o;
#pragma unroll
      for (int tt = 0; tt < TAP_; tt++) {
        int j = p - tt;
        if (j >= 0 && j < 8) acc[j] += bf2f(((unsigned)qr[tt * C4_]) << 16 >> 16 << 16 >> 16);
      }
    }
    ushort_t* ip = P_IT + ((size_t)(b * N_) + n) * 2048 + o * 8;
#pragma unroll
    for (int j = 0; j < 8; j++) { float v = acc[j]; ip[j] = f2bf(v); ssum += v; ssq += v * v; }
  }
  atomicAdd(&P_ST[ST_S5S + o], ssum);
  atomicAdd(&P_ST[ST_S5Q + o], ssq);
}

// --------------------------------------------------------------------------- id 17
// final conv v6 (best measured, 248us): 2-way k-split, grid 512.
__global__ __launch_bounds__(256) void final_conv_kernel(char* base)
{
  BASE(base);
  PROG(17);
  int ks = blockIdx.x & 1;
  int tile = (blockIdx.x >> 1) & 31; int b = blockIdx.x >> 6;
  int n0 = tile * 64;
  int t = threadIdx.x;
  int cg4 = (t & 15) * 4;
  int obase = (t >> 4) * 8;
  __shared__ __align__(16) float tileS[128 * 68];
  __shared__ int sidxT[16 * 64];        // [p][cl]
  for (int i = t; i < 1024; i += 256) {
    int cl = i & 63, p = i >> 6;
    sidxT[p * 64 + cl] = P_IDX[((size_t)(b * N_) + n0 + cl) * K_ + p] & NMASK;
  }
  float acc[32];
#pragma unroll
  for (int i = 0; i < 32; i++) acc[i] = 0.0f;
  int kbeg = ks * 1536;
  for (int k0 = kbeg; k0 < kbeg + 1536; k0 += 128) {
    __syncthreads();
    if (k0 < 1024) {
      int c0 = k0 >> 4;
      int cl = t & 63; int pg = t >> 6;
      for (int pp = 0; pp < 4; pp++) {
        int p = pg * 4 + pp;
        int m = sidxT[p * 64 + cl];
        const float* xp = P_XT + ((size_t)(b * N_) + m) * 64 + c0;
        float4 v0 = *(const float4*)xp;
        float4 v1 = *(const float4*)(xp + 4);
        tileS[(0 * 16 + p) * 68 + cl] = v0.x;
        tileS[(1 * 16 + p) * 68 + cl] = v0.y;
        tileS[(2 * 16 + p) * 68 + cl] = v0.z;
        tileS[(3 * 16 + p) * 68 + cl] = v0.w;
        tileS[(4 * 16 + p) * 68 + cl] = v1.x;
        tileS[(5 * 16 + p) * 68 + cl] = v1.y;
        tileS[(6 * 16 + p) * 68 + cl] = v1.z;
        tileS[(7 * 16 + p) * 68 + cl] = v1.w;
      }
    } else {
      int cl = t & 63; int kg = t >> 6;           // 4 groups x 32 k
      size_t rb = ((size_t)(b * N_) + n0 + cl) * 2048 + (size_t)(k0 - 1024) + kg * 32;
      const ushort_t* mp = P_M + rb;
      for (int j8 = 0; j8 < 4; j8++) {
        uint4 u = *(const uint4*)(mp + j8 * 8);
        unsigned ws[4] = {u.x, u.y, u.z, u.w};
#pragma unroll
        for (int q = 0; q < 4; q++) {
          union { float f; unsigned uu; } lo, hi;
          lo.uu = ws[q] << 16; hi.uu = ws[q] & 0xffff0000u;
          int kc = kg * 32 + j8 * 8 + q * 2;
          tileS[kc * 68 + cl] = lo.f;
          tileS[(kc + 1) * 68 + cl] = hi.f;
        }
      }
    }
    __syncthreads();
    for (int kc = 0; kc < 128; kc++) {
      float4 a = *(const float4*)&tileS[kc * 68 + cg4];
      const float* wr = P_WC2 + (size_t)(k0 + kc) * C2_ + obase;
      float4 w0 = *(const float4*)wr;
      float4 w1 = *(const float4*)(wr + 4);
      float av[4] = {a.x, a.y, a.z, a.w};
      float wv[8] = {w0.x, w0.y, w0.z, w0.w, w1.x, w1.y, w1.z, w1.w};
#pragma unroll
      for (int oi = 0; oi < 8; oi++)
#pragma unroll
        for (int cj = 0; cj < 4; cj++)
          acc[oi * 4 + cj] += wv[oi] * av[cj];
    }
  }
#pragma unroll
  for (int cj = 0; cj < 4; cj++) {
    float* op = P_PART + ((size_t)ks * B_ * N_ + (size_t)b * N_ + n0 + cg4 + cj) * C2_ + obase;
    *(float4*)op = make_float4(acc[0 * 4 + cj], acc[1 * 4 + cj], acc[2 * 4 + cj], acc[3 * 4 + cj]);
    *(float4*)(op + 4) = make_float4(acc[4 * 4 + cj], acc[5 * 4 + cj], acc[6 * 4 + cj], acc[7 * 4 + cj]);
  }
}

// --------------------------------------------------------------------------- id 18
// reduce_stats v2: grid 512. 32 rows/block.
__global__ __launch_bounds__(256) void reduce_stats_kernel(char* base,
                                                           const float* __restrict__ c2_b)
{
  BASE(base);
  PROG(18);
  int r0 = blockIdx.x * 32;    // grid 512
  int t = threadIdx.x; int o = t & 127; int h = t >> 7;
  const size_t STRIDE = (size_t)B_ * N_ * C2_;
  float cb = c2_b[o];
  float s = 0, q = 0;
  for (int r = r0 + h; r < r0 + 32; r += 2) {
    size_t off = (size_t)r * C2_ + o;
    float v = cb + P_Sb[off] + P_PART[off] + P_PART[STRIDE + off];
    P_OUT2[off] = v;
    s += v; q += v * v;
  }
  __shared__ float rs[256], rq[256];
  rs[t] = s; rq[t] = q; __syncthreads();
  if (t < 128) {
    atomicAdd(&P_ST[ST_S6S + o], rs[t] + rs[t + 128]);
    atomicAdd(&P_ST[ST_S6Q + o], rq[t] + rq[t + 128]);
  }
}

// --------------------------------------------------------------------------- id 20
// output v2: LDS-tiled.
__global__ __launch_bounds__(256) void output_kernel(char* base, float* __restrict__ out)
{
  BASE(base);
  PROG(20);
  int b = blockIdx.x >> 6; int n0 = (blockIdx.x & 63) * 32;
  int t = threadIdx.x;
  __shared__ float tile[32 * 133];
  for (int i = t; i < 4096; i += 256) {
    int o = i & 127, nl = i >> 7;
    float v = P_OUT2[((size_t)(b * N_) + n0 + nl) * C2_ + o];
    v = v * P_ST[ST_B6SC + o] + P_ST[ST_B6SH + o];
    tile[nl * 133 + o] = fmaxf(v, 0.0f);
  }
  __syncthreads();
  for (int i = t; i < 4096; i += 256) {
    int nl = i & 31, o = i >> 5;
    out[(((size_t)b * 64 + (o >> 1)) * 2 + (o & 1)) * 2048 + n0 + nl] = tile[nl * 133 + o];
  }
}

// --------------------------------------------------------------------------- diagnostics
__global__ void diag_kernel(char* base, float* __restrict__ out)
{
  BASE(base);
  const int expctd[22] = {1, 2253, 2048, 512, 1024, 1, 1, 1024, 256, 1, 4096,
                          0, 1, 8192, 512, 4096, 1, 512, 512, 1, 512, 0};
  int t = threadIdx.x;
  int bad = 99;
  if (t < 22 && P_PROG[t] != expctd[t]) bad = t;
#pragma unroll
  for (int off = 32; off > 0; off >>= 1) {
    int ob = __shfl_xor(bad, off);
    if (ob < bad) bad = ob;
  }
  if (t == 0 && bad != 99) out[0] = 100.0f + 10.0f * (float)bad;
}

__global__ void code_kernel(float* __restrict__ out, float code)
{
  if (threadIdx.x == 0 && blockIdx.x == 0) out[0] = code;
}

// ---------------------------------------------------------------------------
extern "C" void kernel_launch(void* const* d_in, const int* in_sizes, int n_in,
                              void* d_out, int out_size, void* d_ws, size_t ws_size,
                              hipStream_t stream) {
  const float* x      = (const float*)d_in[0];
  const float* pc     = (const float*)d_in[1];
  const float* fea_w  = (const float*)d_in[2];
  const float* fea_b  = (const float*)d_in[3];
  const float* fea_g  = (const float*)d_in[4];
  const float* fea_be = (const float*)d_in[5];
  const float* xyz_w  = (const float*)d_in[6];
  const float* xyz_b  = (const float*)d_in[7];
  const float* xyz_g  = (const float*)d_in[8];
  const float* xyz_be = (const float*)d_in[9];
  const float* all1_w = (const float*)d_in[10];
  const float* all1_b = (const float*)d_in[11];
  const float* all1_g = (const float*)d_in[12];
  const float* all1_be= (const float*)d_in[13];
  const float* all2_w = (const float*)d_in[14];
  const float* all2_b = (const float*)d_in[15];
  const float* all2_g = (const float*)d_in[16];
  const float* all2_be= (const float*)d_in[17];
  const float* inte_w = (const float*)d_in[18];
  const float* inte_b = (const float*)d_in[19];
  const float* inte_g = (const float*)d_in[20];
  const float* inte_be= (const float*)d_in[21];
  const float* c2_w   = (const float*)d_in[22];
  const float* c2_b   = (const float*)d_in[23];
  const float* c2_g   = (const float*)d_in[24];
  const float* c2_be  = (const float*)d_in[25];
  float* out = (float*)d_out;
  (void)in_sizes; (void)n_in; (void)out_size; (void)d_ws; (void)ws_size;

  if (g_pool_mem == nullptr) {
    code_kernel<<<1, 64, 0, stream>>>(out, 500.0f);
    return;
  }
  char* base = g_pool_mem;

  zero_kernel<<<1, 256, 0, stream>>>(base);
  xt_kernel<<<256, 256, 0, stream>>>(base, x);
  prep_kernel<<<2253, 256, 0, stream>>>(base, fea_w, xyz_w, inte_w, c2_w, all1_w, all2_w);
  knn_kernel<<<2048, 256, 0, stream>>>(base, x);
  point_gemm_kernel<<<512, 256, 0, stream>>>(base, pc);
  stats12_kernel<<<1024, 256, 0, stream>>>(base, fea_b, xyz_b);
  finalize_bn_kernel<<<1, 256, 0, stream>>>(base, fea_g, fea_be, ST_S1S, ST_S1Q, ST_B1SC, ST_B1SH, 16, 1.0f / 262144.0f, 5);
  finalize_bn_kernel<<<1, 256, 0, stream>>>(base, xyz_g, xyz_be, ST_S2S, ST_S2Q, ST_B2SC, ST_B2SH, 16, 1.0f / 262144.0f, 6);
  w1_kernel<<<1024, 256, 0, stream>>>(base, fea_b, xyz_b);
  finalize_bn3_kernel<<<1, 256, 0, stream>>>(base, all1_b, all1_g, all1_be);
  a4_kernel<<<4096, 256, 0, stream>>>(base, all1_b, all2_b);
  finalize_bn_kernel<<<1, 256, 0, stream>>>(base, all2_g, all2_be, ST_S4S, ST_S4Q, ST_B4SC, ST_B4SH, 128, 1.0f / 262144.0f, 12);
  qgemm_kernel<<<512, 256, 0, stream>>>(base);
  inte_fused_kernel<<<4096, 256, 0, stream>>>(base, inte_b);
  finalize_bn_kernel<<<1, 256, 0, stream>>>(base, inte_g, inte_be, ST_S5S, ST_S5Q, ST_B5SC, ST_B5SH, 256, 1.0f / 131072.0f, 16);
  softfuse_kernel<<<8192, 256, 0, stream>>>(base);
  final_conv_kernel<<<512, 256, 0, stream>>>(base);
  reduce_stats_kernel<<<512, 256, 0, stream>>>(base, c2_b);
  finalize_bn_kernel<<<1, 256, 0, stream>>>(base, c2_g, c2_be, ST_S6S, ST_S6Q, ST_B6SC, ST_B6SH, 128, 1.0f / 16384.0f, 19);
  output_kernel<<<512, 256, 0, stream>>>(base, out);
  diag_kernel<<<1, 64, 0, stream>>>(base, out);
}

// Round 14
// 1226.436 us; speedup vs baseline: 1.0246x; 1.0246x over previous
//
#include <hip/hip_runtime.h>
#include <math.h>

typedef unsigned short ushort_t;

#define B_   8
#define N_   2048
#define K_   16
#define C2_  128
#define C4_  256
#define KH_  8
#define TAP_ 9
#define NK_  32768
#define EPSv 1e-5f
#define BIGF 3.0e38f
#define NMASK 2047

constexpr size_t AL(size_t x) { return (x + 255) & ~(size_t)255; }
constexpr size_t OFF_XT   = 0;                                                  // f32 [B][N][64]
constexpr size_t OFF_IDX  = OFF_XT  + AL(4ull * B_ * N_ * 64);
constexpr size_t OFF_U1   = OFF_IDX + AL(4ull * B_ * N_ * K_);
constexpr size_t OFF_V1   = OFF_U1  + AL(4ull * B_ * 16 * N_);
constexpr size_t OFF_U2   = OFF_V1  + AL(4ull * B_ * N_ * 16);
constexpr size_t OFF_V2   = OFF_U2  + AL(4ull * B_ * 16 * N_);
constexpr size_t OFF_S    = OFF_V2  + AL(4ull * B_ * N_ * 16);                  // f32 [B][N][128]
constexpr size_t OFF_P    = OFF_S   + AL(4ull * B_ * N_ * C2_);                 // f32 [B][N][256]
constexpr size_t OFF_W1   = OFF_P   + AL(4ull * B_ * N_ * C4_);                 // f32 [B][16][NK]
constexpr size_t OFF_QB   = OFF_W1  + AL(4ull * B_ * 16 * NK_);                 // bf16 [B][N][9][256]
constexpr size_t OFF_ITB  = OFF_QB  + AL(2ull * (size_t)B_ * N_ * TAP_ * C4_);  // bf16 [B][N][2048]
constexpr size_t OFF_A4B  = OFF_ITB + AL(2ull * (size_t)B_ * N_ * 2048);        // bf16 [B][N][2048]
constexpr size_t OFF_M    = OFF_A4B + AL(2ull * (size_t)B_ * N_ * 2048);        // bf16 [B][N][2048]
constexpr size_t OFF_PART = OFF_M   + AL(2ull * (size_t)B_ * N_ * 2048);        // f32 [2][B][N][128]
constexpr size_t OFF_OUT2 = OFF_PART+ AL(4ull * 2 * (size_t)B_ * N_ * C2_);     // f32 [B][N][128]
constexpr size_t OFF_WQ2  = OFF_OUT2+ AL(4ull * B_ * N_ * C2_);
constexpr size_t OFF_WC2  = OFF_WQ2 + AL(4ull * TAP_ * C4_ * 64);
constexpr size_t OFF_WP2  = OFF_WC2 + AL(4ull * 3072 * C2_);
constexpr size_t OFF_WS2  = OFF_WP2 + AL(4ull * C4_ * 64);
constexpr size_t OFF_WU12 = OFF_WS2 + AL(4ull * C2_ * 64);
constexpr size_t OFF_WV12 = OFF_WU12+ AL(4ull * 16 * 64);
constexpr size_t OFF_WU22 = OFF_WV12+ AL(4ull * 16 * 64);
constexpr size_t OFF_WV22 = OFF_WU22+ AL(4ull * 64);
constexpr size_t OFF_A12  = OFF_WV22+ AL(4ull * 64);
constexpr size_t OFF_A22  = OFF_A12 + AL(4ull * 64 * 16);
constexpr size_t OFF_ST   = OFF_A22 + AL(4ull * C2_ * 64);
constexpr size_t OFF_PROG = OFF_ST  + AL(4ull * 4096);
constexpr size_t POOL_SZ  = OFF_PROG + AL(4ull * 64);

static char* g_pool_mem = nullptr;
struct PoolInit {
  PoolInit() { if (hipMalloc((void**)&g_pool_mem, POOL_SZ) != hipSuccess) g_pool_mem = nullptr; }
};
static PoolInit g_pool_init;

// g_st float offsets
#define ST_S1S 0
#define ST_S1Q 16
#define ST_S2S 32
#define ST_S2Q 48
#define ST_S5S 64
#define ST_S5Q 320
#define ST_S4S 576
#define ST_S4Q 704
#define ST_S6S 832
#define ST_S6Q 960
#define ST_B1SC 1088
#define ST_B1SH 1104
#define ST_B2SC 1120
#define ST_B2SH 1136
#define ST_B3SC 1152
#define ST_B3SH 1216
#define ST_B4SC 1280
#define ST_B4SH 1408
#define ST_B5SC 1536
#define ST_B5SH 1792
#define ST_B6SC 2048
#define ST_B6SH 2176
#define ST_S3M  2304
#define ST_S3V  2440

#define BASE(b)  char* bb = (b)
#define P_XT   ((float*)(bb + OFF_XT))
#define P_IDX  ((int*)(bb + OFF_IDX))
#define P_U1   ((float*)(bb + OFF_U1))
#define P_V1   ((float*)(bb + OFF_V1))
#define P_U2   ((float*)(bb + OFF_U2))
#define P_V2   ((float*)(bb + OFF_V2))
#define P_Sb   ((float*)(bb + OFF_S))
#define P_P    ((float*)(bb + OFF_P))
#define P_W1   ((float*)(bb + OFF_W1))
#define P_QB   ((ushort_t*)(bb + OFF_QB))
#define P_IT   ((ushort_t*)(bb + OFF_ITB))
#define P_A4   ((ushort_t*)(bb + OFF_A4B))
#define P_M    ((ushort_t*)(bb + OFF_M))
#define P_PART ((float*)(bb + OFF_PART))
#define P_OUT2 ((float*)(bb + OFF_OUT2))
#define P_WQ2  ((float*)(bb + OFF_WQ2))
#define P_WC2  ((float*)(bb + OFF_WC2))
#define P_WP2  ((float*)(bb + OFF_WP2))
#define P_WS2  ((float*)(bb + OFF_WS2))
#define P_WU12 ((float*)(bb + OFF_WU12))
#define P_WV12 ((float*)(bb + OFF_WV12))
#define P_WU22 ((float*)(bb + OFF_WU22))
#define P_WV22 ((float*)(bb + OFF_WV22))
#define P_A12  ((float*)(bb + OFF_A12))
#define P_A22  ((float*)(bb + OFF_A22))
#define P_ST   ((float*)(bb + OFF_ST))
#define P_PROG ((int*)(bb + OFF_PROG))

#define PROG(id) do { if (threadIdx.x == 0) atomicAdd(&P_PROG[(id)], 1); } while (0)

static __device__ __forceinline__ float lrelu(float x) { return x >= 0.0f ? x : 0.01f * x; }
static __device__ __forceinline__ float bf2f(unsigned h) {
  union { float f; unsigned u; } v; v.u = h << 16; return v.f;
}
static __device__ __forceinline__ ushort_t f2bf(float f) {
  union { float f; unsigned u; } v; v.f = f;
  unsigned r = v.u + 0x7fffu + ((v.u >> 16) & 1u);
  return (ushort_t)(r >> 16);
}

// --------------------------------------------------------------------------- id 0
__global__ __launch_bounds__(256) void zero_kernel(char* base)
{
  BASE(base);
  for (int i = threadIdx.x; i < 4096; i += 256) P_ST[i] = 0.0f;
  for (int i = threadIdx.x; i < 64; i += 256) P_PROG[i] = 0;
  __syncthreads();
  if (threadIdx.x == 0) P_PROG[0] = 1;
}

// --------------------------------------------------------------------------- id 8
// xt v2: LDS-tiled transpose (coalesced both sides, conflict-free [c][65]).
__global__ __launch_bounds__(256) void xt_kernel(char* base, const float* __restrict__ x)
{
  BASE(base);
  PROG(8);
  int b = blockIdx.x >> 5; int m0 = (blockIdx.x & 31) * 64;
  int t = threadIdx.x;
  __shared__ float tile[64 * 65];
  for (int i = t; i < 4096; i += 256) {
    int ml = i & 63, c = i >> 6;
    tile[c * 65 + ml] = x[((size_t)(b * 64 + c)) * N_ + m0 + ml];
  }
  __syncthreads();
  for (int i = t; i < 4096; i += 256) {
    int c = i & 63, ml = i >> 6;
    P_XT[((size_t)(b * N_) + m0 + ml) * 64 + c] = tile[c * 65 + ml];
  }
}

// --------------------------------------------------------------------------- id 1
// prep v3: weights only. 576640 elements, grid 2253.
__global__ __launch_bounds__(256) void prep_kernel(char* base,
    const float* __restrict__ fea_w,
    const float* __restrict__ xyz_w, const float* __restrict__ inte_w,
    const float* __restrict__ c2_w, const float* __restrict__ all1_w,
    const float* __restrict__ all2_w)
{
  BASE(base);
  PROG(1);
  int i = blockIdx.x * 256 + threadIdx.x;
  if (i < 1024) { int o = i & 15, c = i >> 4;    // WU12T[c][o]
    P_WU12[i] = fea_w[o * 128 + c] - fea_w[o * 128 + 64 + c]; return; }
  i -= 1024;
  if (i < 1024) { int o = i & 15, c = i >> 4;    // WV12T[c][o]
    P_WV12[i] = fea_w[o * 128 + 64 + c]; return; }
  i -= 1024;
  if (i < 64) { int c = i & 3, o = i >> 2;
    P_WU22[i] = (c < 3) ? (xyz_w[o * 6 + c] - xyz_w[o * 6 + 3 + c]) : 0.0f; return; }
  i -= 64;
  if (i < 64) { int c = i & 3, o = i >> 2;
    P_WV22[i] = (c < 3) ? xyz_w[o * 6 + 3 + c] : 0.0f; return; }
  i -= 64;
  if (i < 16384) { int o = i & 255, c = i >> 8;  // WP2T[c][o]
    float s = 0.0f;
    for (int t = 0; t < TAP_; t++)
      s += inte_w[(o * 128 + c) * TAP_ + t] - inte_w[(o * 128 + 64 + c) * TAP_ + t];
    P_WP2[i] = s; return; }
  i -= 16384;
  if (i < 147456) {                       // WQ2T[t9][c][o]  (o fastest)
    int o = i & 255; int tc = i >> 8; int c = tc & 63; int tt = tc >> 6;
    P_WQ2[i] = inte_w[(o * 128 + 64 + c) * TAP_ + tt]; return; }
  i -= 147456;
  if (i < 8192) { int o = i & 127, c = i >> 7;   // WS2T[c][o]
    float s = 0.0f;
    for (int p = 0; p < 16; p++)
      s += c2_w[(o * 128 + c) * 32 + p] - c2_w[(o * 128 + 64 + c) * 32 + p];
    P_WS2[i] = s; return; }
  i -= 8192;
  if (i < 393216) { int o = i & 127; int k = i >> 7; float v;
    if (k < 1024) { int c = k >> 4, p = k & 15; v = c2_w[(o * 128 + 64 + c) * 32 + p]; }
    else { int kr = k - 1024; int cc = kr >> 4, kk = kr & 15; v = c2_w[(o * 128 + cc) * 32 + 16 + kk]; }
    P_WC2[i] = v; return; }
  i -= 393216;
  if (i < 1024) { int c = i & 15, o = i >> 4; P_A12[i] = all1_w[o * 16 + c]; return; }
  i -= 1024;
  if (i < 8192) {                         // A22T[c][o]  (o fastest)
    int o = i & 127, c = i >> 7; P_A22[i] = all2_w[o * 64 + c]; return; }
}

// --------------------------------------------------------------------------- id 2
// knn v3 (reverted from v4): coalesced channel-major distance phase +
// register-resident selection. 4 queries/block, grid 4096.
__global__ __launch_bounds__(256) void knn_kernel(char* base,
                                                  const float* __restrict__ x)
{
  BASE(base);
  PROG(2);
  int b = blockIdx.x >> 9; int n0 = (blockIdx.x & 511) * 4;
  int t = threadIdx.x;
  __shared__ float sdist[4][N_];
  __shared__ __align__(16) float xn[4][64];
  __shared__ float sxn[4];
  {
    int nn = t >> 6, c = t & 63;
    xn[nn][c] = P_XT[((size_t)(b * N_) + n0 + nn) * 64 + c];
  }
  __syncthreads();
  if (t < 4) {
    float s = 0.0f;
    for (int c = 0; c < 64; c++) { float v = xn[t][c]; s += v * v; }
    sxn[t] = s;
  }
  __syncthreads();
  float dd[32]; float xs[8];
#pragma unroll
  for (int i = 0; i < 32; i++) dd[i] = 0.0f;
#pragma unroll
  for (int i = 0; i < 8; i++) xs[i] = 0.0f;
  const float* xbase = x + (size_t)b * 64 * N_ + (t << 3);   // channel-major rows
  for (int cq = 0; cq < 16; cq++) {
    float4 a0 = *(const float4*)&xn[0][cq * 4];
    float4 a1 = *(const float4*)&xn[1][cq * 4];
    float4 a2 = *(const float4*)&xn[2][cq * 4];
    float4 a3 = *(const float4*)&xn[3][cq * 4];
    float p[4][8];
#pragma unroll
    for (int cc = 0; cc < 4; cc++) {
      const float* xr = xbase + (size_t)(cq * 4 + cc) * N_;
      float4 u = *(const float4*)xr;
      float4 v = *(const float4*)(xr + 4);
      p[cc][0] = u.x; p[cc][1] = u.y; p[cc][2] = u.z; p[cc][3] = u.w;
      p[cc][4] = v.x; p[cc][5] = v.y; p[cc][6] = v.z; p[cc][7] = v.w;
    }
#pragma unroll
    for (int j = 0; j < 8; j++) {
      float x0 = p[0][j], x1 = p[1][j], x2 = p[2][j], x3 = p[3][j];
      xs[j] += x0 * x0 + x1 * x1 + x2 * x2 + x3 * x3;
      dd[0 * 8 + j] += a0.x * x0 + a0.y * x1 + a0.z * x2 + a0.w * x3;
      dd[1 * 8 + j] += a1.x * x0 + a1.y * x1 + a1.z * x2 + a1.w * x3;
      dd[2 * 8 + j] += a2.x * x0 + a2.y * x1 + a2.z * x2 + a2.w * x3;
      dd[3 * 8 + j] += a3.x * x0 + a3.y * x1 + a3.z * x2 + a3.w * x3;
    }
  }
  float sx0 = sxn[0], sx1 = sxn[1], sx2 = sxn[2], sx3 = sxn[3];
  int mb = t << 3;
#pragma unroll
  for (int j = 0; j < 8; j++) {
    int m = mb + j;
    float d0 = -2.0f * dd[0 * 8 + j] + sx0 + xs[j];
    float d1 = -2.0f * dd[1 * 8 + j] + sx1 + xs[j];
    float d2 = -2.0f * dd[2 * 8 + j] + sx2 + xs[j];
    float d3 = -2.0f * dd[3 * 8 + j] + sx3 + xs[j];
    sdist[0][m] = (m == n0 + 0) ? BIGF : d0;
    sdist[1][m] = (m == n0 + 1) ? BIGF : d1;
    sdist[2][m] = (m == n0 + 2) ? BIGF : d2;
    sdist[3][m] = (m == n0 + 3) ? BIGF : d3;
  }
  __syncthreads();
  int ln = t & 63; int wv = t >> 6;
  float v[32];
#pragma unroll
  for (int j = 0; j < 32; j++) v[j] = sdist[wv][ln + j * 64];
  float bv = v[0]; int bj = 0;
#pragma unroll
  for (int j = 1; j < 32; j++) { if (v[j] < bv) { bv = v[j]; bj = j; } }
  int* op = P_IDX + ((size_t)(b * N_) + n0 + wv) * K_;
  for (int it = 0; it < K_; it++) {
    float rv = bv; int ri = ln + (bj << 6);
#pragma unroll
    for (int off = 32; off > 0; off >>= 1) {
      float ov = __shfl_xor(rv, off);
      int oi = __shfl_xor(ri, off);
      if (ov < rv || (ov == rv && oi < ri)) { rv = ov; ri = oi; }
    }
    if (ln == 0) op[it] = ri;
    if ((ri & 63) == ln) {
      int slot = ri >> 6;
#pragma unroll
      for (int j = 0; j < 32; j++) v[j] = (j == slot) ? BIGF : v[j];
      bv = v[0]; bj = 0;
#pragma unroll
      for (int j = 1; j < 32; j++) { if (v[j] < bv) { bv = v[j]; bj = j; } }
    }
  }
}

// --------------------------------------------------------------------------- id 3
// point_gemm v2: register-blocked.
__global__ __launch_bounds__(256) void point_gemm_kernel(char* base,
                                                         const float* __restrict__ pc)
{
  BASE(base);
  PROG(3);
  int b = blockIdx.x >> 6; int m0 = (blockIdx.x & 63) * 32;
  int t = threadIdx.x;
  __shared__ __align__(16) float actS[64][40];   // [c][pt]
  __shared__ float pcs[3][32];
  for (int i = t; i < 2048; i += 256) {
    int c = i & 63, mm = i >> 6;
    actS[c][mm] = P_XT[((size_t)(b * N_) + m0 + mm) * 64 + c];
  }
  if (t < 96) {
    int c = t >> 5, mm = t & 31;
    pcs[c][mm] = pc[(b * 3 + c) * N_ + m0 + mm];
  }
  __syncthreads();
  size_t bN = (size_t)(b * N_);
  // ---- P: 256 outs ----
  {
    int og = t & 31, pg = t >> 5;
    float acc[8][4];
#pragma unroll
    for (int oi = 0; oi < 8; oi++)
#pragma unroll
      for (int pj = 0; pj < 4; pj++) acc[oi][pj] = 0.0f;
    for (int c = 0; c < 64; c++) {
      float4 a = *(const float4*)&actS[c][pg * 4];
      const float* wr = P_WP2 + c * 256 + og * 8;
      float4 w0 = *(const float4*)wr;
      float4 w1 = *(const float4*)(wr + 4);
      float av[4] = {a.x, a.y, a.z, a.w};
      float wv[8] = {w0.x, w0.y, w0.z, w0.w, w1.x, w1.y, w1.z, w1.w};
#pragma unroll
      for (int oi = 0; oi < 8; oi++)
#pragma unroll
        for (int pj = 0; pj < 4; pj++) acc[oi][pj] += wv[oi] * av[pj];
    }
#pragma unroll
    for (int pj = 0; pj < 4; pj++) {
      float* pp = P_P + (bN + m0 + pg * 4 + pj) * C4_ + og * 8;
      *(float4*)pp = make_float4(acc[0][pj], acc[1][pj], acc[2][pj], acc[3][pj]);
      *(float4*)(pp + 4) = make_float4(acc[4][pj], acc[5][pj], acc[6][pj], acc[7][pj]);
    }
  }
  // ---- Sb: 128 outs ----
  {
    int og = t & 15, pg = t >> 4;
    float acc[8][2];
#pragma unroll
    for (int oi = 0; oi < 8; oi++) { acc[oi][0] = 0.0f; acc[oi][1] = 0.0f; }
    for (int c = 0; c < 64; c++) {
      float a0 = actS[c][pg * 2], a1 = actS[c][pg * 2 + 1];
      const float* wr = P_WS2 + c * 128 + og * 8;
      float4 w0 = *(const float4*)wr;
      float4 w1 = *(const float4*)(wr + 4);
      float wv[8] = {w0.x, w0.y, w0.z, w0.w, w1.x, w1.y, w1.z, w1.w};
#pragma unroll
      for (int oi = 0; oi < 8; oi++) { acc[oi][0] += wv[oi] * a0; acc[oi][1] += wv[oi] * a1; }
    }
#pragma unroll
    for (int pj = 0; pj < 2; pj++) {
      float* sp = P_Sb + (bN + m0 + pg * 2 + pj) * C2_ + og * 8;
      *(float4*)sp = make_float4(acc[0][pj], acc[1][pj], acc[2][pj], acc[3][pj]);
      *(float4*)(sp + 4) = make_float4(acc[4][pj], acc[5][pj], acc[6][pj], acc[7][pj]);
    }
  }
  // ---- U1/V1 + U2/V2 ----
  {
    int o = t & 15, pg = t >> 4;
    float aU[2] = {0.0f, 0.0f}, aV[2] = {0.0f, 0.0f};
    for (int c = 0; c < 64; c++) {
      float wu = P_WU12[c * 16 + o];
      float wv = P_WV12[c * 16 + o];
      float a0 = actS[c][pg * 2], a1 = actS[c][pg * 2 + 1];
      aU[0] += wu * a0; aU[1] += wu * a1;
      aV[0] += wv * a0; aV[1] += wv * a1;
    }
    float u0 = P_WU22[o * 4], u1 = P_WU22[o * 4 + 1], u2w = P_WU22[o * 4 + 2];
    float v0 = P_WV22[o * 4], v1 = P_WV22[o * 4 + 1], v2w = P_WV22[o * 4 + 2];
#pragma unroll
    for (int pj = 0; pj < 2; pj++) {
      int m = m0 + pg * 2 + pj;
      P_U1[((b * 16 + o) << 11) + m] = aU[pj];
      P_V1[(bN + m) * 16 + o] = aV[pj];
      float p0 = pcs[0][pg * 2 + pj], p1 = pcs[1][pg * 2 + pj], p2 = pcs[2][pg * 2 + pj];
      P_U2[((b * 16 + o) << 11) + m] = u0 * p0 + u1 * p1 + u2w * p2;
      P_V2[(bN + m) * 16 + o] = v0 * p0 + v1 * p1 + v2w * p2;
    }
  }
}

// --------------------------------------------------------------------------- id 4
// stats12 v2: grid 1024 (16 n/block).
__global__ __launch_bounds__(256) void stats12_kernel(char* base,
    const float* __restrict__ fea_b, const float* __restrict__ xyz_b)
{
  BASE(base);
  PROG(4);
  int b = blockIdx.x >> 7; int n0 = (blockIdx.x & 127) * 16;
  int t = threadIdx.x; int o = t & 15; int kk = t >> 4;
  float fb = fea_b[o], xb = xyz_b[o];
  float s1 = 0, q1 = 0, s2 = 0, q2 = 0;
  for (int nn = 0; nn < 16; nn++) {
    int n = n0 + nn;
    int m = P_IDX[((b << 11) + n) * K_ + kk] & NMASK;
    float a1 = fb + P_U1[((b * 16 + o) << 11) + n] + P_V1[(((size_t)(b << 11) + m) << 4) + o];
    s1 += a1; q1 += a1 * a1;
    float a2 = xb + P_U2[((b * 16 + o) << 11) + n] + P_V2[(((size_t)(b << 11) + m) << 4) + o];
    s2 += a2; q2 += a2 * a2;
  }
  __shared__ float red[256];
  red[t] = s1; __syncthreads();
  if (t < 16) { float s = 0; for (int k2 = 0; k2 < 16; k2++) s += red[k2 * 16 + t]; atomicAdd(&P_ST[ST_S1S + t], s); }
  __syncthreads();
  red[t] = q1; __syncthreads();
  if (t < 16) { float s = 0; for (int k2 = 0; k2 < 16; k2++) s += red[k2 * 16 + t]; atomicAdd(&P_ST[ST_S1Q + t], s); }
  __syncthreads();
  red[t] = s2; __syncthreads();
  if (t < 16) { float s = 0; for (int k2 = 0; k2 < 16; k2++) s += red[k2 * 16 + t]; atomicAdd(&P_ST[ST_S2S + t], s); }
  __syncthreads();
  red[t] = q2; __syncthreads();
  if (t < 16) { float s = 0; for (int k2 = 0; k2 < 16; k2++) s += red[k2 * 16 + t]; atomicAdd(&P_ST[ST_S2Q + t], s); }
}

// --------------------------------------------------------------------------- finalize (ids vary)
__global__ __launch_bounds__(256) void finalize_bn_kernel(char* base,
                                   const float* __restrict__ g,
                                   const float* __restrict__ be,
                                   int sum_off, int sq_off, int sc_off, int sh_off,
                                   int nch, float inv_cnt, int kid)
{
  BASE(base);
  PROG(kid);
  int i = threadIdx.x;
  if (i < nch) {
    float mu = P_ST[sum_off + i] * inv_cnt;
    float var = fmaxf(P_ST[sq_off + i] * inv_cnt - mu * mu, 0.0f);
    float s = g[i] * rsqrtf(var + EPSv);
    P_ST[sc_off + i] = s; P_ST[sh_off + i] = be[i] - mu * s;
  }
}

// --------------------------------------------------------------------------- id 7
// w1 v2: fused stats3 Gram.
__global__ __launch_bounds__(256) void w1_kernel(char* base,
    const float* __restrict__ fea_b, const float* __restrict__ xyz_b)
{
  BASE(base);
  PROG(7);
  int b = blockIdx.x >> 7; int n0 = (blockIdx.x & 127) * 16;
  int t = threadIdx.x;
  __shared__ int sidx[16 * 16];                 // [nl][k]
  __shared__ __align__(16) float ol[16 * 260];  // [c][e], e = nl*16+k
  {
    int nl = t >> 4, k = t & 15;
    sidx[nl * 16 + k] = P_IDX[((size_t)((b << 11) + n0 + nl)) * 16 + k] & NMASK;
  }
  __syncthreads();
  int c = t >> 4; int nl = t & 15; int n = n0 + nl;
  float u1 = P_U1[((b * 16 + c) << 11) + n];
  float u2 = P_U2[((b * 16 + c) << 11) + n];
  float c1 = fea_b[c] + u1, c2v = xyz_b[c] + u2;
  float s1 = P_ST[ST_B1SC + c], h1 = P_ST[ST_B1SH + c];
  float s2 = P_ST[ST_B2SC + c], h2 = P_ST[ST_B2SH + c];
  float o16[16];
#pragma unroll
  for (int kk = 0; kk < 16; kk++) {
    int m = sidx[nl * 16 + kk];
    float a1 = c1 + P_V1[(((size_t)(b << 11) + m) << 4) + c];
    a1 = lrelu(a1 * s1 + h1);
    float a2 = c2v + P_V2[(((size_t)(b << 11) + m) << 4) + c];
    a2 = lrelu(a2 * s2 + h2);
    o16[kk] = a1 * a2;
  }
  float* wp = P_W1 + ((size_t)(b * 16 + c)) * NK_ + ((size_t)n << 4);
#pragma unroll
  for (int j = 0; j < 4; j++)
    *(float4*)(wp + j * 4) = make_float4(o16[4 * j], o16[4 * j + 1], o16[4 * j + 2], o16[4 * j + 3]);
  float* orow = ol + c * 260 + nl * 16;
#pragma unroll
  for (int j = 0; j < 4; j++)
    *(float4*)(orow + j * 4) = make_float4(o16[4 * j], o16[4 * j + 1], o16[4 * j + 2], o16[4 * j + 3]);
  __syncthreads();
  if (t < 136) {
    int cc1 = 0, rem = t;
    while (rem >= 16 - cc1) { rem -= 16 - cc1; cc1++; }
    int cc2 = cc1 + rem;
    const float* r1 = ol + cc1 * 260;
    const float* r2 = ol + cc2 * 260;
    float acc = 0.0f;
    for (int e = 0; e < 256; e += 4) {
      float4 xv = *(const float4*)(r1 + e);
      float4 yv = *(const float4*)(r2 + e);
      acc += xv.x * yv.x + xv.y * yv.y + xv.z * yv.z + xv.w * yv.w;
    }
    atomicAdd(&P_ST[ST_S3M + t], acc);
  } else if (t < 152) {
    const float* r = ol + (t - 136) * 260;
    float acc = 0.0f;
    for (int e = 0; e < 256; e += 4) {
      float4 xv = *(const float4*)(r + e);
      acc += xv.x + xv.y + xv.z + xv.w;
    }
    atomicAdd(&P_ST[ST_S3V + t - 136], acc);
  }
}

// --------------------------------------------------------------------------- id 9
__global__ __launch_bounds__(256) void finalize_bn3_kernel(char* base,
                                    const float* __restrict__ b1,
                                    const float* __restrict__ g,
                                    const float* __restrict__ be)
{
  BASE(base);
  PROG(9);
  int o = threadIdx.x;
  if (o >= 64) return;
  float A[16];
  for (int c = 0; c < 16; c++) A[c] = P_A12[o * 16 + c];
  float dv = 0.0f;
  for (int c = 0; c < 16; c++) dv += A[c] * P_ST[ST_S3V + c];
  float quad = 0.0f; int p = 0;
  for (int c1 = 0; c1 < 16; c1++)
    for (int c2 = c1; c2 < 16; c2++) {
      float m = P_ST[ST_S3M + p]; p++;
      quad += (c1 == c2 ? 1.0f : 2.0f) * A[c1] * A[c2] * m;
    }
  float bo = b1[o];
  const float inv = 1.0f / 262144.0f;
  float mean = dv * inv + bo;
  float e2 = quad * inv + 2.0f * bo * dv * inv + bo * bo;
  float var = fmaxf(e2 - mean * mean, 0.0f);
  float s = g[o] * rsqrtf(var + EPSv);
  P_ST[ST_B3SC + o] = s; P_ST[ST_B3SH + o] = be[o] - mean * s;
}

// --------------------------------------------------------------------------- id 10
// a4 v3: register-blocked 2-phase + FUSED stats4 reduction in the epilogue.
__global__ __launch_bounds__(256) void a4_kernel(char* base,
                                                 const float* __restrict__ all1_b,
                                                 const float* __restrict__ all2_b)
{
  BASE(base);
  PROG(10);
  int b = blockIdx.x >> 9; int col0 = (blockIdx.x & 511) * 64;
  int t = threadIdx.x;
  __shared__ float sw[16 * 68];
  __shared__ __align__(16) float hS[64 * 68];
  for (int i = t; i < 1024; i += 256) {
    int c = i >> 6, l = i & 63;
    sw[c * 68 + l] = P_W1[((size_t)(b * 16 + c)) * NK_ + col0 + l];
  }
  __syncthreads();
  {
    int col = t & 63; int q = t >> 6;
    float in16[16];
#pragma unroll
    for (int c = 0; c < 16; c++) in16[c] = sw[c * 68 + col];
    for (int oo = 0; oo < 16; oo++) {
      int o = q * 16 + oo;
      const float* wr = P_A12 + o * 16;
      float a = all1_b[o];
#pragma unroll
      for (int c = 0; c < 16; c++) a += wr[c] * in16[c];
      hS[o * 68 + col] = lrelu(a * P_ST[ST_B3SC + o] + P_ST[ST_B3SH + o]);
    }
  }
  __syncthreads();
  int cg = t & 15;            // 4 consecutive cols
  int og = t >> 4;            // 8 consecutive outs
  float acc[8][4];
#pragma unroll
  for (int oi = 0; oi < 8; oi++) {
    float bo = all2_b[og * 8 + oi];
#pragma unroll
    for (int cj = 0; cj < 4; cj++) acc[oi][cj] = bo;
  }
  for (int hk = 0; hk < 64; hk++) {
    float4 hv = *(const float4*)&hS[hk * 68 + cg * 4];
    const float* wr = P_A22 + hk * 128 + og * 8;
    float4 w0 = *(const float4*)wr;
    float4 w1 = *(const float4*)(wr + 4);
    float av[4] = {hv.x, hv.y, hv.z, hv.w};
    float wv[8] = {w0.x, w0.y, w0.z, w0.w, w1.x, w1.y, w1.z, w1.w};
#pragma unroll
    for (int oi = 0; oi < 8; oi++)
#pragma unroll
      for (int cj = 0; cj < 4; cj++)
        acc[oi][cj] += wv[oi] * av[cj];
  }
  int colb = col0 + cg * 4;
  int n = colb >> 4; int kk0 = colb & 15;
  ushort_t* dst = P_A4 + ((size_t)(b * N_) + n) * 2048 + kk0;
  float psum[8], qsum[8];
#pragma unroll
  for (int oi = 0; oi < 8; oi++) {
    int o = og * 8 + oi;
    unsigned lo = (unsigned)f2bf(acc[oi][0]) | ((unsigned)f2bf(acc[oi][1]) << 16);
    unsigned hi = (unsigned)f2bf(acc[oi][2]) | ((unsigned)f2bf(acc[oi][3]) << 16);
    *(uint2*)(dst + o * 16) = make_uint2(lo, hi);
    float r0 = bf2f(lo & 0xffffu), r1 = bf2f(lo >> 16);
    float r2 = bf2f(hi & 0xffffu), r3 = bf2f(hi >> 16);
    psum[oi] = r0 + r1 + r2 + r3;
    qsum[oi] = r0 * r0 + r1 * r1 + r2 * r2 + r3 * r3;
  }
  __syncthreads();            // all phase-2 reads of hS done
  float* redS = hS;
#pragma unroll
  for (int oi = 0; oi < 8; oi++) redS[(og * 8 + oi) * 16 + cg] = psum[oi];
  __syncthreads();
  if (t < 128) {
    float s = 0.0f;
    for (int j = 0; j < 16; j++) s += redS[t * 16 + j];
    atomicAdd(&P_ST[ST_S4S + t], s);
  }
  __syncthreads();
#pragma unroll
  for (int oi = 0; oi < 8; oi++) redS[(og * 8 + oi) * 16 + cg] = qsum[oi];
  __syncthreads();
  if (t < 128) {
    float s = 0.0f;
    for (int j = 0; j < 16; j++) s += redS[t * 16 + j];
    atomicAdd(&P_ST[ST_S4Q + t], s);
  }
}

// --------------------------------------------------------------------------- id 13
// softfuse: softmax(bn4(A4)) fused with M = lrelu(bn5(IT)) * P.
__global__ __launch_bounds__(256) void softfuse_kernel(char* base)
{
  BASE(base);
  PROG(13);
  int rid = blockIdx.x * 256 + threadIdx.x;   // 2,097,152
  int cc = rid & 127; int r = rid >> 7;
  float s = P_ST[ST_B4SC + cc], h = P_ST[ST_B4SH + cc];
  size_t base_off = (size_t)r * 2048 + cc * 16;
  const ushort_t* pa = P_A4 + base_off;
  uint4 u0 = *(const uint4*)pa;
  uint4 u1 = *(const uint4*)(pa + 8);
  unsigned ws[8] = {u0.x, u0.y, u0.z, u0.w, u1.x, u1.y, u1.z, u1.w};
  float v[16];
#pragma unroll
  for (int j = 0; j < 8; j++) {
    union { float f; unsigned u; } lo, hi;
    lo.u = ws[j] << 16; hi.u = ws[j] & 0xffff0000u;
    v[2 * j] = lo.f; v[2 * j + 1] = hi.f;
  }
  float mx = -BIGF;
#pragma unroll
  for (int i = 0; i < 16; i++) {
    float y = lrelu(v[i] * s + h);
    v[i] = y; mx = fmaxf(mx, y);
  }
  float sum = 0.0f;
#pragma unroll
  for (int i = 0; i < 16; i++) { float e = expf(v[i] - mx); v[i] = e; sum += e; }
  float inv = (sum > 0.0f) ? 1.0f / sum : 0.0f;
#pragma unroll
  for (int i = 0; i < 16; i++) v[i] = bf2f((unsigned)f2bf(v[i] * inv));
  float s5a = P_ST[ST_B5SC + cc * 2],     h5a = P_ST[ST_B5SH + cc * 2];
  float s5b = P_ST[ST_B5SC + cc * 2 + 1], h5b = P_ST[ST_B5SH + cc * 2 + 1];
  const ushort_t* itp = P_IT + base_off;
  uint4 i0 = *(const uint4*)itp;
  uint4 i1 = *(const uint4*)(itp + 8);
  unsigned iw[8] = {i0.x, i0.y, i0.z, i0.w, i1.x, i1.y, i1.z, i1.w};
  unsigned mw[8];
#pragma unroll
  for (int j = 0; j < 8; j++) {
    union { float f; unsigned u; } il, ih;
    il.u = iw[j] << 16; ih.u = iw[j] & 0xffff0000u;
    float s5 = (j < 4) ? s5a : s5b;
    float h5 = (j < 4) ? h5a : h5b;
    float m0 = lrelu(il.f * s5 + h5) * v[2 * j];
    float m1 = lrelu(ih.f * s5 + h5) * v[2 * j + 1];
    mw[j] = (unsigned)f2bf(m0) | ((unsigned)f2bf(m1) << 16);
  }
  ushort_t* mp = P_M + base_off;
  *(uint4*)mp = make_uint4(mw[0], mw[1], mw[2], mw[3]);
  *(uint4*)(mp + 8) = make_uint4(mw[4], mw[5], mw[6], mw[7]);
}

// --------------------------------------------------------------------------- id 14
// qgemm v2: register-blocked. Block = 32 points x 256 outs x 9 taps.
__global__ __launch_bounds__(256) void qgemm_kernel(char* base)
{
  BASE(base);
  PROG(14);
  int b = blockIdx.x >> 6; int m0 = (blockIdx.x & 63) * 32;
  int t = threadIdx.x;
  int og = t & 31;            // outs og*8 .. +8
  int pg = t >> 5;            // points pg*4 .. +3
  __shared__ __align__(16) float actS[64][40];   // [c][pt]
  for (int i = t; i < 2048; i += 256) {
    int c = i & 63, mm = i >> 6;
    actS[c][mm] = P_XT[((size_t)(b * N_) + m0 + mm) * 64 + c];
  }
  __syncthreads();
  int m = m0 + pg * 4;
  for (int t9 = 0; t9 < TAP_; t9++) {
    const float* wbase = P_WQ2 + ((size_t)t9 * 64) * 256 + og * 8;
    float acc[8][4];
#pragma unroll
    for (int oi = 0; oi < 8; oi++)
#pragma unroll
      for (int pj = 0; pj < 4; pj++) acc[oi][pj] = 0.0f;
    for (int kc = 0; kc < 64; kc++) {
      float4 a = *(const float4*)&actS[kc][pg * 4];
      const float* wr = wbase + (size_t)kc * 256;
      float4 w0 = *(const float4*)wr;
      float4 w1 = *(const float4*)(wr + 4);
      float av[4] = {a.x, a.y, a.z, a.w};
      float wv[8] = {w0.x, w0.y, w0.z, w0.w, w1.x, w1.y, w1.z, w1.w};
#pragma unroll
      for (int oi = 0; oi < 8; oi++)
#pragma unroll
        for (int pj = 0; pj < 4; pj++)
          acc[oi][pj] += wv[oi] * av[pj];
    }
#pragma unroll
    for (int pj = 0; pj < 4; pj++) {
      ushort_t* qp = P_QB + ((size_t)(b * N_ + m + pj) * TAP_ + t9) * C4_ + og * 8;
      unsigned u0 = (unsigned)f2bf(acc[0][pj]) | ((unsigned)f2bf(acc[1][pj]) << 16);
      unsigned u1 = (unsigned)f2bf(acc[2][pj]) | ((unsigned)f2bf(acc[3][pj]) << 16);
      unsigned u2 = (unsigned)f2bf(acc[4][pj]) | ((unsigned)f2bf(acc[5][pj]) << 16);
      unsigned u3 = (unsigned)f2bf(acc[6][pj]) | ((unsigned)f2bf(acc[7][pj]) << 16);
      *(uint4*)qp = make_uint4(u0, u1, u2, u3);
    }
  }
}

// --------------------------------------------------------------------------- id 15
__global__ __launch_bounds__(256) void inte_fused_kernel(char* base,
                                                         const float* __restrict__ inte_b)
{
  BASE(base);
  PROG(15);
  int b = blockIdx.x >> 9; int n0 = (blockIdx.x & 511) * 4;
  int t = threadIdx.x; int o = t;
  __shared__ int sidx[4][16];
  if (t < 64) sidx[t >> 4][t & 15] = P_IDX[((size_t)(b * N_) + n0 + (t >> 4)) * K_ + (t & 15)] & NMASK;
  __syncthreads();
  float bias = inte_b[o];
  float ssum = 0.0f, ssq = 0.0f;
  for (int nn = 0; nn < 4; nn++) {
    int n = n0 + nn;
    float bse = bias + P_P[((size_t)(b * N_) + n) * C4_ + o];
    float acc[8];
#pragma unroll
    for (int j = 0; j < 8; j++) acc[j] = bse;
    for (int p = 0; p < 16; p++) {
      const ushort_t* qr = P_QB + (size_t)(b * N_ + sidx[nn][p]) * TAP_ * C4_ + o;
#pragma unroll
      for (int tt = 0; tt < TAP_; tt++) {
        int j = p - tt;
        if (j >= 0 && j < 8) acc[j] += bf2f(((unsigned)qr[tt * C4_]) << 16 >> 16 << 16 >> 16);
      }
    }
    ushort_t* ip = P_IT + ((size_t)(b * N_) + n) * 2048 + o * 8;
#pragma unroll
    for (int j = 0; j < 8; j++) { float v = acc[j]; ip[j] = f2bf(v); ssum += v; ssq += v * v; }
  }
  atomicAdd(&P_ST[ST_S5S + o], ssum);
  atomicAdd(&P_ST[ST_S5Q + o], ssq);
}

// --------------------------------------------------------------------------- id 17
// final conv v6 (best measured, 248us): 2-way k-split, grid 512.
__global__ __launch_bounds__(256) void final_conv_kernel(char* base)
{
  BASE(base);
  PROG(17);
  int ks = blockIdx.x & 1;
  int tile = (blockIdx.x >> 1) & 31; int b = blockIdx.x >> 6;
  int n0 = tile * 64;
  int t = threadIdx.x;
  int cg4 = (t & 15) * 4;
  int obase = (t >> 4) * 8;
  __shared__ __align__(16) float tileS[128 * 68];
  __shared__ int sidxT[16 * 64];        // [p][cl]
  for (int i = t; i < 1024; i += 256) {
    int cl = i & 63, p = i >> 6;
    sidxT[p * 64 + cl] = P_IDX[((size_t)(b * N_) + n0 + cl) * K_ + p] & NMASK;
  }
  float acc[32];
#pragma unroll
  for (int i = 0; i < 32; i++) acc[i] = 0.0f;
  int kbeg = ks * 1536;
  for (int k0 = kbeg; k0 < kbeg + 1536; k0 += 128) {
    __syncthreads();
    if (k0 < 1024) {
      int c0 = k0 >> 4;
      int cl = t & 63; int pg = t >> 6;
      for (int pp = 0; pp < 4; pp++) {
        int p = pg * 4 + pp;
        int m = sidxT[p * 64 + cl];
        const float* xp = P_XT + ((size_t)(b * N_) + m) * 64 + c0;
        float4 v0 = *(const float4*)xp;
        float4 v1 = *(const float4*)(xp + 4);
        tileS[(0 * 16 + p) * 68 + cl] = v0.x;
        tileS[(1 * 16 + p) * 68 + cl] = v0.y;
        tileS[(2 * 16 + p) * 68 + cl] = v0.z;
        tileS[(3 * 16 + p) * 68 + cl] = v0.w;
        tileS[(4 * 16 + p) * 68 + cl] = v1.x;
        tileS[(5 * 16 + p) * 68 + cl] = v1.y;
        tileS[(6 * 16 + p) * 68 + cl] = v1.z;
        tileS[(7 * 16 + p) * 68 + cl] = v1.w;
      }
    } else {
      int cl = t & 63; int kg = t >> 6;           // 4 groups x 32 k
      size_t rb = ((size_t)(b * N_) + n0 + cl) * 2048 + (size_t)(k0 - 1024) + kg * 32;
      const ushort_t* mp = P_M + rb;
      for (int j8 = 0; j8 < 4; j8++) {
        uint4 u = *(const uint4*)(mp + j8 * 8);
        unsigned ws[4] = {u.x, u.y, u.z, u.w};
#pragma unroll
        for (int q = 0; q < 4; q++) {
          union { float f; unsigned uu; } lo, hi;
          lo.uu = ws[q] << 16; hi.uu = ws[q] & 0xffff0000u;
          int kc = kg * 32 + j8 * 8 + q * 2;
          tileS[kc * 68 + cl] = lo.f;
          tileS[(kc + 1) * 68 + cl] = hi.f;
        }
      }
    }
    __syncthreads();
    for (int kc = 0; kc < 128; kc++) {
      float4 a = *(const float4*)&tileS[kc * 68 + cg4];
      const float* wr = P_WC2 + (size_t)(k0 + kc) * C2_ + obase;
      float4 w0 = *(const float4*)wr;
      float4 w1 = *(const float4*)(wr + 4);
      float av[4] = {a.x, a.y, a.z, a.w};
      float wv[8] = {w0.x, w0.y, w0.z, w0.w, w1.x, w1.y, w1.z, w1.w};
#pragma unroll
      for (int oi = 0; oi < 8; oi++)
#pragma unroll
        for (int cj = 0; cj < 4; cj++)
          acc[oi * 4 + cj] += wv[oi] * av[cj];
    }
  }
#pragma unroll
  for (int cj = 0; cj < 4; cj++) {
    float* op = P_PART + ((size_t)ks * B_ * N_ + (size_t)b * N_ + n0 + cg4 + cj) * C2_ + obase;
    *(float4*)op = make_float4(acc[0 * 4 + cj], acc[1 * 4 + cj], acc[2 * 4 + cj], acc[3 * 4 + cj]);
    *(float4*)(op + 4) = make_float4(acc[4 * 4 + cj], acc[5 * 4 + cj], acc[6 * 4 + cj], acc[7 * 4 + cj]);
  }
}

// --------------------------------------------------------------------------- id 18
// reduce_stats v2: grid 512. 32 rows/block.
__global__ __launch_bounds__(256) void reduce_stats_kernel(char* base,
                                                           const float* __restrict__ c2_b)
{
  BASE(base);
  PROG(18);
  int r0 = blockIdx.x * 32;    // grid 512
  int t = threadIdx.x; int o = t & 127; int h = t >> 7;
  const size_t STRIDE = (size_t)B_ * N_ * C2_;
  float cb = c2_b[o];
  float s = 0, q = 0;
  for (int r = r0 + h; r < r0 + 32; r += 2) {
    size_t off = (size_t)r * C2_ + o;
    float v = cb + P_Sb[off] + P_PART[off] + P_PART[STRIDE + off];
    P_OUT2[off] = v;
    s += v; q += v * v;
  }
  __shared__ float rs[256], rq[256];
  rs[t] = s; rq[t] = q; __syncthreads();
  if (t < 128) {
    atomicAdd(&P_ST[ST_S6S + o], rs[t] + rs[t + 128]);
    atomicAdd(&P_ST[ST_S6Q + o], rq[t] + rq[t + 128]);
  }
}

// --------------------------------------------------------------------------- id 20
// output v2: LDS-tiled.
__global__ __launch_bounds__(256) void output_kernel(char* base, float* __restrict__ out)
{
  BASE(base);
  PROG(20);
  int b = blockIdx.x >> 6; int n0 = (blockIdx.x & 63) * 32;
  int t = threadIdx.x;
  __shared__ float tile[32 * 133];
  for (int i = t; i < 4096; i += 256) {
    int o = i & 127, nl = i >> 7;
    float v = P_OUT2[((size_t)(b * N_) + n0 + nl) * C2_ + o];
    v = v * P_ST[ST_B6SC + o] + P_ST[ST_B6SH + o];
    tile[nl * 133 + o] = fmaxf(v, 0.0f);
  }
  __syncthreads();
  for (int i = t; i < 4096; i += 256) {
    int nl = i & 31, o = i >> 5;
    out[(((size_t)b * 64 + (o >> 1)) * 2 + (o & 1)) * 2048 + n0 + nl] = tile[nl * 133 + o];
  }
}

// --------------------------------------------------------------------------- diagnostics
__global__ void diag_kernel(char* base, float* __restrict__ out)
{
  BASE(base);
  const int expctd[22] = {1, 2253, 4096, 512, 1024, 1, 1, 1024, 256, 1, 4096,
                          0, 1, 8192, 512, 4096, 1, 512, 512, 1, 512, 0};
  int t = threadIdx.x;
  int bad = 99;
  if (t < 22 && P_PROG[t] != expctd[t]) bad = t;
#pragma unroll
  for (int off = 32; off > 0; off >>= 1) {
    int ob = __shfl_xor(bad, off);
    if (ob < bad) bad = ob;
  }
  if (t == 0 && bad != 99) out[0] = 100.0f + 10.0f * (float)bad;
}

__global__ void code_kernel(float* __restrict__ out, float code)
{
  if (threadIdx.x == 0 && blockIdx.x == 0) out[0] = code;
}

// ---------------------------------------------------------------------------
extern "C" void kernel_launch(void* const* d_in, const int* in_sizes, int n_in,
                              void* d_out, int out_size, void* d_ws, size_t ws_size,
                              hipStream_t stream) {
  const float* x      = (const float*)d_in[0];
  const float* pc     = (const float*)d_in[1];
  const float* fea_w  = (const float*)d_in[2];
  const float* fea_b  = (const float*)d_in[3];
  const float* fea_g  = (const float*)d_in[4];
  const float* fea_be = (const float*)d_in[5];
  const float* xyz_w  = (const float*)d_in[6];
  const float* xyz_b  = (const float*)d_in[7];
  const float* xyz_g  = (const float*)d_in[8];
  const float* xyz_be = (const float*)d_in[9];
  const float* all1_w = (const float*)d_in[10];
  const float* all1_b = (const float*)d_in[11];
  const float* all1_g = (const float*)d_in[12];
  const float* all1_be= (const float*)d_in[13];
  const float* all2_w = (const float*)d_in[14];
  const float* all2_b = (const float*)d_in[15];
  const float* all2_g = (const float*)d_in[16];
  const float* all2_be= (const float*)d_in[17];
  const float* inte_w = (const float*)d_in[18];
  const float* inte_b = (const float*)d_in[19];
  const float* inte_g = (const float*)d_in[20];
  const float* inte_be= (const float*)d_in[21];
  const float* c2_w   = (const float*)d_in[22];
  const float* c2_b   = (const float*)d_in[23];
  const float* c2_g   = (const float*)d_in[24];
  const float* c2_be  = (const float*)d_in[25];
  float* out = (float*)d_out;
  (void)in_sizes; (void)n_in; (void)out_size; (void)d_ws; (void)ws_size;

  if (g_pool_mem == nullptr) {
    code_kernel<<<1, 64, 0, stream>>>(out, 500.0f);
    return;
  }
  char* base = g_pool_mem;

  zero_kernel<<<1, 256, 0, stream>>>(base);
  xt_kernel<<<256, 256, 0, stream>>>(base, x);
  prep_kernel<<<2253, 256, 0, stream>>>(base, fea_w, xyz_w, inte_w, c2_w, all1_w, all2_w);
  knn_kernel<<<4096, 256, 0, stream>>>(base, x);
  point_gemm_kernel<<<512, 256, 0, stream>>>(base, pc);
  stats12_kernel<<<1024, 256, 0, stream>>>(base, fea_b, xyz_b);
  finalize_bn_kernel<<<1, 256, 0, stream>>>(base, fea_g, fea_be, ST_S1S, ST_S1Q, ST_B1SC, ST_B1SH, 16, 1.0f / 262144.0f, 5);
  finalize_bn_kernel<<<1, 256, 0, stream>>>(base, xyz_g, xyz_be, ST_S2S, ST_S2Q, ST_B2SC, ST_B2SH, 16, 1.0f / 262144.0f, 6);
  w1_kernel<<<1024, 256, 0, stream>>>(base, fea_b, xyz_b);
  finalize_bn3_kernel<<<1, 256, 0, stream>>>(base, all1_b, all1_g, all1_be);
  a4_kernel<<<4096, 256, 0, stream>>>(base, all1_b, all2_b);
  finalize_bn_kernel<<<1, 256, 0, stream>>>(base, all2_g, all2_be, ST_S4S, ST_S4Q, ST_B4SC, ST_B4SH, 128, 1.0f / 262144.0f, 12);
  qgemm_kernel<<<512, 256, 0, stream>>>(base);
  inte_fused_kernel<<<4096, 256, 0, stream>>>(base, inte_b);
  finalize_bn_kernel<<<1, 256, 0, stream>>>(base, inte_g, inte_be, ST_S5S, ST_S5Q, ST_B5SC, ST_B5SH, 256, 1.0f / 131072.0f, 16);
  softfuse_kernel<<<8192, 256, 0, stream>>>(base);
  final_conv_kernel<<<512, 256, 0, stream>>>(base);
  reduce_stats_kernel<<<512, 256, 0, stream>>>(base, c2_b);
  finalize_bn_kernel<<<1, 256, 0, stream>>>(base, c2_g, c2_be, ST_S6S, ST_S6Q, ST_B6SC, ST_B6SH, 128, 1.0f / 16384.0f, 19);
  output_kernel<<<512, 256, 0, stream>>>(base, out);
  diag_kernel<<<1, 64, 0, stream>>>(base, out);
}

// Round 15
// 1192.523 us; speedup vs baseline: 1.0538x; 1.0284x over previous
//
#include <hip/hip_runtime.h>
#include <math.h>

typedef unsigned short ushort_t;

#define B_   8
#define N_   2048
#define K_   16
#define C2_  128
#define C4_  256
#define KH_  8
#define TAP_ 9
#define NK_  32768
#define EPSv 1e-5f
#define BIGF 3.0e38f
#define NMASK 2047

constexpr size_t AL(size_t x) { return (x + 255) & ~(size_t)255; }
constexpr size_t OFF_XT   = 0;                                                  // f32 [B][N][64]
constexpr size_t OFF_IDX  = OFF_XT  + AL(4ull * B_ * N_ * 64);
constexpr size_t OFF_U1   = OFF_IDX + AL(4ull * B_ * N_ * K_);
constexpr size_t OFF_V1   = OFF_U1  + AL(4ull * B_ * 16 * N_);
constexpr size_t OFF_U2   = OFF_V1  + AL(4ull * B_ * N_ * 16);
constexpr size_t OFF_V2   = OFF_U2  + AL(4ull * B_ * 16 * N_);
constexpr size_t OFF_S    = OFF_V2  + AL(4ull * B_ * N_ * 16);                  // f32 [B][N][128]
constexpr size_t OFF_P    = OFF_S   + AL(4ull * B_ * N_ * C2_);                 // f32 [B][N][256]
constexpr size_t OFF_W1   = OFF_P   + AL(4ull * B_ * N_ * C4_);                 // f32 [B][16][NK]
constexpr size_t OFF_QB   = OFF_W1  + AL(4ull * B_ * 16 * NK_);                 // bf16 [B][N][9][256]
constexpr size_t OFF_ITB  = OFF_QB  + AL(2ull * (size_t)B_ * N_ * TAP_ * C4_);  // bf16 [B][N][2048]
constexpr size_t OFF_A4B  = OFF_ITB + AL(2ull * (size_t)B_ * N_ * 2048);        // bf16 [B][N][2048]
constexpr size_t OFF_M    = OFF_A4B + AL(2ull * (size_t)B_ * N_ * 2048);        // bf16 [B][N][2048]
constexpr size_t OFF_PART = OFF_M   + AL(2ull * (size_t)B_ * N_ * 2048);        // f32 [2][B][N][128]
constexpr size_t OFF_OUT2 = OFF_PART+ AL(4ull * 2 * (size_t)B_ * N_ * C2_);     // f32 [B][N][128]
constexpr size_t OFF_WQ2  = OFF_OUT2+ AL(4ull * B_ * N_ * C2_);
constexpr size_t OFF_WC2  = OFF_WQ2 + AL(4ull * TAP_ * C4_ * 64);
constexpr size_t OFF_WP2  = OFF_WC2 + AL(4ull * 3072 * C2_);
constexpr size_t OFF_WS2  = OFF_WP2 + AL(4ull * C4_ * 64);
constexpr size_t OFF_WU12 = OFF_WS2 + AL(4ull * C2_ * 64);
constexpr size_t OFF_WV12 = OFF_WU12+ AL(4ull * 16 * 64);
constexpr size_t OFF_WU22 = OFF_WV12+ AL(4ull * 16 * 64);
constexpr size_t OFF_WV22 = OFF_WU22+ AL(4ull * 64);
constexpr size_t OFF_A12  = OFF_WV22+ AL(4ull * 64);
constexpr size_t OFF_A22  = OFF_A12 + AL(4ull * 64 * 16);
constexpr size_t OFF_ST   = OFF_A22 + AL(4ull * C2_ * 64);
constexpr size_t OFF_PROG = OFF_ST  + AL(4ull * 4096);
constexpr size_t POOL_SZ  = OFF_PROG + AL(4ull * 64);

static char* g_pool_mem = nullptr;
struct PoolInit {
  PoolInit() { if (hipMalloc((void**)&g_pool_mem, POOL_SZ) != hipSuccess) g_pool_mem = nullptr; }
};
static PoolInit g_pool_init;

// g_st float offsets
#define ST_S1S 0
#define ST_S1Q 16
#define ST_S2S 32
#define ST_S2Q 48
#define ST_S5S 64
#define ST_S5Q 320
#define ST_S4S 576
#define ST_S4Q 704
#define ST_S6S 832
#define ST_S6Q 960
#define ST_B1SC 1088
#define ST_B1SH 1104
#define ST_B2SC 1120
#define ST_B2SH 1136
#define ST_B3SC 1152
#define ST_B3SH 1216
#define ST_B4SC 1280
#define ST_B4SH 1408
#define ST_B5SC 1536
#define ST_B5SH 1792
#define ST_B6SC 2048
#define ST_B6SH 2176
#define ST_S3M  2304
#define ST_S3V  2440

#define BASE(b)  char* bb = (b)
#define P_XT   ((float*)(bb + OFF_XT))
#define P_IDX  ((int*)(bb + OFF_IDX))
#define P_U1   ((float*)(bb + OFF_U1))
#define P_V1   ((float*)(bb + OFF_V1))
#define P_U2   ((float*)(bb + OFF_U2))
#define P_V2   ((float*)(bb + OFF_V2))
#define P_Sb   ((float*)(bb + OFF_S))
#define P_P    ((float*)(bb + OFF_P))
#define P_W1   ((float*)(bb + OFF_W1))
#define P_QB   ((ushort_t*)(bb + OFF_QB))
#define P_IT   ((ushort_t*)(bb + OFF_ITB))
#define P_A4   ((ushort_t*)(bb + OFF_A4B))
#define P_M    ((ushort_t*)(bb + OFF_M))
#define P_PART ((float*)(bb + OFF_PART))
#define P_OUT2 ((float*)(bb + OFF_OUT2))
#define P_WQ2  ((float*)(bb + OFF_WQ2))
#define P_WC2  ((float*)(bb + OFF_WC2))
#define P_WP2  ((float*)(bb + OFF_WP2))
#define P_WS2  ((float*)(bb + OFF_WS2))
#define P_WU12 ((float*)(bb + OFF_WU12))
#define P_WV12 ((float*)(bb + OFF_WV12))
#define P_WU22 ((float*)(bb + OFF_WU22))
#define P_WV22 ((float*)(bb + OFF_WV22))
#define P_A12  ((float*)(bb + OFF_A12))
#define P_A22  ((float*)(bb + OFF_A22))
#define P_ST   ((float*)(bb + OFF_ST))
#define P_PROG ((int*)(bb + OFF_PROG))

#define PROG(id) do { if (threadIdx.x == 0) atomicAdd(&P_PROG[(id)], 1); } while (0)

static __device__ __forceinline__ float lrelu(float x) { return x >= 0.0f ? x : 0.01f * x; }
static __device__ __forceinline__ float bf2f(unsigned h) {
  union { float f; unsigned u; } v; v.u = h << 16; return v.f;
}
static __device__ __forceinline__ ushort_t f2bf(float f) {
  union { float f; unsigned u; } v; v.f = f;
  unsigned r = v.u + 0x7fffu + ((v.u >> 16) & 1u);
  return (ushort_t)(r >> 16);
}

// --------------------------------------------------------------------------- id 0
__global__ __launch_bounds__(256) void zero_kernel(char* base)
{
  BASE(base);
  for (int i = threadIdx.x; i < 4096; i += 256) P_ST[i] = 0.0f;
  for (int i = threadIdx.x; i < 64; i += 256) P_PROG[i] = 0;
  __syncthreads();
  if (threadIdx.x == 0) P_PROG[0] = 1;
}

// --------------------------------------------------------------------------- id 8
// xt v2: LDS-tiled transpose (coalesced both sides, conflict-free [c][65]).
__global__ __launch_bounds__(256) void xt_kernel(char* base, const float* __restrict__ x)
{
  BASE(base);
  PROG(8);
  int b = blockIdx.x >> 5; int m0 = (blockIdx.x & 31) * 64;
  int t = threadIdx.x;
  __shared__ float tile[64 * 65];
  for (int i = t; i < 4096; i += 256) {
    int ml = i & 63, c = i >> 6;
    tile[c * 65 + ml] = x[((size_t)(b * 64 + c)) * N_ + m0 + ml];
  }
  __syncthreads();
  for (int i = t; i < 4096; i += 256) {
    int c = i & 63, ml = i >> 6;
    P_XT[((size_t)(b * N_) + m0 + ml) * 64 + c] = tile[c * 65 + ml];
  }
}

// --------------------------------------------------------------------------- id 1
// prep v3: weights only. 576640 elements, grid 2253.
__global__ __launch_bounds__(256) void prep_kernel(char* base,
    const float* __restrict__ fea_w,
    const float* __restrict__ xyz_w, const float* __restrict__ inte_w,
    const float* __restrict__ c2_w, const float* __restrict__ all1_w,
    const float* __restrict__ all2_w)
{
  BASE(base);
  PROG(1);
  int i = blockIdx.x * 256 + threadIdx.x;
  if (i < 1024) { int o = i & 15, c = i >> 4;    // WU12T[c][o]
    P_WU12[i] = fea_w[o * 128 + c] - fea_w[o * 128 + 64 + c]; return; }
  i -= 1024;
  if (i < 1024) { int o = i & 15, c = i >> 4;    // WV12T[c][o]
    P_WV12[i] = fea_w[o * 128 + 64 + c]; return; }
  i -= 1024;
  if (i < 64) { int c = i & 3, o = i >> 2;
    P_WU22[i] = (c < 3) ? (xyz_w[o * 6 + c] - xyz_w[o * 6 + 3 + c]) : 0.0f; return; }
  i -= 64;
  if (i < 64) { int c = i & 3, o = i >> 2;
    P_WV22[i] = (c < 3) ? xyz_w[o * 6 + 3 + c] : 0.0f; return; }
  i -= 64;
  if (i < 16384) { int o = i & 255, c = i >> 8;  // WP2T[c][o]
    float s = 0.0f;
    for (int t = 0; t < TAP_; t++)
      s += inte_w[(o * 128 + c) * TAP_ + t] - inte_w[(o * 128 + 64 + c) * TAP_ + t];
    P_WP2[i] = s; return; }
  i -= 16384;
  if (i < 147456) {                       // WQ2T[t9][c][o]  (o fastest)
    int o = i & 255; int tc = i >> 8; int c = tc & 63; int tt = tc >> 6;
    P_WQ2[i] = inte_w[(o * 128 + 64 + c) * TAP_ + tt]; return; }
  i -= 147456;
  if (i < 8192) { int o = i & 127, c = i >> 7;   // WS2T[c][o]
    float s = 0.0f;
    for (int p = 0; p < 16; p++)
      s += c2_w[(o * 128 + c) * 32 + p] - c2_w[(o * 128 + 64 + c) * 32 + p];
    P_WS2[i] = s; return; }
  i -= 8192;
  if (i < 393216) { int o = i & 127; int k = i >> 7; float v;
    if (k < 1024) { int c = k >> 4, p = k & 15; v = c2_w[(o * 128 + 64 + c) * 32 + p]; }
    else { int kr = k - 1024; int cc = kr >> 4, kk = kr & 15; v = c2_w[(o * 128 + cc) * 32 + 16 + kk]; }
    P_WC2[i] = v; return; }
  i -= 393216;
  if (i < 1024) { int c = i & 15, o = i >> 4; P_A12[i] = all1_w[o * 16 + c]; return; }
  i -= 1024;
  if (i < 8192) {                         // A22T[c][o]  (o fastest)
    int o = i & 127, c = i >> 7; P_A22[i] = all2_w[o * 64 + c]; return; }
}

// --------------------------------------------------------------------------- id 2
// phaseA: fused knn (4096 blks) + point_gemm (512) + qgemm (512) in ONE
// dispatch, interleaved bid%5==0 -> GEMM pool so resident waves are a 4:1
// knn:GEMM mix. knn is latency-bound (31% VALU, 1% HBM); GEMM blocks fill
// its idle issue slots. Each branch's arithmetic is bit-identical to the
// previous standalone kernels. LDS = union (33.8KB = knn footprint).
__global__ __launch_bounds__(256) void phaseA_kernel(char* base,
                                                     const float* __restrict__ x,
                                                     const float* __restrict__ pc)
{
  BASE(base);
  PROG(2);
  __shared__ __align__(16) char smem[33824];
  int bid = blockIdx.x;
  int t = threadIdx.x;
  if (bid % 5 != 0) {
    // ---------------- knn branch (4096 logical blocks) ----------------
    int kb = bid - bid / 5 - 1;
    int b = kb >> 9; int n0 = (kb & 511) * 4;
    float (*sdist)[N_] = (float(*)[N_])smem;                     // 32768 B
    float (*xn)[64]    = (float(*)[64])(smem + 32768);           // 1024 B
    float* sxn         = (float*)(smem + 32768 + 1024);          // 16 B
    {
      int nn = t >> 6, c = t & 63;
      xn[nn][c] = P_XT[((size_t)(b * N_) + n0 + nn) * 64 + c];
    }
    __syncthreads();
    if (t < 4) {
      float s = 0.0f;
      for (int c = 0; c < 64; c++) { float v = xn[t][c]; s += v * v; }
      sxn[t] = s;
    }
    __syncthreads();
    float dd[32]; float xs[8];
#pragma unroll
    for (int i = 0; i < 32; i++) dd[i] = 0.0f;
#pragma unroll
    for (int i = 0; i < 8; i++) xs[i] = 0.0f;
    const float* xbase = x + (size_t)b * 64 * N_ + (t << 3);   // channel-major rows
    for (int cq = 0; cq < 16; cq++) {
      float4 a0 = *(const float4*)&xn[0][cq * 4];
      float4 a1 = *(const float4*)&xn[1][cq * 4];
      float4 a2 = *(const float4*)&xn[2][cq * 4];
      float4 a3 = *(const float4*)&xn[3][cq * 4];
      float p[4][8];
#pragma unroll
      for (int cc = 0; cc < 4; cc++) {
        const float* xr = xbase + (size_t)(cq * 4 + cc) * N_;
        float4 u = *(const float4*)xr;
        float4 v = *(const float4*)(xr + 4);
        p[cc][0] = u.x; p[cc][1] = u.y; p[cc][2] = u.z; p[cc][3] = u.w;
        p[cc][4] = v.x; p[cc][5] = v.y; p[cc][6] = v.z; p[cc][7] = v.w;
      }
#pragma unroll
      for (int j = 0; j < 8; j++) {
        float x0 = p[0][j], x1 = p[1][j], x2 = p[2][j], x3 = p[3][j];
        xs[j] += x0 * x0 + x1 * x1 + x2 * x2 + x3 * x3;
        dd[0 * 8 + j] += a0.x * x0 + a0.y * x1 + a0.z * x2 + a0.w * x3;
        dd[1 * 8 + j] += a1.x * x0 + a1.y * x1 + a1.z * x2 + a1.w * x3;
        dd[2 * 8 + j] += a2.x * x0 + a2.y * x1 + a2.z * x2 + a2.w * x3;
        dd[3 * 8 + j] += a3.x * x0 + a3.y * x1 + a3.z * x2 + a3.w * x3;
      }
    }
    float sx0 = sxn[0], sx1 = sxn[1], sx2 = sxn[2], sx3 = sxn[3];
    int mb = t << 3;
#pragma unroll
    for (int j = 0; j < 8; j++) {
      int m = mb + j;
      float d0 = -2.0f * dd[0 * 8 + j] + sx0 + xs[j];
      float d1 = -2.0f * dd[1 * 8 + j] + sx1 + xs[j];
      float d2 = -2.0f * dd[2 * 8 + j] + sx2 + xs[j];
      float d3 = -2.0f * dd[3 * 8 + j] + sx3 + xs[j];
      sdist[0][m] = (m == n0 + 0) ? BIGF : d0;
      sdist[1][m] = (m == n0 + 1) ? BIGF : d1;
      sdist[2][m] = (m == n0 + 2) ? BIGF : d2;
      sdist[3][m] = (m == n0 + 3) ? BIGF : d3;
    }
    __syncthreads();
    int ln = t & 63; int wv = t >> 6;
    float v[32];
#pragma unroll
    for (int j = 0; j < 32; j++) v[j] = sdist[wv][ln + j * 64];
    float bv = v[0]; int bj = 0;
#pragma unroll
    for (int j = 1; j < 32; j++) { if (v[j] < bv) { bv = v[j]; bj = j; } }
    int* op = P_IDX + ((size_t)(b * N_) + n0 + wv) * K_;
    for (int it = 0; it < K_; it++) {
      float rv = bv; int ri = ln + (bj << 6);
#pragma unroll
      for (int off = 32; off > 0; off >>= 1) {
        float ov = __shfl_xor(rv, off);
        int oi = __shfl_xor(ri, off);
        if (ov < rv || (ov == rv && oi < ri)) { rv = ov; ri = oi; }
      }
      if (ln == 0) op[it] = ri;
      if ((ri & 63) == ln) {
        int slot = ri >> 6;
#pragma unroll
        for (int j = 0; j < 32; j++) v[j] = (j == slot) ? BIGF : v[j];
        bv = v[0]; bj = 0;
#pragma unroll
        for (int j = 1; j < 32; j++) { if (v[j] < bv) { bv = v[j]; bj = j; } }
      }
    }
    return;
  }
  int s = bid / 5;
  if (s < 512) {
    // ---------------- point_gemm branch (512 logical blocks) ----------------
    int b = s >> 6; int m0 = (s & 63) * 32;
    float (*actS)[40] = (float(*)[40])smem;                      // 10240 B
    float (*pcs)[32]  = (float(*)[32])(smem + 10240);            // 384 B
    for (int i = t; i < 2048; i += 256) {
      int c = i & 63, mm = i >> 6;
      actS[c][mm] = P_XT[((size_t)(b * N_) + m0 + mm) * 64 + c];
    }
    if (t < 96) {
      int c = t >> 5, mm = t & 31;
      pcs[c][mm] = pc[(b * 3 + c) * N_ + m0 + mm];
    }
    __syncthreads();
    size_t bN = (size_t)(b * N_);
    {
      int og = t & 31, pg = t >> 5;
      float acc[8][4];
#pragma unroll
      for (int oi = 0; oi < 8; oi++)
#pragma unroll
        for (int pj = 0; pj < 4; pj++) acc[oi][pj] = 0.0f;
      for (int c = 0; c < 64; c++) {
        float4 a = *(const float4*)&actS[c][pg * 4];
        const float* wr = P_WP2 + c * 256 + og * 8;
        float4 w0 = *(const float4*)wr;
        float4 w1 = *(const float4*)(wr + 4);
        float av[4] = {a.x, a.y, a.z, a.w};
        float wv[8] = {w0.x, w0.y, w0.z, w0.w, w1.x, w1.y, w1.z, w1.w};
#pragma unroll
        for (int oi = 0; oi < 8; oi++)
#pragma unroll
          for (int pj = 0; pj < 4; pj++) acc[oi][pj] += wv[oi] * av[pj];
      }
#pragma unroll
      for (int pj = 0; pj < 4; pj++) {
        float* pp = P_P + (bN + m0 + pg * 4 + pj) * C4_ + og * 8;
        *(float4*)pp = make_float4(acc[0][pj], acc[1][pj], acc[2][pj], acc[3][pj]);
        *(float4*)(pp + 4) = make_float4(acc[4][pj], acc[5][pj], acc[6][pj], acc[7][pj]);
      }
    }
    {
      int og = t & 15, pg = t >> 4;
      float acc[8][2];
#pragma unroll
      for (int oi = 0; oi < 8; oi++) { acc[oi][0] = 0.0f; acc[oi][1] = 0.0f; }
      for (int c = 0; c < 64; c++) {
        float a0 = actS[c][pg * 2], a1 = actS[c][pg * 2 + 1];
        const float* wr = P_WS2 + c * 128 + og * 8;
        float4 w0 = *(const float4*)wr;
        float4 w1 = *(const float4*)(wr + 4);
        float wv[8] = {w0.x, w0.y, w0.z, w0.w, w1.x, w1.y, w1.z, w1.w};
#pragma unroll
        for (int oi = 0; oi < 8; oi++) { acc[oi][0] += wv[oi] * a0; acc[oi][1] += wv[oi] * a1; }
      }
#pragma unroll
      for (int pj = 0; pj < 2; pj++) {
        float* sp = P_Sb + (bN + m0 + pg * 2 + pj) * C2_ + og * 8;
        *(float4*)sp = make_float4(acc[0][pj], acc[1][pj], acc[2][pj], acc[3][pj]);
        *(float4*)(sp + 4) = make_float4(acc[4][pj], acc[5][pj], acc[6][pj], acc[7][pj]);
      }
    }
    {
      int o = t & 15, pg = t >> 4;
      float aU[2] = {0.0f, 0.0f}, aV[2] = {0.0f, 0.0f};
      for (int c = 0; c < 64; c++) {
        float wu = P_WU12[c * 16 + o];
        float wv = P_WV12[c * 16 + o];
        float a0 = actS[c][pg * 2], a1 = actS[c][pg * 2 + 1];
        aU[0] += wu * a0; aU[1] += wu * a1;
        aV[0] += wv * a0; aV[1] += wv * a1;
      }
      float u0 = P_WU22[o * 4], u1 = P_WU22[o * 4 + 1], u2w = P_WU22[o * 4 + 2];
      float v0 = P_WV22[o * 4], v1 = P_WV22[o * 4 + 1], v2w = P_WV22[o * 4 + 2];
#pragma unroll
      for (int pj = 0; pj < 2; pj++) {
        int m = m0 + pg * 2 + pj;
        P_U1[((b * 16 + o) << 11) + m] = aU[pj];
        P_V1[(bN + m) * 16 + o] = aV[pj];
        float p0 = pcs[0][pg * 2 + pj], p1 = pcs[1][pg * 2 + pj], p2 = pcs[2][pg * 2 + pj];
        P_U2[((b * 16 + o) << 11) + m] = u0 * p0 + u1 * p1 + u2w * p2;
        P_V2[(bN + m) * 16 + o] = v0 * p0 + v1 * p1 + v2w * p2;
      }
    }
    return;
  }
  {
    // ---------------- qgemm branch (512 logical blocks) ----------------
    int q = s - 512;
    int b = q >> 6; int m0 = (q & 63) * 32;
    float (*actS)[40] = (float(*)[40])smem;                      // 10240 B
    for (int i = t; i < 2048; i += 256) {
      int c = i & 63, mm = i >> 6;
      actS[c][mm] = P_XT[((size_t)(b * N_) + m0 + mm) * 64 + c];
    }
    __syncthreads();
    int og = t & 31;            // outs og*8 .. +8
    int pg = t >> 5;            // points pg*4 .. +3
    int m = m0 + pg * 4;
    for (int t9 = 0; t9 < TAP_; t9++) {
      const float* wbase = P_WQ2 + ((size_t)t9 * 64) * 256 + og * 8;
      float acc[8][4];
#pragma unroll
      for (int oi = 0; oi < 8; oi++)
#pragma unroll
        for (int pj = 0; pj < 4; pj++) acc[oi][pj] = 0.0f;
      for (int kc = 0; kc < 64; kc++) {
        float4 a = *(const float4*)&actS[kc][pg * 4];
        const float* wr = wbase + (size_t)kc * 256;
        float4 w0 = *(const float4*)wr;
        float4 w1 = *(const float4*)(wr + 4);
        float av[4] = {a.x, a.y, a.z, a.w};
        float wv[8] = {w0.x, w0.y, w0.z, w0.w, w1.x, w1.y, w1.z, w1.w};
#pragma unroll
        for (int oi = 0; oi < 8; oi++)
#pragma unroll
          for (int pj = 0; pj < 4; pj++)
            acc[oi][pj] += wv[oi] * av[pj];
      }
#pragma unroll
      for (int pj = 0; pj < 4; pj++) {
        ushort_t* qp = P_QB + ((size_t)(b * N_ + m + pj) * TAP_ + t9) * C4_ + og * 8;
        unsigned u0 = (unsigned)f2bf(acc[0][pj]) | ((unsigned)f2bf(acc[1][pj]) << 16);
        unsigned u1 = (unsigned)f2bf(acc[2][pj]) | ((unsigned)f2bf(acc[3][pj]) << 16);
        unsigned u2 = (unsigned)f2bf(acc[4][pj]) | ((unsigned)f2bf(acc[5][pj]) << 16);
        unsigned u3 = (unsigned)f2bf(acc[6][pj]) | ((unsigned)f2bf(acc[7][pj]) << 16);
        *(uint4*)qp = make_uint4(u0, u1, u2, u3);
      }
    }
    return;
  }
}

// --------------------------------------------------------------------------- id 4
// stats12 v2: grid 1024 (16 n/block).
__global__ __launch_bounds__(256) void stats12_kernel(char* base,
    const float* __restrict__ fea_b, const float* __restrict__ xyz_b)
{
  BASE(base);
  PROG(4);
  int b = blockIdx.x >> 7; int n0 = (blockIdx.x & 127) * 16;
  int t = threadIdx.x; int o = t & 15; int kk = t >> 4;
  float fb = fea_b[o], xb = xyz_b[o];
  float s1 = 0, q1 = 0, s2 = 0, q2 = 0;
  for (int nn = 0; nn < 16; nn++) {
    int n = n0 + nn;
    int m = P_IDX[((b << 11) + n) * K_ + kk] & NMASK;
    float a1 = fb + P_U1[((b * 16 + o) << 11) + n] + P_V1[(((size_t)(b << 11) + m) << 4) + o];
    s1 += a1; q1 += a1 * a1;
    float a2 = xb + P_U2[((b * 16 + o) << 11) + n] + P_V2[(((size_t)(b << 11) + m) << 4) + o];
    s2 += a2; q2 += a2 * a2;
  }
  __shared__ float red[256];
  red[t] = s1; __syncthreads();
  if (t < 16) { float s = 0; for (int k2 = 0; k2 < 16; k2++) s += red[k2 * 16 + t]; atomicAdd(&P_ST[ST_S1S + t], s); }
  __syncthreads();
  red[t] = q1; __syncthreads();
  if (t < 16) { float s = 0; for (int k2 = 0; k2 < 16; k2++) s += red[k2 * 16 + t]; atomicAdd(&P_ST[ST_S1Q + t], s); }
  __syncthreads();
  red[t] = s2; __syncthreads();
  if (t < 16) { float s = 0; for (int k2 = 0; k2 < 16; k2++) s += red[k2 * 16 + t]; atomicAdd(&P_ST[ST_S2S + t], s); }
  __syncthreads();
  red[t] = q2; __syncthreads();
  if (t < 16) { float s = 0; for (int k2 = 0; k2 < 16; k2++) s += red[k2 * 16 + t]; atomicAdd(&P_ST[ST_S2Q + t], s); }
}

// --------------------------------------------------------------------------- finalize (ids vary)
__global__ __launch_bounds__(256) void finalize_bn_kernel(char* base,
                                   const float* __restrict__ g,
                                   const float* __restrict__ be,
                                   int sum_off, int sq_off, int sc_off, int sh_off,
                                   int nch, float inv_cnt, int kid)
{
  BASE(base);
  PROG(kid);
  int i = threadIdx.x;
  if (i < nch) {
    float mu = P_ST[sum_off + i] * inv_cnt;
    float var = fmaxf(P_ST[sq_off + i] * inv_cnt - mu * mu, 0.0f);
    float s = g[i] * rsqrtf(var + EPSv);
    P_ST[sc_off + i] = s; P_ST[sh_off + i] = be[i] - mu * s;
  }
}

// --------------------------------------------------------------------------- id 7
// w1 v2: fused stats3 Gram.
__global__ __launch_bounds__(256) void w1_kernel(char* base,
    const float* __restrict__ fea_b, const float* __restrict__ xyz_b)
{
  BASE(base);
  PROG(7);
  int b = blockIdx.x >> 7; int n0 = (blockIdx.x & 127) * 16;
  int t = threadIdx.x;
  __shared__ int sidx[16 * 16];                 // [nl][k]
  __shared__ __align__(16) float ol[16 * 260];  // [c][e], e = nl*16+k
  {
    int nl = t >> 4, k = t & 15;
    sidx[nl * 16 + k] = P_IDX[((size_t)((b << 11) + n0 + nl)) * 16 + k] & NMASK;
  }
  __syncthreads();
  int c = t >> 4; int nl = t & 15; int n = n0 + nl;
  float u1 = P_U1[((b * 16 + c) << 11) + n];
  float u2 = P_U2[((b * 16 + c) << 11) + n];
  float c1 = fea_b[c] + u1, c2v = xyz_b[c] + u2;
  float s1 = P_ST[ST_B1SC + c], h1 = P_ST[ST_B1SH + c];
  float s2 = P_ST[ST_B2SC + c], h2 = P_ST[ST_B2SH + c];
  float o16[16];
#pragma unroll
  for (int kk = 0; kk < 16; kk++) {
    int m = sidx[nl * 16 + kk];
    float a1 = c1 + P_V1[(((size_t)(b << 11) + m) << 4) + c];
    a1 = lrelu(a1 * s1 + h1);
    float a2 = c2v + P_V2[(((size_t)(b << 11) + m) << 4) + c];
    a2 = lrelu(a2 * s2 + h2);
    o16[kk] = a1 * a2;
  }
  float* wp = P_W1 + ((size_t)(b * 16 + c)) * NK_ + ((size_t)n << 4);
#pragma unroll
  for (int j = 0; j < 4; j++)
    *(float4*)(wp + j * 4) = make_float4(o16[4 * j], o16[4 * j + 1], o16[4 * j + 2], o16[4 * j + 3]);
  float* orow = ol + c * 260 + nl * 16;
#pragma unroll
  for (int j = 0; j < 4; j++)
    *(float4*)(orow + j * 4) = make_float4(o16[4 * j], o16[4 * j + 1], o16[4 * j + 2], o16[4 * j + 3]);
  __syncthreads();
  if (t < 136) {
    int cc1 = 0, rem = t;
    while (rem >= 16 - cc1) { rem -= 16 - cc1; cc1++; }
    int cc2 = cc1 + rem;
    const float* r1 = ol + cc1 * 260;
    const float* r2 = ol + cc2 * 260;
    float acc = 0.0f;
    for (int e = 0; e < 256; e += 4) {
      float4 xv = *(const float4*)(r1 + e);
      float4 yv = *(const float4*)(r2 + e);
      acc += xv.x * yv.x + xv.y * yv.y + xv.z * yv.z + xv.w * yv.w;
    }
    atomicAdd(&P_ST[ST_S3M + t], acc);
  } else if (t < 152) {
    const float* r = ol + (t - 136) * 260;
    float acc = 0.0f;
    for (int e = 0; e < 256; e += 4) {
      float4 xv = *(const float4*)(r + e);
      acc += xv.x + xv.y + xv.z + xv.w;
    }
    atomicAdd(&P_ST[ST_S3V + t - 136], acc);
  }
}

// --------------------------------------------------------------------------- id 9
__global__ __launch_bounds__(256) void finalize_bn3_kernel(char* base,
                                    const float* __restrict__ b1,
                                    const float* __restrict__ g,
                                    const float* __restrict__ be)
{
  BASE(base);
  PROG(9);
  int o = threadIdx.x;
  if (o >= 64) return;
  float A[16];
  for (int c = 0; c < 16; c++) A[c] = P_A12[o * 16 + c];
  float dv = 0.0f;
  for (int c = 0; c < 16; c++) dv += A[c] * P_ST[ST_S3V + c];
  float quad = 0.0f; int p = 0;
  for (int c1 = 0; c1 < 16; c1++)
    for (int c2 = c1; c2 < 16; c2++) {
      float m = P_ST[ST_S3M + p]; p++;
      quad += (c1 == c2 ? 1.0f : 2.0f) * A[c1] * A[c2] * m;
    }
  float bo = b1[o];
  const float inv = 1.0f / 262144.0f;
  float mean = dv * inv + bo;
  float e2 = quad * inv + 2.0f * bo * dv * inv + bo * bo;
  float var = fmaxf(e2 - mean * mean, 0.0f);
  float s = g[o] * rsqrtf(var + EPSv);
  P_ST[ST_B3SC + o] = s; P_ST[ST_B3SH + o] = be[o] - mean * s;
}

// --------------------------------------------------------------------------- id 10
// a4 v3: register-blocked 2-phase + FUSED stats4 reduction in the epilogue.
__global__ __launch_bounds__(256) void a4_kernel(char* base,
                                                 const float* __restrict__ all1_b,
                                                 const float* __restrict__ all2_b)
{
  BASE(base);
  PROG(10);
  int b = blockIdx.x >> 9; int col0 = (blockIdx.x & 511) * 64;
  int t = threadIdx.x;
  __shared__ float sw[16 * 68];
  __shared__ __align__(16) float hS[64 * 68];
  for (int i = t; i < 1024; i += 256) {
    int c = i >> 6, l = i & 63;
    sw[c * 68 + l] = P_W1[((size_t)(b * 16 + c)) * NK_ + col0 + l];
  }
  __syncthreads();
  {
    int col = t & 63; int q = t >> 6;
    float in16[16];
#pragma unroll
    for (int c = 0; c < 16; c++) in16[c] = sw[c * 68 + col];
    for (int oo = 0; oo < 16; oo++) {
      int o = q * 16 + oo;
      const float* wr = P_A12 + o * 16;
      float a = all1_b[o];
#pragma unroll
      for (int c = 0; c < 16; c++) a += wr[c] * in16[c];
      hS[o * 68 + col] = lrelu(a * P_ST[ST_B3SC + o] + P_ST[ST_B3SH + o]);
    }
  }
  __syncthreads();
  int cg = t & 15;            // 4 consecutive cols
  int og = t >> 4;            // 8 consecutive outs
  float acc[8][4];
#pragma unroll
  for (int oi = 0; oi < 8; oi++) {
    float bo = all2_b[og * 8 + oi];
#pragma unroll
    for (int cj = 0; cj < 4; cj++) acc[oi][cj] = bo;
  }
  for (int hk = 0; hk < 64; hk++) {
    float4 hv = *(const float4*)&hS[hk * 68 + cg * 4];
    const float* wr = P_A22 + hk * 128 + og * 8;
    float4 w0 = *(const float4*)wr;
    float4 w1 = *(const float4*)(wr + 4);
    float av[4] = {hv.x, hv.y, hv.z, hv.w};
    float wv[8] = {w0.x, w0.y, w0.z, w0.w, w1.x, w1.y, w1.z, w1.w};
#pragma unroll
    for (int oi = 0; oi < 8; oi++)
#pragma unroll
      for (int cj = 0; cj < 4; cj++)
        acc[oi][cj] += wv[oi] * av[cj];
  }
  int colb = col0 + cg * 4;
  int n = colb >> 4; int kk0 = colb & 15;
  ushort_t* dst = P_A4 + ((size_t)(b * N_) + n) * 2048 + kk0;
  float psum[8], qsum[8];
#pragma unroll
  for (int oi = 0; oi < 8; oi++) {
    int o = og * 8 + oi;
    unsigned lo = (unsigned)f2bf(acc[oi][0]) | ((unsigned)f2bf(acc[oi][1]) << 16);
    unsigned hi = (unsigned)f2bf(acc[oi][2]) | ((unsigned)f2bf(acc[oi][3]) << 16);
    *(uint2*)(dst + o * 16) = make_uint2(lo, hi);
    float r0 = bf2f(lo & 0xffffu), r1 = bf2f(lo >> 16);
    float r2 = bf2f(hi & 0xffffu), r3 = bf2f(hi >> 16);
    psum[oi] = r0 + r1 + r2 + r3;
    qsum[oi] = r0 * r0 + r1 * r1 + r2 * r2 + r3 * r3;
  }
  __syncthreads();            // all phase-2 reads of hS done
  float* redS = hS;
#pragma unroll
  for (int oi = 0; oi < 8; oi++) redS[(og * 8 + oi) * 16 + cg] = psum[oi];
  __syncthreads();
  if (t < 128) {
    float s = 0.0f;
    for (int j = 0; j < 16; j++) s += redS[t * 16 + j];
    atomicAdd(&P_ST[ST_S4S + t], s);
  }
  __syncthreads();
#pragma unroll
  for (int oi = 0; oi < 8; oi++) redS[(og * 8 + oi) * 16 + cg] = qsum[oi];
  __syncthreads();
  if (t < 128) {
    float s = 0.0f;
    for (int j = 0; j < 16; j++) s += redS[t * 16 + j];
    atomicAdd(&P_ST[ST_S4Q + t], s);
  }
}

// --------------------------------------------------------------------------- id 13
// softfuse: softmax(bn4(A4)) fused with M = lrelu(bn5(IT)) * P.
__global__ __launch_bounds__(256) void softfuse_kernel(char* base)
{
  BASE(base);
  PROG(13);
  int rid = blockIdx.x * 256 + threadIdx.x;   // 2,097,152
  int cc = rid & 127; int r = rid >> 7;
  float s = P_ST[ST_B4SC + cc], h = P_ST[ST_B4SH + cc];
  size_t base_off = (size_t)r * 2048 + cc * 16;
  const ushort_t* pa = P_A4 + base_off;
  uint4 u0 = *(const uint4*)pa;
  uint4 u1 = *(const uint4*)(pa + 8);
  unsigned ws[8] = {u0.x, u0.y, u0.z, u0.w, u1.x, u1.y, u1.z, u1.w};
  float v[16];
#pragma unroll
  for (int j = 0; j < 8; j++) {
    union { float f; unsigned u; } lo, hi;
    lo.u = ws[j] << 16; hi.u = ws[j] & 0xffff0000u;
    v[2 * j] = lo.f; v[2 * j + 1] = hi.f;
  }
  float mx = -BIGF;
#pragma unroll
  for (int i = 0; i < 16; i++) {
    float y = lrelu(v[i] * s + h);
    v[i] = y; mx = fmaxf(mx, y);
  }
  float sum = 0.0f;
#pragma unroll
  for (int i = 0; i < 16; i++) { float e = expf(v[i] - mx); v[i] = e; sum += e; }
  float inv = (sum > 0.0f) ? 1.0f / sum : 0.0f;
#pragma unroll
  for (int i = 0; i < 16; i++) v[i] = bf2f((unsigned)f2bf(v[i] * inv));
  float s5a = P_ST[ST_B5SC + cc * 2],     h5a = P_ST[ST_B5SH + cc * 2];
  float s5b = P_ST[ST_B5SC + cc * 2 + 1], h5b = P_ST[ST_B5SH + cc * 2 + 1];
  const ushort_t* itp = P_IT + base_off;
  uint4 i0 = *(const uint4*)itp;
  uint4 i1 = *(const uint4*)(itp + 8);
  unsigned iw[8] = {i0.x, i0.y, i0.z, i0.w, i1.x, i1.y, i1.z, i1.w};
  unsigned mw[8];
#pragma unroll
  for (int j = 0; j < 8; j++) {
    union { float f; unsigned u; } il, ih;
    il.u = iw[j] << 16; ih.u = iw[j] & 0xffff0000u;
    float s5 = (j < 4) ? s5a : s5b;
    float h5 = (j < 4) ? h5a : h5b;
    float m0 = lrelu(il.f * s5 + h5) * v[2 * j];
    float m1 = lrelu(ih.f * s5 + h5) * v[2 * j + 1];
    mw[j] = (unsigned)f2bf(m0) | ((unsigned)f2bf(m1) << 16);
  }
  ushort_t* mp = P_M + base_off;
  *(uint4*)mp = make_uint4(mw[0], mw[1], mw[2], mw[3]);
  *(uint4*)(mp + 8) = make_uint4(mw[4], mw[5], mw[6], mw[7]);
}

// --------------------------------------------------------------------------- id 15
__global__ __launch_bounds__(256) void inte_fused_kernel(char* base,
                                                         const float* __restrict__ inte_b)
{
  BASE(base);
  PROG(15);
  int b = blockIdx.x >> 9; int n0 = (blockIdx.x & 511) * 4;
  int t = threadIdx.x; int o = t;
  __shared__ int sidx[4][16];
  if (t < 64) sidx[t >> 4][t & 15] = P_IDX[((size_t)(b * N_) + n0 + (t >> 4)) * K_ + (t & 15)] & NMASK;
  __syncthreads();
  float bias = inte_b[o];
  float ssum = 0.0f, ssq = 0.0f;
  for (int nn = 0; nn < 4; nn++) {
    int n = n0 + nn;
    float bse = bias + P_P[((size_t)(b * N_) + n) * C4_ + o];
    float acc[8];
#pragma unroll
    for (int j = 0; j < 8; j++) acc[j] = bse;
    for (int p = 0; p < 16; p++) {
      const ushort_t* qr = P_QB + (size_t)(b * N_ + sidx[nn][p]) * TAP_ * C4_ + o;
#pragma unroll
      for (int tt = 0; tt < TAP_; tt++) {
        int j = p - tt;
        if (j >= 0 && j < 8) acc[j] += bf2f(((unsigned)qr[tt * C4_]) << 16 >> 16 << 16 >> 16);
      }
    }
    ushort_t* ip = P_IT + ((size_t)(b * N_) + n) * 2048 + o * 8;
#pragma unroll
    for (int j = 0; j < 8; j++) { float v = acc[j]; ip[j] = f2bf(v); ssum += v; ssq += v * v; }
  }
  atomicAdd(&P_ST[ST_S5S + o], ssum);
  atomicAdd(&P_ST[ST_S5Q + o], ssq);
}

// --------------------------------------------------------------------------- id 17
// final conv v6 (best measured, 248us): 2-way k-split, grid 512.
__global__ __launch_bounds__(256) void final_conv_kernel(char* base)
{
  BASE(base);
  PROG(17);
  int ks = blockIdx.x & 1;
  int tile = (blockIdx.x >> 1) & 31; int b = blockIdx.x >> 6;
  int n0 = tile * 64;
  int t = threadIdx.x;
  int cg4 = (t & 15) * 4;
  int obase = (t >> 4) * 8;
  __shared__ __align__(16) float tileS[128 * 68];
  __shared__ int sidxT[16 * 64];        // [p][cl]
  for (int i = t; i < 1024; i += 256) {
    int cl = i & 63, p = i >> 6;
    sidxT[p * 64 + cl] = P_IDX[((size_t)(b * N_) + n0 + cl) * K_ + p] & NMASK;
  }
  float acc[32];
#pragma unroll
  for (int i = 0; i < 32; i++) acc[i] = 0.0f;
  int kbeg = ks * 1536;
  for (int k0 = kbeg; k0 < kbeg + 1536; k0 += 128) {
    __syncthreads();
    if (k0 < 1024) {
      int c0 = k0 >> 4;
      int cl = t & 63; int pg = t >> 6;
      for (int pp = 0; pp < 4; pp++) {
        int p = pg * 4 + pp;
        int m = sidxT[p * 64 + cl];
        const float* xp = P_XT + ((size_t)(b * N_) + m) * 64 + c0;
        float4 v0 = *(const float4*)xp;
        float4 v1 = *(const float4*)(xp + 4);
        tileS[(0 * 16 + p) * 68 + cl] = v0.x;
        tileS[(1 * 16 + p) * 68 + cl] = v0.y;
        tileS[(2 * 16 + p) * 68 + cl] = v0.z;
        tileS[(3 * 16 + p) * 68 + cl] = v0.w;
        tileS[(4 * 16 + p) * 68 + cl] = v1.x;
        tileS[(5 * 16 + p) * 68 + cl] = v1.y;
        tileS[(6 * 16 + p) * 68 + cl] = v1.z;
        tileS[(7 * 16 + p) * 68 + cl] = v1.w;
      }
    } else {
      int cl = t & 63; int kg = t >> 6;           // 4 groups x 32 k
      size_t rb = ((size_t)(b * N_) + n0 + cl) * 2048 + (size_t)(k0 - 1024) + kg * 32;
      const ushort_t* mp = P_M + rb;
      for (int j8 = 0; j8 < 4; j8++) {
        uint4 u = *(const uint4*)(mp + j8 * 8);
        unsigned ws[4] = {u.x, u.y, u.z, u.w};
#pragma unroll
        for (int q = 0; q < 4; q++) {
          union { float f; unsigned uu; } lo, hi;
          lo.uu = ws[q] << 16; hi.uu = ws[q] & 0xffff0000u;
          int kc = kg * 32 + j8 * 8 + q * 2;
          tileS[kc * 68 + cl] = lo.f;
          tileS[(kc + 1) * 68 + cl] = hi.f;
        }
      }
    }
    __syncthreads();
    for (int kc = 0; kc < 128; kc++) {
      float4 a = *(const float4*)&tileS[kc * 68 + cg4];
      const float* wr = P_WC2 + (size_t)(k0 + kc) * C2_ + obase;
      float4 w0 = *(const float4*)wr;
      float4 w1 = *(const float4*)(wr + 4);
      float av[4] = {a.x, a.y, a.z, a.w};
      float wv[8] = {w0.x, w0.y, w0.z, w0.w, w1.x, w1.y, w1.z, w1.w};
#pragma unroll
      for (int oi = 0; oi < 8; oi++)
#pragma unroll
        for (int cj = 0; cj < 4; cj++)
          acc[oi * 4 + cj] += wv[oi] * av[cj];
    }
  }
#pragma unroll
  for (int cj = 0; cj < 4; cj++) {
    float* op = P_PART + ((size_t)ks * B_ * N_ + (size_t)b * N_ + n0 + cg4 + cj) * C2_ + obase;
    *(float4*)op = make_float4(acc[0 * 4 + cj], acc[1 * 4 + cj], acc[2 * 4 + cj], acc[3 * 4 + cj]);
    *(float4*)(op + 4) = make_float4(acc[4 * 4 + cj], acc[5 * 4 + cj], acc[6 * 4 + cj], acc[7 * 4 + cj]);
  }
}

// --------------------------------------------------------------------------- id 18
// reduce_stats v2: grid 512. 32 rows/block.
__global__ __launch_bounds__(256) void reduce_stats_kernel(char* base,
                                                           const float* __restrict__ c2_b)
{
  BASE(base);
  PROG(18);
  int r0 = blockIdx.x * 32;    // grid 512
  int t = threadIdx.x; int o = t & 127; int h = t >> 7;
  const size_t STRIDE = (size_t)B_ * N_ * C2_;
  float cb = c2_b[o];
  float s = 0, q = 0;
  for (int r = r0 + h; r < r0 + 32; r += 2) {
    size_t off = (size_t)r * C2_ + o;
    float v = cb + P_Sb[off] + P_PART[off] + P_PART[STRIDE + off];
    P_OUT2[off] = v;
    s += v; q += v * v;
  }
  __shared__ float rs[256], rq[256];
  rs[t] = s; rq[t] = q; __syncthreads();
  if (t < 128) {
    atomicAdd(&P_ST[ST_S6S + o], rs[t] + rs[t + 128]);
    atomicAdd(&P_ST[ST_S6Q + o], rq[t] + rq[t + 128]);
  }
}

// --------------------------------------------------------------------------- id 20
// output v2: LDS-tiled.
__global__ __launch_bounds__(256) void output_kernel(char* base, float* __restrict__ out)
{
  BASE(base);
  PROG(20);
  int b = blockIdx.x >> 6; int n0 = (blockIdx.x & 63) * 32;
  int t = threadIdx.x;
  __shared__ float tile[32 * 133];
  for (int i = t; i < 4096; i += 256) {
    int o = i & 127, nl = i >> 7;
    float v = P_OUT2[((size_t)(b * N_) + n0 + nl) * C2_ + o];
    v = v * P_ST[ST_B6SC + o] + P_ST[ST_B6SH + o];
    tile[nl * 133 + o] = fmaxf(v, 0.0f);
  }
  __syncthreads();
  for (int i = t; i < 4096; i += 256) {
    int nl = i & 31, o = i >> 5;
    out[(((size_t)b * 64 + (o >> 1)) * 2 + (o & 1)) * 2048 + n0 + nl] = tile[nl * 133 + o];
  }
}

// --------------------------------------------------------------------------- diagnostics
__global__ void diag_kernel(char* base, float* __restrict__ out)
{
  BASE(base);
  const int expctd[22] = {1, 2253, 5120, 0, 1024, 1, 1, 1024, 256, 1, 4096,
                          0, 1, 8192, 0, 4096, 1, 512, 512, 1, 512, 0};
  int t = threadIdx.x;
  int bad = 99;
  if (t < 22 && P_PROG[t] != expctd[t]) bad = t;
#pragma unroll
  for (int off = 32; off > 0; off >>= 1) {
    int ob = __shfl_xor(bad, off);
    if (ob < bad) bad = ob;
  }
  if (t == 0 && bad != 99) out[0] = 100.0f + 10.0f * (float)bad;
}

__global__ void code_kernel(float* __restrict__ out, float code)
{
  if (threadIdx.x == 0 && blockIdx.x == 0) out[0] = code;
}

// ---------------------------------------------------------------------------
extern "C" void kernel_launch(void* const* d_in, const int* in_sizes, int n_in,
                              void* d_out, int out_size, void* d_ws, size_t ws_size,
                              hipStream_t stream) {
  const float* x      = (const float*)d_in[0];
  const float* pc     = (const float*)d_in[1];
  const float* fea_w  = (const float*)d_in[2];
  const float* fea_b  = (const float*)d_in[3];
  const float* fea_g  = (const float*)d_in[4];
  const float* fea_be = (const float*)d_in[5];
  const float* xyz_w  = (const float*)d_in[6];
  const float* xyz_b  = (const float*)d_in[7];
  const float* xyz_g  = (const float*)d_in[8];
  const float* xyz_be = (const float*)d_in[9];
  const float* all1_w = (const float*)d_in[10];
  const float* all1_b = (const float*)d_in[11];
  const float* all1_g = (const float*)d_in[12];
  const float* all1_be= (const float*)d_in[13];
  const float* all2_w = (const float*)d_in[14];
  const float* all2_b = (const float*)d_in[15];
  const float* all2_g = (const float*)d_in[16];
  const float* all2_be= (const float*)d_in[17];
  const float* inte_w = (const float*)d_in[18];
  const float* inte_b = (const float*)d_in[19];
  const float* inte_g = (const float*)d_in[20];
  const float* inte_be= (const float*)d_in[21];
  const float* c2_w   = (const float*)d_in[22];
  const float* c2_b   = (const float*)d_in[23];
  const float* c2_g   = (const float*)d_in[24];
  const float* c2_be  = (const float*)d_in[25];
  float* out = (float*)d_out;
  (void)in_sizes; (void)n_in; (void)out_size; (void)d_ws; (void)ws_size;

  if (g_pool_mem == nullptr) {
    code_kernel<<<1, 64, 0, stream>>>(out, 500.0f);
    return;
  }
  char* base = g_pool_mem;

  zero_kernel<<<1, 256, 0, stream>>>(base);
  xt_kernel<<<256, 256, 0, stream>>>(base, x);
  prep_kernel<<<2253, 256, 0, stream>>>(base, fea_w, xyz_w, inte_w, c2_w, all1_w, all2_w);
  phaseA_kernel<<<5120, 256, 0, stream>>>(base, x, pc);
  stats12_kernel<<<1024, 256, 0, stream>>>(base, fea_b, xyz_b);
  finalize_bn_kernel<<<1, 256, 0, stream>>>(base, fea_g, fea_be, ST_S1S, ST_S1Q, ST_B1SC, ST_B1SH, 16, 1.0f / 262144.0f, 5);
  finalize_bn_kernel<<<1, 256, 0, stream>>>(base, xyz_g, xyz_be, ST_S2S, ST_S2Q, ST_B2SC, ST_B2SH, 16, 1.0f / 262144.0f, 6);
  w1_kernel<<<1024, 256, 0, stream>>>(base, fea_b, xyz_b);
  finalize_bn3_kernel<<<1, 256, 0, stream>>>(base, all1_b, all1_g, all1_be);
  a4_kernel<<<4096, 256, 0, stream>>>(base, all1_b, all2_b);
  finalize_bn_kernel<<<1, 256, 0, stream>>>(base, all2_g, all2_be, ST_S4S, ST_S4Q, ST_B4SC, ST_B4SH, 128, 1.0f / 262144.0f, 12);
  inte_fused_kernel<<<4096, 256, 0, stream>>>(base, inte_b);
  finalize_bn_kernel<<<1, 256, 0, stream>>>(base, inte_g, inte_be, ST_S5S, ST_S5Q, ST_B5SC, ST_B5SH, 256, 1.0f / 131072.0f, 16);
  softfuse_kernel<<<8192, 256, 0, stream>>>(base);
  final_conv_kernel<<<512, 256, 0, stream>>>(base);
  reduce_stats_kernel<<<512, 256, 0, stream>>>(base, c2_b);
  finalize_bn_kernel<<<1, 256, 0, stream>>>(base, c2_g, c2_be, ST_S6S, ST_S6Q, ST_B6SC, ST_B6SH, 128, 1.0f / 16384.0f, 19);
  output_kernel<<<512, 256, 0, stream>>>(base, out);
  diag_kernel<<<1, 64, 0, stream>>>(base, out);
}

// Round 16
// 1157.316 us; speedup vs baseline: 1.0858x; 1.0304x over previous
//
#include <hip/hip_runtime.h>
#include <math.h>

typedef unsigned short ushort_t;

#define B_   8
#define N_   2048
#define K_   16
#define C2_  128
#define C4_  256
#define KH_  8
#define TAP_ 9
#define NK_  32768
#define EPSv 1e-5f
#define BIGF 3.0e38f
#define NMASK 2047

constexpr size_t AL(size_t x) { return (x + 255) & ~(size_t)255; }
constexpr size_t OFF_XT   = 0;                                                  // f32 [B][N][64]
constexpr size_t OFF_IDX  = OFF_XT  + AL(4ull * B_ * N_ * 64);
constexpr size_t OFF_U1   = OFF_IDX + AL(4ull * B_ * N_ * K_);
constexpr size_t OFF_V1   = OFF_U1  + AL(4ull * B_ * 16 * N_);
constexpr size_t OFF_U2   = OFF_V1  + AL(4ull * B_ * N_ * 16);
constexpr size_t OFF_V2   = OFF_U2  + AL(4ull * B_ * 16 * N_);
constexpr size_t OFF_S    = OFF_V2  + AL(4ull * B_ * N_ * 16);                  // f32 [B][N][128]
constexpr size_t OFF_P    = OFF_S   + AL(4ull * B_ * N_ * C2_);                 // f32 [B][N][256]
constexpr size_t OFF_W1   = OFF_P   + AL(4ull * B_ * N_ * C4_);                 // f32 [B][16][NK]
constexpr size_t OFF_QB   = OFF_W1  + AL(4ull * B_ * 16 * NK_);                 // bf16 [B][N][9][256]
constexpr size_t OFF_ITB  = OFF_QB  + AL(2ull * (size_t)B_ * N_ * TAP_ * C4_);  // bf16 [B][N][2048]
constexpr size_t OFF_A4B  = OFF_ITB + AL(2ull * (size_t)B_ * N_ * 2048);        // bf16 [B][N][2048]
constexpr size_t OFF_M    = OFF_A4B + AL(2ull * (size_t)B_ * N_ * 2048);        // bf16 [B][N][2048]
constexpr size_t OFF_PART = OFF_M   + AL(2ull * (size_t)B_ * N_ * 2048);        // f32 [2][B][N][128]
constexpr size_t OFF_OUT2 = OFF_PART+ AL(4ull * 2 * (size_t)B_ * N_ * C2_);     // f32 [B][N][128]
constexpr size_t OFF_WQ2  = OFF_OUT2+ AL(4ull * B_ * N_ * C2_);
constexpr size_t OFF_WC2  = OFF_WQ2 + AL(4ull * TAP_ * C4_ * 64);
constexpr size_t OFF_WP2  = OFF_WC2 + AL(4ull * 3072 * C2_);
constexpr size_t OFF_WS2  = OFF_WP2 + AL(4ull * C4_ * 64);
constexpr size_t OFF_WU12 = OFF_WS2 + AL(4ull * C2_ * 64);
constexpr size_t OFF_WV12 = OFF_WU12+ AL(4ull * 16 * 64);
constexpr size_t OFF_WU22 = OFF_WV12+ AL(4ull * 16 * 64);
constexpr size_t OFF_WV22 = OFF_WU22+ AL(4ull * 64);
constexpr size_t OFF_A12  = OFF_WV22+ AL(4ull * 64);
constexpr size_t OFF_A22  = OFF_A12 + AL(4ull * 64 * 16);
constexpr size_t OFF_ST   = OFF_A22 + AL(4ull * C2_ * 64);
constexpr size_t OFF_PROG = OFF_ST  + AL(4ull * 4096);
constexpr size_t POOL_SZ  = OFF_PROG + AL(4ull * 64);

static char* g_pool_mem = nullptr;
struct PoolInit {
  PoolInit() { if (hipMalloc((void**)&g_pool_mem, POOL_SZ) != hipSuccess) g_pool_mem = nullptr; }
};
static PoolInit g_pool_init;

// g_st float offsets
#define ST_S1S 0
#define ST_S1Q 16
#define ST_S2S 32
#define ST_S2Q 48
#define ST_S5S 64
#define ST_S5Q 320
#define ST_S4S 576
#define ST_S4Q 704
#define ST_S6S 832
#define ST_S6Q 960
#define ST_B1SC 1088
#define ST_B1SH 1104
#define ST_B2SC 1120
#define ST_B2SH 1136
#define ST_B3SC 1152
#define ST_B3SH 1216
#define ST_B4SC 1280
#define ST_B4SH 1408
#define ST_B5SC 1536
#define ST_B5SH 1792
#define ST_B6SC 2048
#define ST_B6SH 2176
#define ST_S3M  2304
#define ST_S3V  2440

#define BASE(b)  char* bb = (b)
#define P_XT   ((float*)(bb + OFF_XT))
#define P_IDX  ((int*)(bb + OFF_IDX))
#define P_U1   ((float*)(bb + OFF_U1))
#define P_V1   ((float*)(bb + OFF_V1))
#define P_U2   ((float*)(bb + OFF_U2))
#define P_V2   ((float*)(bb + OFF_V2))
#define P_Sb   ((float*)(bb + OFF_S))
#define P_P    ((float*)(bb + OFF_P))
#define P_W1   ((float*)(bb + OFF_W1))
#define P_QB   ((ushort_t*)(bb + OFF_QB))
#define P_IT   ((ushort_t*)(bb + OFF_ITB))
#define P_A4   ((ushort_t*)(bb + OFF_A4B))
#define P_M    ((ushort_t*)(bb + OFF_M))
#define P_PART ((float*)(bb + OFF_PART))
#define P_OUT2 ((float*)(bb + OFF_OUT2))
#define P_WQ2  ((float*)(bb + OFF_WQ2))
#define P_WC2  ((float*)(bb + OFF_WC2))
#define P_WP2  ((float*)(bb + OFF_WP2))
#define P_WS2  ((float*)(bb + OFF_WS2))
#define P_WU12 ((float*)(bb + OFF_WU12))
#define P_WV12 ((float*)(bb + OFF_WV12))
#define P_WU22 ((float*)(bb + OFF_WU22))
#define P_WV22 ((float*)(bb + OFF_WV22))
#define P_A12  ((float*)(bb + OFF_A12))
#define P_A22  ((float*)(bb + OFF_A22))
#define P_ST   ((float*)(bb + OFF_ST))
#define P_PROG ((int*)(bb + OFF_PROG))

#define PROG(id) do { if (threadIdx.x == 0) atomicAdd(&P_PROG[(id)], 1); } while (0)

static __device__ __forceinline__ float lrelu(float x) { return x >= 0.0f ? x : 0.01f * x; }
static __device__ __forceinline__ float bf2f(unsigned h) {
  union { float f; unsigned u; } v; v.u = h << 16; return v.f;
}
static __device__ __forceinline__ ushort_t f2bf(float f) {
  union { float f; unsigned u; } v; v.f = f;
  unsigned r = v.u + 0x7fffu + ((v.u >> 16) & 1u);
  return (ushort_t)(r >> 16);
}

// --------------------------------------------------------------------------- id 0
__global__ __launch_bounds__(256) void zero_kernel(char* base)
{
  BASE(base);
  for (int i = threadIdx.x; i < 4096; i += 256) P_ST[i] = 0.0f;
  for (int i = threadIdx.x; i < 64; i += 256) P_PROG[i] = 0;
  __syncthreads();
  if (threadIdx.x == 0) P_PROG[0] = 1;
}

// --------------------------------------------------------------------------- id 8
// xt v2: LDS-tiled transpose (coalesced both sides, conflict-free [c][65]).
__global__ __launch_bounds__(256) void xt_kernel(char* base, const float* __restrict__ x)
{
  BASE(base);
  PROG(8);
  int b = blockIdx.x >> 5; int m0 = (blockIdx.x & 31) * 64;
  int t = threadIdx.x;
  __shared__ float tile[64 * 65];
  for (int i = t; i < 4096; i += 256) {
    int ml = i & 63, c = i >> 6;
    tile[c * 65 + ml] = x[((size_t)(b * 64 + c)) * N_ + m0 + ml];
  }
  __syncthreads();
  for (int i = t; i < 4096; i += 256) {
    int c = i & 63, ml = i >> 6;
    P_XT[((size_t)(b * N_) + m0 + ml) * 64 + c] = tile[c * 65 + ml];
  }
}

// --------------------------------------------------------------------------- id 1
// prep v3: weights only. 576640 elements, grid 2253.
__global__ __launch_bounds__(256) void prep_kernel(char* base,
    const float* __restrict__ fea_w,
    const float* __restrict__ xyz_w, const float* __restrict__ inte_w,
    const float* __restrict__ c2_w, const float* __restrict__ all1_w,
    const float* __restrict__ all2_w)
{
  BASE(base);
  PROG(1);
  int i = blockIdx.x * 256 + threadIdx.x;
  if (i < 1024) { int o = i & 15, c = i >> 4;    // WU12T[c][o]
    P_WU12[i] = fea_w[o * 128 + c] - fea_w[o * 128 + 64 + c]; return; }
  i -= 1024;
  if (i < 1024) { int o = i & 15, c = i >> 4;    // WV12T[c][o]
    P_WV12[i] = fea_w[o * 128 + 64 + c]; return; }
  i -= 1024;
  if (i < 64) { int c = i & 3, o = i >> 2;
    P_WU22[i] = (c < 3) ? (xyz_w[o * 6 + c] - xyz_w[o * 6 + 3 + c]) : 0.0f; return; }
  i -= 64;
  if (i < 64) { int c = i & 3, o = i >> 2;
    P_WV22[i] = (c < 3) ? xyz_w[o * 6 + 3 + c] : 0.0f; return; }
  i -= 64;
  if (i < 16384) { int o = i & 255, c = i >> 8;  // WP2T[c][o]
    float s = 0.0f;
    for (int t = 0; t < TAP_; t++)
      s += inte_w[(o * 128 + c) * TAP_ + t] - inte_w[(o * 128 + 64 + c) * TAP_ + t];
    P_WP2[i] = s; return; }
  i -= 16384;
  if (i < 147456) {                       // WQ2T[t9][c][o]  (o fastest)
    int o = i & 255; int tc = i >> 8; int c = tc & 63; int tt = tc >> 6;
    P_WQ2[i] = inte_w[(o * 128 + 64 + c) * TAP_ + tt]; return; }
  i -= 147456;
  if (i < 8192) { int o = i & 127, c = i >> 7;   // WS2T[c][o]
    float s = 0.0f;
    for (int p = 0; p < 16; p++)
      s += c2_w[(o * 128 + c) * 32 + p] - c2_w[(o * 128 + 64 + c) * 32 + p];
    P_WS2[i] = s; return; }
  i -= 8192;
  if (i < 393216) { int o = i & 127; int k = i >> 7; float v;
    if (k < 1024) { int c = k >> 4, p = k & 15; v = c2_w[(o * 128 + 64 + c) * 32 + p]; }
    else { int kr = k - 1024; int cc = kr >> 4, kk = kr & 15; v = c2_w[(o * 128 + cc) * 32 + 16 + kk]; }
    P_WC2[i] = v; return; }
  i -= 393216;
  if (i < 1024) { int c = i & 15, o = i >> 4; P_A12[i] = all1_w[o * 16 + c]; return; }
  i -= 1024;
  if (i < 8192) {                         // A22T[c][o]  (o fastest)
    int o = i & 127, c = i >> 7; P_A22[i] = all2_w[o * 64 + c]; return; }
}

// --------------------------------------------------------------------------- id 2
// phaseA: fused knn (4096) + point_gemm (512) + qgemm (512), bid%5 interleave.
__global__ __launch_bounds__(256) void phaseA_kernel(char* base,
                                                     const float* __restrict__ x,
                                                     const float* __restrict__ pc)
{
  BASE(base);
  PROG(2);
  __shared__ __align__(16) char smem[33824];
  int bid = blockIdx.x;
  int t = threadIdx.x;
  if (bid % 5 != 0) {
    // ---------------- knn branch (4096 logical blocks) ----------------
    int kb = bid - bid / 5 - 1;
    int b = kb >> 9; int n0 = (kb & 511) * 4;
    float (*sdist)[N_] = (float(*)[N_])smem;                     // 32768 B
    float (*xn)[64]    = (float(*)[64])(smem + 32768);           // 1024 B
    float* sxn         = (float*)(smem + 32768 + 1024);          // 16 B
    {
      int nn = t >> 6, c = t & 63;
      xn[nn][c] = P_XT[((size_t)(b * N_) + n0 + nn) * 64 + c];
    }
    __syncthreads();
    if (t < 4) {
      float s = 0.0f;
      for (int c = 0; c < 64; c++) { float v = xn[t][c]; s += v * v; }
      sxn[t] = s;
    }
    __syncthreads();
    float dd[32]; float xs[8];
#pragma unroll
    for (int i = 0; i < 32; i++) dd[i] = 0.0f;
#pragma unroll
    for (int i = 0; i < 8; i++) xs[i] = 0.0f;
    const float* xbase = x + (size_t)b * 64 * N_ + (t << 3);   // channel-major rows
    for (int cq = 0; cq < 16; cq++) {
      float4 a0 = *(const float4*)&xn[0][cq * 4];
      float4 a1 = *(const float4*)&xn[1][cq * 4];
      float4 a2 = *(const float4*)&xn[2][cq * 4];
      float4 a3 = *(const float4*)&xn[3][cq * 4];
      float p[4][8];
#pragma unroll
      for (int cc = 0; cc < 4; cc++) {
        const float* xr = xbase + (size_t)(cq * 4 + cc) * N_;
        float4 u = *(const float4*)xr;
        float4 v = *(const float4*)(xr + 4);
        p[cc][0] = u.x; p[cc][1] = u.y; p[cc][2] = u.z; p[cc][3] = u.w;
        p[cc][4] = v.x; p[cc][5] = v.y; p[cc][6] = v.z; p[cc][7] = v.w;
      }
#pragma unroll
      for (int j = 0; j < 8; j++) {
        float x0 = p[0][j], x1 = p[1][j], x2 = p[2][j], x3 = p[3][j];
        xs[j] += x0 * x0 + x1 * x1 + x2 * x2 + x3 * x3;
        dd[0 * 8 + j] += a0.x * x0 + a0.y * x1 + a0.z * x2 + a0.w * x3;
        dd[1 * 8 + j] += a1.x * x0 + a1.y * x1 + a1.z * x2 + a1.w * x3;
        dd[2 * 8 + j] += a2.x * x0 + a2.y * x1 + a2.z * x2 + a2.w * x3;
        dd[3 * 8 + j] += a3.x * x0 + a3.y * x1 + a3.z * x2 + a3.w * x3;
      }
    }
    float sx0 = sxn[0], sx1 = sxn[1], sx2 = sxn[2], sx3 = sxn[3];
    int mb = t << 3;
#pragma unroll
    for (int j = 0; j < 8; j++) {
      int m = mb + j;
      float d0 = -2.0f * dd[0 * 8 + j] + sx0 + xs[j];
      float d1 = -2.0f * dd[1 * 8 + j] + sx1 + xs[j];
      float d2 = -2.0f * dd[2 * 8 + j] + sx2 + xs[j];
      float d3 = -2.0f * dd[3 * 8 + j] + sx3 + xs[j];
      sdist[0][m] = (m == n0 + 0) ? BIGF : d0;
      sdist[1][m] = (m == n0 + 1) ? BIGF : d1;
      sdist[2][m] = (m == n0 + 2) ? BIGF : d2;
      sdist[3][m] = (m == n0 + 3) ? BIGF : d3;
    }
    __syncthreads();
    int ln = t & 63; int wv = t >> 6;
    float v[32];
#pragma unroll
    for (int j = 0; j < 32; j++) v[j] = sdist[wv][ln + j * 64];
    float bv = v[0]; int bj = 0;
#pragma unroll
    for (int j = 1; j < 32; j++) { if (v[j] < bv) { bv = v[j]; bj = j; } }
    int* op = P_IDX + ((size_t)(b * N_) + n0 + wv) * K_;
    for (int it = 0; it < K_; it++) {
      float rv = bv; int ri = ln + (bj << 6);
#pragma unroll
      for (int off = 32; off > 0; off >>= 1) {
        float ov = __shfl_xor(rv, off);
        int oi = __shfl_xor(ri, off);
        if (ov < rv || (ov == rv && oi < ri)) { rv = ov; ri = oi; }
      }
      if (ln == 0) op[it] = ri;
      if ((ri & 63) == ln) {
        int slot = ri >> 6;
#pragma unroll
        for (int j = 0; j < 32; j++) v[j] = (j == slot) ? BIGF : v[j];
        bv = v[0]; bj = 0;
#pragma unroll
        for (int j = 1; j < 32; j++) { if (v[j] < bv) { bv = v[j]; bj = j; } }
      }
    }
    return;
  }
  int s = bid / 5;
  if (s < 512) {
    // ---------------- point_gemm branch (512 logical blocks) ----------------
    int b = s >> 6; int m0 = (s & 63) * 32;
    float (*actS)[40] = (float(*)[40])smem;                      // 10240 B
    float (*pcs)[32]  = (float(*)[32])(smem + 10240);            // 384 B
    for (int i = t; i < 2048; i += 256) {
      int c = i & 63, mm = i >> 6;
      actS[c][mm] = P_XT[((size_t)(b * N_) + m0 + mm) * 64 + c];
    }
    if (t < 96) {
      int c = t >> 5, mm = t & 31;
      pcs[c][mm] = pc[(b * 3 + c) * N_ + m0 + mm];
    }
    __syncthreads();
    size_t bN = (size_t)(b * N_);
    {
      int og = t & 31, pg = t >> 5;
      float acc[8][4];
#pragma unroll
      for (int oi = 0; oi < 8; oi++)
#pragma unroll
        for (int pj = 0; pj < 4; pj++) acc[oi][pj] = 0.0f;
      for (int c = 0; c < 64; c++) {
        float4 a = *(const float4*)&actS[c][pg * 4];
        const float* wr = P_WP2 + c * 256 + og * 8;
        float4 w0 = *(const float4*)wr;
        float4 w1 = *(const float4*)(wr + 4);
        float av[4] = {a.x, a.y, a.z, a.w};
        float wv[8] = {w0.x, w0.y, w0.z, w0.w, w1.x, w1.y, w1.z, w1.w};
#pragma unroll
        for (int oi = 0; oi < 8; oi++)
#pragma unroll
          for (int pj = 0; pj < 4; pj++) acc[oi][pj] += wv[oi] * av[pj];
      }
#pragma unroll
      for (int pj = 0; pj < 4; pj++) {
        float* pp = P_P + (bN + m0 + pg * 4 + pj) * C4_ + og * 8;
        *(float4*)pp = make_float4(acc[0][pj], acc[1][pj], acc[2][pj], acc[3][pj]);
        *(float4*)(pp + 4) = make_float4(acc[4][pj], acc[5][pj], acc[6][pj], acc[7][pj]);
      }
    }
    {
      int og = t & 15, pg = t >> 4;
      float acc[8][2];
#pragma unroll
      for (int oi = 0; oi < 8; oi++) { acc[oi][0] = 0.0f; acc[oi][1] = 0.0f; }
      for (int c = 0; c < 64; c++) {
        float a0 = actS[c][pg * 2], a1 = actS[c][pg * 2 + 1];
        const float* wr = P_WS2 + c * 128 + og * 8;
        float4 w0 = *(const float4*)wr;
        float4 w1 = *(const float4*)(wr + 4);
        float wv[8] = {w0.x, w0.y, w0.z, w0.w, w1.x, w1.y, w1.z, w1.w};
#pragma unroll
        for (int oi = 0; oi < 8; oi++) { acc[oi][0] += wv[oi] * a0; acc[oi][1] += wv[oi] * a1; }
      }
#pragma unroll
      for (int pj = 0; pj < 2; pj++) {
        float* sp = P_Sb + (bN + m0 + pg * 2 + pj) * C2_ + og * 8;
        *(float4*)sp = make_float4(acc[0][pj], acc[1][pj], acc[2][pj], acc[3][pj]);
        *(float4*)(sp + 4) = make_float4(acc[4][pj], acc[5][pj], acc[6][pj], acc[7][pj]);
      }
    }
    {
      int o = t & 15, pg = t >> 4;
      float aU[2] = {0.0f, 0.0f}, aV[2] = {0.0f, 0.0f};
      for (int c = 0; c < 64; c++) {
        float wu = P_WU12[c * 16 + o];
        float wv = P_WV12[c * 16 + o];
        float a0 = actS[c][pg * 2], a1 = actS[c][pg * 2 + 1];
        aU[0] += wu * a0; aU[1] += wu * a1;
        aV[0] += wv * a0; aV[1] += wv * a1;
      }
      float u0 = P_WU22[o * 4], u1 = P_WU22[o * 4 + 1], u2w = P_WU22[o * 4 + 2];
      float v0 = P_WV22[o * 4], v1 = P_WV22[o * 4 + 1], v2w = P_WV22[o * 4 + 2];
#pragma unroll
      for (int pj = 0; pj < 2; pj++) {
        int m = m0 + pg * 2 + pj;
        P_U1[((b * 16 + o) << 11) + m] = aU[pj];
        P_V1[(bN + m) * 16 + o] = aV[pj];
        float p0 = pcs[0][pg * 2 + pj], p1 = pcs[1][pg * 2 + pj], p2 = pcs[2][pg * 2 + pj];
        P_U2[((b * 16 + o) << 11) + m] = u0 * p0 + u1 * p1 + u2w * p2;
        P_V2[(bN + m) * 16 + o] = v0 * p0 + v1 * p1 + v2w * p2;
      }
    }
    return;
  }
  {
    // ---------------- qgemm branch (512 logical blocks) ----------------
    int q = s - 512;
    int b = q >> 6; int m0 = (q & 63) * 32;
    float (*actS)[40] = (float(*)[40])smem;                      // 10240 B
    for (int i = t; i < 2048; i += 256) {
      int c = i & 63, mm = i >> 6;
      actS[c][mm] = P_XT[((size_t)(b * N_) + m0 + mm) * 64 + c];
    }
    __syncthreads();
    int og = t & 31;            // outs og*8 .. +8
    int pg = t >> 5;            // points pg*4 .. +3
    int m = m0 + pg * 4;
    for (int t9 = 0; t9 < TAP_; t9++) {
      const float* wbase = P_WQ2 + ((size_t)t9 * 64) * 256 + og * 8;
      float acc[8][4];
#pragma unroll
      for (int oi = 0; oi < 8; oi++)
#pragma unroll
        for (int pj = 0; pj < 4; pj++) acc[oi][pj] = 0.0f;
      for (int kc = 0; kc < 64; kc++) {
        float4 a = *(const float4*)&actS[kc][pg * 4];
        const float* wr = wbase + (size_t)kc * 256;
        float4 w0 = *(const float4*)wr;
        float4 w1 = *(const float4*)(wr + 4);
        float av[4] = {a.x, a.y, a.z, a.w};
        float wv[8] = {w0.x, w0.y, w0.z, w0.w, w1.x, w1.y, w1.z, w1.w};
#pragma unroll
        for (int oi = 0; oi < 8; oi++)
#pragma unroll
          for (int pj = 0; pj < 4; pj++)
            acc[oi][pj] += wv[oi] * av[pj];
      }
#pragma unroll
      for (int pj = 0; pj < 4; pj++) {
        ushort_t* qp = P_QB + ((size_t)(b * N_ + m + pj) * TAP_ + t9) * C4_ + og * 8;
        unsigned u0 = (unsigned)f2bf(acc[0][pj]) | ((unsigned)f2bf(acc[1][pj]) << 16);
        unsigned u1 = (unsigned)f2bf(acc[2][pj]) | ((unsigned)f2bf(acc[3][pj]) << 16);
        unsigned u2 = (unsigned)f2bf(acc[4][pj]) | ((unsigned)f2bf(acc[5][pj]) << 16);
        unsigned u3 = (unsigned)f2bf(acc[6][pj]) | ((unsigned)f2bf(acc[7][pj]) << 16);
        *(uint4*)qp = make_uint4(u0, u1, u2, u3);
      }
    }
    return;
  }
}

// --------------------------------------------------------------------------- id 15
// phaseB: fused inte_fused (4096 logical blocks) + stats12 (1024), bid%5
// interleave. Both depend only on phaseA outputs; stats12's gather latency
// hides inside inte's. Per-branch arithmetic identical to the previous
// standalone kernels. LDS union = 1KB.
__global__ __launch_bounds__(256) void phaseB_kernel(char* base,
                                                     const float* __restrict__ inte_b,
                                                     const float* __restrict__ fea_b,
                                                     const float* __restrict__ xyz_b)
{
  BASE(base);
  PROG(15);
  __shared__ __align__(16) char smem[1024];
  int bid = blockIdx.x;
  int t = threadIdx.x;
  if (bid % 5 != 0) {
    // ---------------- inte_fused branch (4096 logical blocks) ----------------
    int kb = bid - bid / 5 - 1;
    int b = kb >> 9; int n0 = (kb & 511) * 4;
    int o = t;
    int (*sidx)[16] = (int(*)[16])smem;          // 256 B
    if (t < 64) sidx[t >> 4][t & 15] = P_IDX[((size_t)(b * N_) + n0 + (t >> 4)) * K_ + (t & 15)] & NMASK;
    __syncthreads();
    float bias = inte_b[o];
    float ssum = 0.0f, ssq = 0.0f;
    for (int nn = 0; nn < 4; nn++) {
      int n = n0 + nn;
      float bse = bias + P_P[((size_t)(b * N_) + n) * C4_ + o];
      float acc[8];
#pragma unroll
      for (int j = 0; j < 8; j++) acc[j] = bse;
      for (int p = 0; p < 16; p++) {
        const ushort_t* qr = P_QB + (size_t)(b * N_ + sidx[nn][p]) * TAP_ * C4_ + o;
#pragma unroll
        for (int tt = 0; tt < TAP_; tt++) {
          int j = p - tt;
          if (j >= 0 && j < 8) acc[j] += bf2f(((unsigned)qr[tt * C4_]) << 16 >> 16 << 16 >> 16);
        }
      }
      ushort_t* ip = P_IT + ((size_t)(b * N_) + n) * 2048 + o * 8;
#pragma unroll
      for (int j = 0; j < 8; j++) { float v = acc[j]; ip[j] = f2bf(v); ssum += v; ssq += v * v; }
    }
    atomicAdd(&P_ST[ST_S5S + o], ssum);
    atomicAdd(&P_ST[ST_S5Q + o], ssq);
    return;
  }
  {
    // ---------------- stats12 branch (1024 logical blocks) ----------------
    int s = bid / 5;
    int b = s >> 7; int n0 = (s & 127) * 16;
    int o = t & 15; int kk = t >> 4;
    float* red = (float*)smem;                   // 1024 B
    float fb = fea_b[o], xb = xyz_b[o];
    float s1 = 0, q1 = 0, s2 = 0, q2 = 0;
    for (int nn = 0; nn < 16; nn++) {
      int n = n0 + nn;
      int m = P_IDX[((b << 11) + n) * K_ + kk] & NMASK;
      float a1 = fb + P_U1[((b * 16 + o) << 11) + n] + P_V1[(((size_t)(b << 11) + m) << 4) + o];
      s1 += a1; q1 += a1 * a1;
      float a2 = xb + P_U2[((b * 16 + o) << 11) + n] + P_V2[(((size_t)(b << 11) + m) << 4) + o];
      s2 += a2; q2 += a2 * a2;
    }
    red[t] = s1; __syncthreads();
    if (t < 16) { float s = 0; for (int k2 = 0; k2 < 16; k2++) s += red[k2 * 16 + t]; atomicAdd(&P_ST[ST_S1S + t], s); }
    __syncthreads();
    red[t] = q1; __syncthreads();
    if (t < 16) { float s = 0; for (int k2 = 0; k2 < 16; k2++) s += red[k2 * 16 + t]; atomicAdd(&P_ST[ST_S1Q + t], s); }
    __syncthreads();
    red[t] = s2; __syncthreads();
    if (t < 16) { float s = 0; for (int k2 = 0; k2 < 16; k2++) s += red[k2 * 16 + t]; atomicAdd(&P_ST[ST_S2S + t], s); }
    __syncthreads();
    red[t] = q2; __syncthreads();
    if (t < 16) { float s = 0; for (int k2 = 0; k2 < 16; k2++) s += red[k2 * 16 + t]; atomicAdd(&P_ST[ST_S2Q + t], s); }
    return;
  }
}

// --------------------------------------------------------------------------- finalize (ids vary)
__global__ __launch_bounds__(256) void finalize_bn_kernel(char* base,
                                   const float* __restrict__ g,
                                   const float* __restrict__ be,
                                   int sum_off, int sq_off, int sc_off, int sh_off,
                                   int nch, float inv_cnt, int kid)
{
  BASE(base);
  PROG(kid);
  int i = threadIdx.x;
  if (i < nch) {
    float mu = P_ST[sum_off + i] * inv_cnt;
    float var = fmaxf(P_ST[sq_off + i] * inv_cnt - mu * mu, 0.0f);
    float s = g[i] * rsqrtf(var + EPSv);
    P_ST[sc_off + i] = s; P_ST[sh_off + i] = be[i] - mu * s;
  }
}

// --------------------------------------------------------------------------- id 7
// w1 v2: fused stats3 Gram.
__global__ __launch_bounds__(256) void w1_kernel(char* base,
    const float* __restrict__ fea_b, const float* __restrict__ xyz_b)
{
  BASE(base);
  PROG(7);
  int b = blockIdx.x >> 7; int n0 = (blockIdx.x & 127) * 16;
  int t = threadIdx.x;
  __shared__ int sidx[16 * 16];                 // [nl][k]
  __shared__ __align__(16) float ol[16 * 260];  // [c][e], e = nl*16+k
  {
    int nl = t >> 4, k = t & 15;
    sidx[nl * 16 + k] = P_IDX[((size_t)((b << 11) + n0 + nl)) * 16 + k] & NMASK;
  }
  __syncthreads();
  int c = t >> 4; int nl = t & 15; int n = n0 + nl;
  float u1 = P_U1[((b * 16 + c) << 11) + n];
  float u2 = P_U2[((b * 16 + c) << 11) + n];
  float c1 = fea_b[c] + u1, c2v = xyz_b[c] + u2;
  float s1 = P_ST[ST_B1SC + c], h1 = P_ST[ST_B1SH + c];
  float s2 = P_ST[ST_B2SC + c], h2 = P_ST[ST_B2SH + c];
  float o16[16];
#pragma unroll
  for (int kk = 0; kk < 16; kk++) {
    int m = sidx[nl * 16 + kk];
    float a1 = c1 + P_V1[(((size_t)(b << 11) + m) << 4) + c];
    a1 = lrelu(a1 * s1 + h1);
    float a2 = c2v + P_V2[(((size_t)(b << 11) + m) << 4) + c];
    a2 = lrelu(a2 * s2 + h2);
    o16[kk] = a1 * a2;
  }
  float* wp = P_W1 + ((size_t)(b * 16 + c)) * NK_ + ((size_t)n << 4);
#pragma unroll
  for (int j = 0; j < 4; j++)
    *(float4*)(wp + j * 4) = make_float4(o16[4 * j], o16[4 * j + 1], o16[4 * j + 2], o16[4 * j + 3]);
  float* orow = ol + c * 260 + nl * 16;
#pragma unroll
  for (int j = 0; j < 4; j++)
    *(float4*)(orow + j * 4) = make_float4(o16[4 * j], o16[4 * j + 1], o16[4 * j + 2], o16[4 * j + 3]);
  __syncthreads();
  if (t < 136) {
    int cc1 = 0, rem = t;
    while (rem >= 16 - cc1) { rem -= 16 - cc1; cc1++; }
    int cc2 = cc1 + rem;
    const float* r1 = ol + cc1 * 260;
    const float* r2 = ol + cc2 * 260;
    float acc = 0.0f;
    for (int e = 0; e < 256; e += 4) {
      float4 xv = *(const float4*)(r1 + e);
      float4 yv = *(const float4*)(r2 + e);
      acc += xv.x * yv.x + xv.y * yv.y + xv.z * yv.z + xv.w * yv.w;
    }
    atomicAdd(&P_ST[ST_S3M + t], acc);
  } else if (t < 152) {
    const float* r = ol + (t - 136) * 260;
    float acc = 0.0f;
    for (int e = 0; e < 256; e += 4) {
      float4 xv = *(const float4*)(r + e);
      acc += xv.x + xv.y + xv.z + xv.w;
    }
    atomicAdd(&P_ST[ST_S3V + t - 136], acc);
  }
}

// --------------------------------------------------------------------------- id 9
__global__ __launch_bounds__(256) void finalize_bn3_kernel(char* base,
                                    const float* __restrict__ b1,
                                    const float* __restrict__ g,
                                    const float* __restrict__ be)
{
  BASE(base);
  PROG(9);
  int o = threadIdx.x;
  if (o >= 64) return;
  float A[16];
  for (int c = 0; c < 16; c++) A[c] = P_A12[o * 16 + c];
  float dv = 0.0f;
  for (int c = 0; c < 16; c++) dv += A[c] * P_ST[ST_S3V + c];
  float quad = 0.0f; int p = 0;
  for (int c1 = 0; c1 < 16; c1++)
    for (int c2 = c1; c2 < 16; c2++) {
      float m = P_ST[ST_S3M + p]; p++;
      quad += (c1 == c2 ? 1.0f : 2.0f) * A[c1] * A[c2] * m;
    }
  float bo = b1[o];
  const float inv = 1.0f / 262144.0f;
  float mean = dv * inv + bo;
  float e2 = quad * inv + 2.0f * bo * dv * inv + bo * bo;
  float var = fmaxf(e2 - mean * mean, 0.0f);
  float s = g[o] * rsqrtf(var + EPSv);
  P_ST[ST_B3SC + o] = s; P_ST[ST_B3SH + o] = be[o] - mean * s;
}

// --------------------------------------------------------------------------- id 10
// a4 v3: register-blocked 2-phase + FUSED stats4 reduction in the epilogue.
__global__ __launch_bounds__(256) void a4_kernel(char* base,
                                                 const float* __restrict__ all1_b,
                                                 const float* __restrict__ all2_b)
{
  BASE(base);
  PROG(10);
  int b = blockIdx.x >> 9; int col0 = (blockIdx.x & 511) * 64;
  int t = threadIdx.x;
  __shared__ float sw[16 * 68];
  __shared__ __align__(16) float hS[64 * 68];
  for (int i = t; i < 1024; i += 256) {
    int c = i >> 6, l = i & 63;
    sw[c * 68 + l] = P_W1[((size_t)(b * 16 + c)) * NK_ + col0 + l];
  }
  __syncthreads();
  {
    int col = t & 63; int q = t >> 6;
    float in16[16];
#pragma unroll
    for (int c = 0; c < 16; c++) in16[c] = sw[c * 68 + col];
    for (int oo = 0; oo < 16; oo++) {
      int o = q * 16 + oo;
      const float* wr = P_A12 + o * 16;
      float a = all1_b[o];
#pragma unroll
      for (int c = 0; c < 16; c++) a += wr[c] * in16[c];
      hS[o * 68 + col] = lrelu(a * P_ST[ST_B3SC + o] + P_ST[ST_B3SH + o]);
    }
  }
  __syncthreads();
  int cg = t & 15;            // 4 consecutive cols
  int og = t >> 4;            // 8 consecutive outs
  float acc[8][4];
#pragma unroll
  for (int oi = 0; oi < 8; oi++) {
    float bo = all2_b[og * 8 + oi];
#pragma unroll
    for (int cj = 0; cj < 4; cj++) acc[oi][cj] = bo;
  }
  for (int hk = 0; hk < 64; hk++) {
    float4 hv = *(const float4*)&hS[hk * 68 + cg * 4];
    const float* wr = P_A22 + hk * 128 + og * 8;
    float4 w0 = *(const float4*)wr;
    float4 w1 = *(const float4*)(wr + 4);
    float av[4] = {hv.x, hv.y, hv.z, hv.w};
    float wv[8] = {w0.x, w0.y, w0.z, w0.w, w1.x, w1.y, w1.z, w1.w};
#pragma unroll
    for (int oi = 0; oi < 8; oi++)
#pragma unroll
      for (int cj = 0; cj < 4; cj++)
        acc[oi][cj] += wv[oi] * av[cj];
  }
  int colb = col0 + cg * 4;
  int n = colb >> 4; int kk0 = colb & 15;
  ushort_t* dst = P_A4 + ((size_t)(b * N_) + n) * 2048 + kk0;
  float psum[8], qsum[8];
#pragma unroll
  for (int oi = 0; oi < 8; oi++) {
    int o = og * 8 + oi;
    unsigned lo = (unsigned)f2bf(acc[oi][0]) | ((unsigned)f2bf(acc[oi][1]) << 16);
    unsigned hi = (unsigned)f2bf(acc[oi][2]) | ((unsigned)f2bf(acc[oi][3]) << 16);
    *(uint2*)(dst + o * 16) = make_uint2(lo, hi);
    float r0 = bf2f(lo & 0xffffu), r1 = bf2f(lo >> 16);
    float r2 = bf2f(hi & 0xffffu), r3 = bf2f(hi >> 16);
    psum[oi] = r0 + r1 + r2 + r3;
    qsum[oi] = r0 * r0 + r1 * r1 + r2 * r2 + r3 * r3;
  }
  __syncthreads();            // all phase-2 reads of hS done
  float* redS = hS;
#pragma unroll
  for (int oi = 0; oi < 8; oi++) redS[(og * 8 + oi) * 16 + cg] = psum[oi];
  __syncthreads();
  if (t < 128) {
    float s = 0.0f;
    for (int j = 0; j < 16; j++) s += redS[t * 16 + j];
    atomicAdd(&P_ST[ST_S4S + t], s);
  }
  __syncthreads();
#pragma unroll
  for (int oi = 0; oi < 8; oi++) redS[(og * 8 + oi) * 16 + cg] = qsum[oi];
  __syncthreads();
  if (t < 128) {
    float s = 0.0f;
    for (int j = 0; j < 16; j++) s += redS[t * 16 + j];
    atomicAdd(&P_ST[ST_S4Q + t], s);
  }
}

// --------------------------------------------------------------------------- id 13
// softfuse: softmax(bn4(A4)) fused with M = lrelu(bn5(IT)) * P.
__global__ __launch_bounds__(256) void softfuse_kernel(char* base)
{
  BASE(base);
  PROG(13);
  int rid = blockIdx.x * 256 + threadIdx.x;   // 2,097,152
  int cc = rid & 127; int r = rid >> 7;
  float s = P_ST[ST_B4SC + cc], h = P_ST[ST_B4SH + cc];
  size_t base_off = (size_t)r * 2048 + cc * 16;
  const ushort_t* pa = P_A4 + base_off;
  uint4 u0 = *(const uint4*)pa;
  uint4 u1 = *(const uint4*)(pa + 8);
  unsigned ws[8] = {u0.x, u0.y, u0.z, u0.w, u1.x, u1.y, u1.z, u1.w};
  float v[16];
#pragma unroll
  for (int j = 0; j < 8; j++) {
    union { float f; unsigned u; } lo, hi;
    lo.u = ws[j] << 16; hi.u = ws[j] & 0xffff0000u;
    v[2 * j] = lo.f; v[2 * j + 1] = hi.f;
  }
  float mx = -BIGF;
#pragma unroll
  for (int i = 0; i < 16; i++) {
    float y = lrelu(v[i] * s + h);
    v[i] = y; mx = fmaxf(mx, y);
  }
  float sum = 0.0f;
#pragma unroll
  for (int i = 0; i < 16; i++) { float e = expf(v[i] - mx); v[i] = e; sum += e; }
  float inv = (sum > 0.0f) ? 1.0f / sum : 0.0f;
#pragma unroll
  for (int i = 0; i < 16; i++) v[i] = bf2f((unsigned)f2bf(v[i] * inv));
  float s5a = P_ST[ST_B5SC + cc * 2],     h5a = P_ST[ST_B5SH + cc * 2];
  float s5b = P_ST[ST_B5SC + cc * 2 + 1], h5b = P_ST[ST_B5SH + cc * 2 + 1];
  const ushort_t* itp = P_IT + base_off;
  uint4 i0 = *(const uint4*)itp;
  uint4 i1 = *(const uint4*)(itp + 8);
  unsigned iw[8] = {i0.x, i0.y, i0.z, i0.w, i1.x, i1.y, i1.z, i1.w};
  unsigned mw[8];
#pragma unroll
  for (int j = 0; j < 8; j++) {
    union { float f; unsigned u; } il, ih;
    il.u = iw[j] << 16; ih.u = iw[j] & 0xffff0000u;
    float s5 = (j < 4) ? s5a : s5b;
    float h5 = (j < 4) ? h5a : h5b;
    float m0 = lrelu(il.f * s5 + h5) * v[2 * j];
    float m1 = lrelu(ih.f * s5 + h5) * v[2 * j + 1];
    mw[j] = (unsigned)f2bf(m0) | ((unsigned)f2bf(m1) << 16);
  }
  ushort_t* mp = P_M + base_off;
  *(uint4*)mp = make_uint4(mw[0], mw[1], mw[2], mw[3]);
  *(uint4*)(mp + 8) = make_uint4(mw[4], mw[5], mw[6], mw[7]);
}

// --------------------------------------------------------------------------- id 17
// final conv v6 (best measured, 248us): 2-way k-split, grid 512.
__global__ __launch_bounds__(256) void final_conv_kernel(char* base)
{
  BASE(base);
  PROG(17);
  int ks = blockIdx.x & 1;
  int tile = (blockIdx.x >> 1) & 31; int b = blockIdx.x >> 6;
  int n0 = tile * 64;
  int t = threadIdx.x;
  int cg4 = (t & 15) * 4;
  int obase = (t >> 4) * 8;
  __shared__ __align__(16) float tileS[128 * 68];
  __shared__ int sidxT[16 * 64];        // [p][cl]
  for (int i = t; i < 1024; i += 256) {
    int cl = i & 63, p = i >> 6;
    sidxT[p * 64 + cl] = P_IDX[((size_t)(b * N_) + n0 + cl) * K_ + p] & NMASK;
  }
  float acc[32];
#pragma unroll
  for (int i = 0; i < 32; i++) acc[i] = 0.0f;
  int kbeg = ks * 1536;
  for (int k0 = kbeg; k0 < kbeg + 1536; k0 += 128) {
    __syncthreads();
    if (k0 < 1024) {
      int c0 = k0 >> 4;
      int cl = t & 63; int pg = t >> 6;
      for (int pp = 0; pp < 4; pp++) {
        int p = pg * 4 + pp;
        int m = sidxT[p * 64 + cl];
        const float* xp = P_XT + ((size_t)(b * N_) + m) * 64 + c0;
        float4 v0 = *(const float4*)xp;
        float4 v1 = *(const float4*)(xp + 4);
        tileS[(0 * 16 + p) * 68 + cl] = v0.x;
        tileS[(1 * 16 + p) * 68 + cl] = v0.y;
        tileS[(2 * 16 + p) * 68 + cl] = v0.z;
        tileS[(3 * 16 + p) * 68 + cl] = v0.w;
        tileS[(4 * 16 + p) * 68 + cl] = v1.x;
        tileS[(5 * 16 + p) * 68 + cl] = v1.y;
        tileS[(6 * 16 + p) * 68 + cl] = v1.z;
        tileS[(7 * 16 + p) * 68 + cl] = v1.w;
      }
    } else {
      int cl = t & 63; int kg = t >> 6;           // 4 groups x 32 k
      size_t rb = ((size_t)(b * N_) + n0 + cl) * 2048 + (size_t)(k0 - 1024) + kg * 32;
      const ushort_t* mp = P_M + rb;
      for (int j8 = 0; j8 < 4; j8++) {
        uint4 u = *(const uint4*)(mp + j8 * 8);
        unsigned ws[4] = {u.x, u.y, u.z, u.w};
#pragma unroll
        for (int q = 0; q < 4; q++) {
          union { float f; unsigned uu; } lo, hi;
          lo.uu = ws[q] << 16; hi.uu = ws[q] & 0xffff0000u;
          int kc = kg * 32 + j8 * 8 + q * 2;
          tileS[kc * 68 + cl] = lo.f;
          tileS[(kc + 1) * 68 + cl] = hi.f;
        }
      }
    }
    __syncthreads();
    for (int kc = 0; kc < 128; kc++) {
      float4 a = *(const float4*)&tileS[kc * 68 + cg4];
      const float* wr = P_WC2 + (size_t)(k0 + kc) * C2_ + obase;
      float4 w0 = *(const float4*)wr;
      float4 w1 = *(const float4*)(wr + 4);
      float av[4] = {a.x, a.y, a.z, a.w};
      float wv[8] = {w0.x, w0.y, w0.z, w0.w, w1.x, w1.y, w1.z, w1.w};
#pragma unroll
      for (int oi = 0; oi < 8; oi++)
#pragma unroll
        for (int cj = 0; cj < 4; cj++)
          acc[oi * 4 + cj] += wv[oi] * av[cj];
    }
  }
#pragma unroll
  for (int cj = 0; cj < 4; cj++) {
    float* op = P_PART + ((size_t)ks * B_ * N_ + (size_t)b * N_ + n0 + cg4 + cj) * C2_ + obase;
    *(float4*)op = make_float4(acc[0 * 4 + cj], acc[1 * 4 + cj], acc[2 * 4 + cj], acc[3 * 4 + cj]);
    *(float4*)(op + 4) = make_float4(acc[4 * 4 + cj], acc[5 * 4 + cj], acc[6 * 4 + cj], acc[7 * 4 + cj]);
  }
}

// --------------------------------------------------------------------------- id 18
// reduce_stats v2: grid 512. 32 rows/block.
__global__ __launch_bounds__(256) void reduce_stats_kernel(char* base,
                                                           const float* __restrict__ c2_b)
{
  BASE(base);
  PROG(18);
  int r0 = blockIdx.x * 32;    // grid 512
  int t = threadIdx.x; int o = t & 127; int h = t >> 7;
  const size_t STRIDE = (size_t)B_ * N_ * C2_;
  float cb = c2_b[o];
  float s = 0, q = 0;
  for (int r = r0 + h; r < r0 + 32; r += 2) {
    size_t off = (size_t)r * C2_ + o;
    float v = cb + P_Sb[off] + P_PART[off] + P_PART[STRIDE + off];
    P_OUT2[off] = v;
    s += v; q += v * v;
  }
  __shared__ float rs[256], rq[256];
  rs[t] = s; rq[t] = q; __syncthreads();
  if (t < 128) {
    atomicAdd(&P_ST[ST_S6S + o], rs[t] + rs[t + 128]);
    atomicAdd(&P_ST[ST_S6Q + o], rq[t] + rq[t + 128]);
  }
}

// --------------------------------------------------------------------------- id 20
// output v2: LDS-tiled.
__global__ __launch_bounds__(256) void output_kernel(char* base, float* __restrict__ out)
{
  BASE(base);
  PROG(20);
  int b = blockIdx.x >> 6; int n0 = (blockIdx.x & 63) * 32;
  int t = threadIdx.x;
  __shared__ float tile[32 * 133];
  for (int i = t; i < 4096; i += 256) {
    int o = i & 127, nl = i >> 7;
    float v = P_OUT2[((size_t)(b * N_) + n0 + nl) * C2_ + o];
    v = v * P_ST[ST_B6SC + o] + P_ST[ST_B6SH + o];
    tile[nl * 133 + o] = fmaxf(v, 0.0f);
  }
  __syncthreads();
  for (int i = t; i < 4096; i += 256) {
    int nl = i & 31, o = i >> 5;
    out[(((size_t)b * 64 + (o >> 1)) * 2 + (o & 1)) * 2048 + n0 + nl] = tile[nl * 133 + o];
  }
}

// --------------------------------------------------------------------------- diagnostics
__global__ void diag_kernel(char* base, float* __restrict__ out)
{
  BASE(base);
  const int expctd[22] = {1, 2253, 5120, 0, 0, 1, 1, 1024, 256, 1, 4096,
                          0, 1, 8192, 0, 5120, 1, 512, 512, 1, 512, 0};
  int t = threadIdx.x;
  int bad = 99;
  if (t < 22 && P_PROG[t] != expctd[t]) bad = t;
#pragma unroll
  for (int off = 32; off > 0; off >>= 1) {
    int ob = __shfl_xor(bad, off);
    if (ob < bad) bad = ob;
  }
  if (t == 0 && bad != 99) out[0] = 100.0f + 10.0f * (float)bad;
}

__global__ void code_kernel(float* __restrict__ out, float code)
{
  if (threadIdx.x == 0 && blockIdx.x == 0) out[0] = code;
}

// ---------------------------------------------------------------------------
extern "C" void kernel_launch(void* const* d_in, const int* in_sizes, int n_in,
                              void* d_out, int out_size, void* d_ws, size_t ws_size,
                              hipStream_t stream) {
  const float* x      = (const float*)d_in[0];
  const float* pc     = (const float*)d_in[1];
  const float* fea_w  = (const float*)d_in[2];
  const float* fea_b  = (const float*)d_in[3];
  const float* fea_g  = (const float*)d_in[4];
  const float* fea_be = (const float*)d_in[5];
  const float* xyz_w  = (const float*)d_in[6];
  const float* xyz_b  = (const float*)d_in[7];
  const float* xyz_g  = (const float*)d_in[8];
  const float* xyz_be = (const float*)d_in[9];
  const float* all1_w = (const float*)d_in[10];
  const float* all1_b = (const float*)d_in[11];
  const float* all1_g = (const float*)d_in[12];
  const float* all1_be= (const float*)d_in[13];
  const float* all2_w = (const float*)d_in[14];
  const float* all2_b = (const float*)d_in[15];
  const float* all2_g = (const float*)d_in[16];
  const float* all2_be= (const float*)d_in[17];
  const float* inte_w = (const float*)d_in[18];
  const float* inte_b = (const float*)d_in[19];
  const float* inte_g = (const float*)d_in[20];
  const float* inte_be= (const float*)d_in[21];
  const float* c2_w   = (const float*)d_in[22];
  const float* c2_b   = (const float*)d_in[23];
  const float* c2_g   = (const float*)d_in[24];
  const float* c2_be  = (const float*)d_in[25];
  float* out = (float*)d_out;
  (void)in_sizes; (void)n_in; (void)out_size; (void)d_ws; (void)ws_size;

  if (g_pool_mem == nullptr) {
    code_kernel<<<1, 64, 0, stream>>>(out, 500.0f);
    return;
  }
  char* base = g_pool_mem;

  zero_kernel<<<1, 256, 0, stream>>>(base);
  xt_kernel<<<256, 256, 0, stream>>>(base, x);
  prep_kernel<<<2253, 256, 0, stream>>>(base, fea_w, xyz_w, inte_w, c2_w, all1_w, all2_w);
  phaseA_kernel<<<5120, 256, 0, stream>>>(base, x, pc);
  phaseB_kernel<<<5120, 256, 0, stream>>>(base, inte_b, fea_b, xyz_b);
  finalize_bn_kernel<<<1, 256, 0, stream>>>(base, fea_g, fea_be, ST_S1S, ST_S1Q, ST_B1SC, ST_B1SH, 16, 1.0f / 262144.0f, 5);
  finalize_bn_kernel<<<1, 256, 0, stream>>>(base, xyz_g, xyz_be, ST_S2S, ST_S2Q, ST_B2SC, ST_B2SH, 16, 1.0f / 262144.0f, 6);
  finalize_bn_kernel<<<1, 256, 0, stream>>>(base, inte_g, inte_be, ST_S5S, ST_S5Q, ST_B5SC, ST_B5SH, 256, 1.0f / 131072.0f, 16);
  w1_kernel<<<1024, 256, 0, stream>>>(base, fea_b, xyz_b);
  finalize_bn3_kernel<<<1, 256, 0, stream>>>(base, all1_b, all1_g, all1_be);
  a4_kernel<<<4096, 256, 0, stream>>>(base, all1_b, all2_b);
  finalize_bn_kernel<<<1, 256, 0, stream>>>(base, all2_g, all2_be, ST_S4S, ST_S4Q, ST_B4SC, ST_B4SH, 128, 1.0f / 262144.0f, 12);
  softfuse_kernel<<<8192, 256, 0, stream>>>(base);
  final_conv_kernel<<<512, 256, 0, stream>>>(base);
  reduce_stats_kernel<<<512, 256, 0, stream>>>(base, c2_b);
  finalize_bn_kernel<<<1, 256, 0, stream>>>(base, c2_g, c2_be, ST_S6S, ST_S6Q, ST_B6SC, ST_B6SH, 128, 1.0f / 16384.0f, 19);
  output_kernel<<<512, 256, 0, stream>>>(base, out);
  diag_kernel<<<1, 64, 0, stream>>>(base, out);
}